// Round 4
// baseline (330.880 us; speedup 1.0000x reference)
//
#include <hip/hip_runtime.h>

// Instant-NGP hash encode (16 levels, F=2) + 32->64->64->8 MLP via MFMA,
// outer trilinear over 8 corners of a 512^3 grid.
//
// R13: phase-split regs, zero barriers, 133us. Law: dur tracks FETCH at
//   ~2.35 TB/s (L2-miss path).
// R14: two-pass level split (pass A: coarse L3/L4, 4MB = per-XCD L2;
//   pass B: dense+fine+MLP, 5.3MB). FETCH 312->91MB, pb 92us. CONFIRMED.
//   pb now: streams (partial 16MB + xyz 3MB) thrash L2 -> ~70MB re-misses.
// R15: (1) non-temporal loads/stores for all streams (xyz, partials, out,
//   prep) so they bypass L2 and stop evicting hot tables. (2) dense levels
//   0+1 merged into one 33^3 x 4-feat bf16 grid (trilinear-on-subbox
//   identity; vertex values precomputed in prep) -> 2 interps instead of 3.
//   (3) launch_bounds(256,8) on pb for occupancy.

typedef __attribute__((ext_vector_type(8))) short short8_t;
typedef __attribute__((ext_vector_type(4))) float f32x4;
typedef unsigned long long ull;

static constexpr unsigned kT    = 1u << 19;
static constexpr unsigned kMask = kT - 1u;
static constexpr unsigned cP1   = 2654435761u;
static constexpr unsigned cP2   = 805459861u;
static constexpr int      BLOCK = 256;
static constexpr int      TOFF  = 4096;        // d_ws dword offset of tables
static constexpr unsigned D01   = 1u << 21;    // tbx dwords: L0+L1 uint2[33^3]
static constexpr unsigned N01   = 35937u;      // 33^3
static constexpr unsigned D2    = D01 + 72000u;// tbx dwords: L2 dword[65^3]
static constexpr unsigned N2    = 274625u;     // 65^3
static constexpr unsigned PARTO = 2621440u;    // dword offset of partials
static constexpr size_t   WS_NEED  = ((size_t)TOFF + (1u << 21)) * 4;   // 8MB+
static constexpr size_t   WS_NEED2 = ((size_t)PARTO + (1u << 22)) * 4;  // 26MB+

static __device__ __forceinline__ unsigned bf16_rn(float x) {
    unsigned u = __float_as_uint(x);
    return (u + 0x7fffu + ((u >> 16) & 1u)) >> 16;   // round-to-nearest-even
}

static __device__ __forceinline__ float2 bf2dec(unsigned u) {
    return make_float2(__uint_as_float(u << 16),
                       __uint_as_float(u & 0xffff0000u));
}

// packed f32x2 -> bf16x2, RNE (bit-identical to bf16_rn pair). lo in low 16.
static __device__ __forceinline__ unsigned cvtpk(float lo, float hi) {
    unsigned r;
    asm("v_cvt_pk_bf16_f32 %0, %1, %2" : "=v"(r) : "v"(lo), "v"(hi));
    return r;
}

static __device__ __forceinline__ f32x4 mfma16(short8_t a, short8_t b, f32x4 c) {
    return __builtin_amdgcn_mfma_f32_16x16x32_bf16(a, b, c, 0, 0, 0);
}

// ---- fused prep: [0,ncc) coarse bf16; [+ncf) fine compact; [+ncd) dense L2;
// [+nc01) merged L0+L1 grid; tail 4 blocks = weight pre-swizzle.
__global__ __launch_bounds__(256)
void prep_all(const float* __restrict__ W0, const float* __restrict__ W1,
              const float* __restrict__ W2, const float2* __restrict__ tbl,
              unsigned* __restrict__ ws, int ncc, int ncf, int ncd, int nc01)
{
    const int bx = blockIdx.x, tid = threadIdx.x;
    if (bx < ncc) {
        // coarse levels 3,4: fp32x2 -> packed bf16x2 (pairs of entries)
        const int i = bx * 256 + tid;                // < 2^19
        const ull* __restrict__ p = (const ull*)(tbl + (size_t)3 * kT);
        const ull a = __builtin_nontemporal_load(p + 2 * (size_t)i);
        const ull b = __builtin_nontemporal_load(p + 2 * (size_t)i + 1);
        const ull o = (ull)(bf16_rn(__uint_as_float((unsigned)a))
                          | (bf16_rn(__uint_as_float((unsigned)(a >> 32))) << 16))
                    | ((ull)(bf16_rn(__uint_as_float((unsigned)b))
                          | (bf16_rn(__uint_as_float((unsigned)(b >> 32))) << 16)) << 32);
        __builtin_nontemporal_store(o, (ull*)(ws + TOFF) + i);
    } else if (bx < ncc + ncf) {
        // fine level 5+s entry (j<<s) -> compact slot j at fineOff(s)
        const int i = (bx - ncc) * 256 + tid;        // < 2^20 - 2^9
        const unsigned vv = (1u << 20) - 1u - (unsigned)i;
        const int s = __clz((int)vv) - 12;           // 0..10
        const unsigned fo = (1u << 20) - ((1u << 20) >> s);
        const unsigned j = (unsigned)i - fo;
        const ull e = __builtin_nontemporal_load(
            (const ull*)tbl + ((size_t)(5 + s) << 19) + ((size_t)j << s));
        const unsigned o = bf16_rn(__uint_as_float((unsigned)e))
                         | (bf16_rn(__uint_as_float((unsigned)(e >> 32))) << 16);
        __builtin_nontemporal_store(o, ws + TOFF + (1u << 20) + i);
    } else if (bx < ncc + ncf + ncd) {
        // dense level 2: fp32x2 -> bf16x2 dword, contiguous 65^3
        const int i = (bx - ncc - ncf) * 256 + tid;
        if (i < (int)N2) {
            const ull e = __builtin_nontemporal_load(
                (const ull*)tbl + (size_t)2 * kT + i);
            const unsigned o = bf16_rn(__uint_as_float((unsigned)e))
                             | (bf16_rn(__uint_as_float((unsigned)(e >> 32))) << 16);
            __builtin_nontemporal_store(o, ws + TOFF + D2 + i);
        }
    } else if (bx < ncc + ncf + ncd + nc01) {
        // merged L0+L1 grid: per level-1 vertex v (33^3), store
        // (bf16 f0(v), bf16 f1(v)) where f0 = level-0 trilinear at v/2.
        const int i = (bx - ncc - ncf - ncd) * 256 + tid;
        if (i < (int)N01) {
            const int vz = i / 1089;
            const int r  = i - vz * 1089;
            const int vy = r / 33;
            const int vx = r - vy * 33;
            const float2 f1 = tbl[(size_t)kT + i];   // level-1 value (gather)
            const int x0 = vx >> 1, y0 = vy >> 1, z0 = vz >> 1;
            const int x1 = (x0 + 1 > 16) ? 16 : x0 + 1;
            const int y1 = (y0 + 1 > 16) ? 16 : y0 + 1;
            const int z1 = (z0 + 1 > 16) ? 16 : z0 + 1;
            const float fx = (vx & 1) ? 0.5f : 0.0f;
            const float fy = (vy & 1) ? 0.5f : 0.0f;
            const float fz = (vz & 1) ? 0.5f : 0.0f;
            const int Y0 = y0 * 17, Y1 = y1 * 17, Z0 = z0 * 289, Z1 = z1 * 289;
            const float2 g0 = tbl[x0 + Y0 + Z0], g1 = tbl[x1 + Y0 + Z0];
            const float2 g2 = tbl[x0 + Y1 + Z0], g3 = tbl[x1 + Y1 + Z0];
            const float2 g4 = tbl[x0 + Y0 + Z1], g5 = tbl[x1 + Y0 + Z1];
            const float2 g6 = tbl[x0 + Y1 + Z1], g7 = tbl[x1 + Y1 + Z1];
            const float wx1 = fx, wx0 = 1.0f - fx;
            const float wy1 = fy, wy0 = 1.0f - fy;
            const float wz1 = fz, wz0 = 1.0f - fz;
            const float w00 = wx0 * wy0, w10 = wx1 * wy0, w01 = wx0 * wy1, w11 = wx1 * wy1;
            const float a0 = w00 * wz0, a1 = w10 * wz0, a2 = w01 * wz0, a3 = w11 * wz0;
            const float a4 = w00 * wz1, a5 = w10 * wz1, a6 = w01 * wz1, a7 = w11 * wz1;
            const float f0x = a0 * g0.x + a1 * g1.x + a2 * g2.x + a3 * g3.x
                            + a4 * g4.x + a5 * g5.x + a6 * g6.x + a7 * g7.x;
            const float f0y = a0 * g0.y + a1 * g1.y + a2 * g2.y + a3 * g3.y
                            + a4 * g4.y + a5 * g5.y + a6 * g6.y + a7 * g7.y;
            const ull o = (ull)cvtpk(f0x, f0y) | ((ull)cvtpk(f1.x, f1.y) << 32);
            __builtin_nontemporal_store(o, (ull*)(ws + TOFF + D01) + i);
        }
    } else {
        // weights: A-frag order, bf16 RNE. tiles 0..3 = W0; 4..11 = W1
        // (mt=(t-4)>>1, kt=(t-4)&1, K pi-permuted); 12..13 = W2 (cols>=8 zero)
        const int t = (bx - ncc - ncf - ncd - nc01) * 4 + (tid >> 6);
        if (t >= 14) return;
        const int lane = tid & 63;
        const int n = lane & 15, q = lane >> 4;
        unsigned hi[4];
        #pragma unroll
        for (int d = 0; d < 4; ++d) {
            unsigned h2[2];
            #pragma unroll
            for (int s = 0; s < 2; ++s) {
                const int j = d * 2 + s;
                float v;
                if (t < 4) {
                    v = W0[(q * 8 + j) * 64 + t * 16 + n];
                } else {
                    const int kp = (j < 4) ? (q * 4 + j) : (16 + q * 4 + (j - 4));
                    if (t < 12) v = W1[(((t - 4) & 1) * 32 + kp) * 64 + ((t - 4) >> 1) * 16 + n];
                    else        v = (n < 8) ? W2[((t - 12) * 32 + kp) * 8 + n] : 0.0f;
                }
                h2[s] = bf16_rn(v);
            }
            hi[d] = h2[0] | (h2[1] << 16);
        }
        ((uint4*)ws)[t * 64 + lane] = make_uint4(hi[0], hi[1], hi[2], hi[3]);
    }
}

// ---- pass A: coarse levels 3,4 only (4MB working set = per-XCD L2).
// Streams (xyz in, partial out) are non-temporal: tables own the L2.
__global__ __launch_bounds__(256, 8)
void ngp_pa(const float* __restrict__ xyz, const int* __restrict__ boundp,
            unsigned* __restrict__ ws)
{
    const int tid = threadIdx.x;
    const int ge  = blockIdx.x * 256 + tid;
    const int pt  = ge >> 3;
    const int b   = ge & 7;

    const float bnd = (float)boundp[0];
    const float sc  = 0.5f / bnd;
    const float pxv = __builtin_nontemporal_load(xyz + pt * 3 + 0);
    const float pyv = __builtin_nontemporal_load(xyz + pt * 3 + 1);
    const float pzv = __builtin_nontemporal_load(xyz + pt * 3 + 2);
    const float cxf = (pxv + bnd) * sc * 512.0f;
    const float cyf = (pyv + bnd) * sc * 512.0f;
    const float czf = (pzv + bnd) * sc * 512.0f;
    const float c0x = fminf(fmaxf(floorf(cxf), 0.0f), 511.0f);
    const float c0y = fminf(fmaxf(floorf(cyf), 0.0f), 511.0f);
    const float c0z = fminf(fmaxf(floorf(czf), 0.0f), 511.0f);
    const unsigned kx = (unsigned)c0x + (unsigned)(b & 1);
    const unsigned ky = (unsigned)c0y + (unsigned)((b >> 1) & 1);
    const unsigned kz = (unsigned)c0z + (unsigned)((b >> 2) & 1);

    const unsigned* __restrict__ tbx = ws + TOFF;
    unsigned gH[2][8];
    #pragma unroll
    for (int l = 3; l < 5; ++l) {
        const int d = 5 - l;
        const unsigned qx = kx >> d, qy = ky >> d, qz = kz >> d;
        const unsigned hy0 = qy * cP1, hy1 = hy0 + cP1;
        const unsigned hz0 = qz * cP2, hz1 = hz0 + cP2;
        const unsigned x1u = qx + 1u;
        unsigned hidx[8];
        hidx[0] = (qx  ^ hy0 ^ hz0) & kMask;  hidx[1] = (x1u ^ hy0 ^ hz0) & kMask;
        hidx[2] = (qx  ^ hy1 ^ hz0) & kMask;  hidx[3] = (x1u ^ hy1 ^ hz0) & kMask;
        hidx[4] = (qx  ^ hy0 ^ hz1) & kMask;  hidx[5] = (x1u ^ hy0 ^ hz1) & kMask;
        hidx[6] = (qx  ^ hy1 ^ hz1) & kMask;  hidx[7] = (x1u ^ hy1 ^ hz1) & kMask;
        const unsigned* __restrict__ base = tbx + (size_t)(l - 3) * kT;
        #pragma unroll
        for (int c = 0; c < 8; ++c) gH[l - 3][c] = base[hidx[c]];
    }

    unsigned xd34[2];
    #pragma unroll
    for (int l = 3; l < 5; ++l) {
        const int d = 5 - l;
        const unsigned m = (1u << d) - 1u;
        const float inv = 1.0f / (float)(1 << d);
        const float fx = (float)(kx & m) * inv;
        const float fy = (float)(ky & m) * inv;
        const float fz = (float)(kz & m) * inv;
        const float2 g0 = bf2dec(gH[l - 3][0]), g1 = bf2dec(gH[l - 3][1]);
        const float2 g2 = bf2dec(gH[l - 3][2]), g3 = bf2dec(gH[l - 3][3]);
        const float2 g4 = bf2dec(gH[l - 3][4]), g5 = bf2dec(gH[l - 3][5]);
        const float2 g6 = bf2dec(gH[l - 3][6]), g7 = bf2dec(gH[l - 3][7]);
        const float wx1 = fx, wx0 = 1.0f - fx;
        const float wy1 = fy, wy0 = 1.0f - fy;
        const float wz1 = fz, wz0 = 1.0f - fz;
        const float w00 = wx0 * wy0, w10 = wx1 * wy0, w01 = wx0 * wy1, w11 = wx1 * wy1;
        const float a0 = w00 * wz0, a1 = w10 * wz0, a2 = w01 * wz0, a3 = w11 * wz0;
        const float a4 = w00 * wz1, a5 = w10 * wz1, a6 = w01 * wz1, a7 = w11 * wz1;
        const float vx = a0 * g0.x + a1 * g1.x + a2 * g2.x + a3 * g3.x
                       + a4 * g4.x + a5 * g5.x + a6 * g6.x + a7 * g7.x;
        const float vy = a0 * g0.y + a1 * g1.y + a2 * g2.y + a3 * g3.y
                       + a4 * g4.y + a5 * g5.y + a6 * g6.y + a7 * g7.y;
        xd34[l - 3] = cvtpk(vx, vy);
    }
    const ull o = (ull)xd34[0] | ((ull)xd34[1] << 32);
    __builtin_nontemporal_store(o, (ull*)(ws + PARTO) + ge);
}

// ---- pass B: dense (L01 merged + L2) + fine + partial + MLP. Hot ~5.4MB,
// all streams non-temporal.
__global__ __launch_bounds__(BLOCK, 8)
void ngp_pb(const float*  __restrict__ xyz,
            const int*    __restrict__ boundp,
            const unsigned* __restrict__ wsw,
            float*        __restrict__ out)
{
    // LDS: x only. row = eval (16 dw = 32 bf16 feats), quad XOR-swizzled.
    __shared__ __align__(16) unsigned lds[4096];
    const int tid  = threadIdx.x;
    const int lane = tid & 63;
    const int wv   = tid >> 6;
    const int col  = lane & 15;
    const int q    = lane >> 4;
    const int swz  = (tid ^ (tid >> 2) ^ (tid >> 4)) & 3;

    const unsigned* __restrict__ tbx = wsw + TOFF;
    const float bnd = (float)boundp[0];
    const float sc  = 0.5f / bnd;
    const f32x4 zero = {0.0f, 0.0f, 0.0f, 0.0f};

    // ================= encode (no weights live) =================
    const int ge = blockIdx.x * BLOCK + tid;
    const int pt = ge >> 3;
    const int b  = ge & 7;

    const float pxv = __builtin_nontemporal_load(xyz + pt * 3 + 0);
    const float pyv = __builtin_nontemporal_load(xyz + pt * 3 + 1);
    const float pzv = __builtin_nontemporal_load(xyz + pt * 3 + 2);
    const float cxf = (pxv + bnd) * sc * 512.0f;
    const float cyf = (pyv + bnd) * sc * 512.0f;
    const float czf = (pzv + bnd) * sc * 512.0f;
    const float c0x = fminf(fmaxf(floorf(cxf), 0.0f), 511.0f);
    const float c0y = fminf(fmaxf(floorf(cyf), 0.0f), 511.0f);
    const float c0z = fminf(fmaxf(floorf(czf), 0.0f), 511.0f);
    const float frx = cxf - c0x;
    const float fry = cyf - c0y;
    const float frz = czf - c0z;

    const unsigned kx = (unsigned)c0x + (unsigned)(b & 1);
    const unsigned ky = (unsigned)c0y + (unsigned)((b >> 1) & 1);
    const unsigned kz = (unsigned)c0z + (unsigned)((b >> 2) & 1);

    const float wb = ((b & 1) ? frx : 1.0f - frx)
                   * ((b & 2) ? fry : 1.0f - fry)
                   * ((b & 4) ? frz : 1.0f - frz);

    // fine levels (l=5..15): frac==0, single gather each (compacted).
    const unsigned kyp = ky * cP1;
    const unsigned kzp = kz * cP2;
    const unsigned X   = kx ^ kyp ^ kzp;
    unsigned gfu[11];
    #pragma unroll
    for (int l = 5; l < 16; ++l) {
        const int s = l - 5;
        const unsigned base = (1u << 20) + ((1u << 20) - ((1u << 20) >> s));
        gfu[l - 5] = tbx[base + (X & (kMask >> s))];
    }

    // coarse partial (written by pass A): non-temporal stream read
    const ull pv = __builtin_nontemporal_load((const ull*)(wsw + PARTO) + ge);

    unsigned xd[16];
    // merged levels 0+1 on the 33^3 level-1 grid (4 feats/vertex)
    {
        const unsigned qx = kx >> 4, qy = ky >> 4, qz = kz >> 4;
        const float fx = (float)(kx & 15u) * 0.0625f;
        const float fy = (float)(ky & 15u) * 0.0625f;
        const float fz = (float)(kz & 15u) * 0.0625f;
        const unsigned x0 = qx, x1 = (qx + 1u > 32u) ? 32u : qx + 1u;
        const unsigned y0 = qy * 33u, y1 = ((qy + 1u > 32u) ? 32u : qy + 1u) * 33u;
        const unsigned z0 = qz * 1089u, z1 = ((qz + 1u > 32u) ? 32u : qz + 1u) * 1089u;
        const uint2* __restrict__ b01 = (const uint2*)(tbx + D01);
        const uint2 h0 = b01[x0 + y0 + z0], h1 = b01[x1 + y0 + z0];
        const uint2 h2 = b01[x0 + y1 + z0], h3 = b01[x1 + y1 + z0];
        const uint2 h4 = b01[x0 + y0 + z1], h5 = b01[x1 + y0 + z1];
        const uint2 h6 = b01[x0 + y1 + z1], h7 = b01[x1 + y1 + z1];
        const float wx1 = fx, wx0 = 1.0f - fx;
        const float wy1 = fy, wy0 = 1.0f - fy;
        const float wz1 = fz, wz0 = 1.0f - fz;
        const float w00 = wx0 * wy0, w10 = wx1 * wy0, w01 = wx0 * wy1, w11 = wx1 * wy1;
        const float a0 = w00 * wz0, a1 = w10 * wz0, a2 = w01 * wz0, a3 = w11 * wz0;
        const float a4 = w00 * wz1, a5 = w10 * wz1, a6 = w01 * wz1, a7 = w11 * wz1;
        float f0x, f0y, f1x, f1y;
        float2 d;
        d = bf2dec(h0.x); f0x  = a0 * d.x; f0y  = a0 * d.y;
        d = bf2dec(h0.y); f1x  = a0 * d.x; f1y  = a0 * d.y;
        d = bf2dec(h1.x); f0x += a1 * d.x; f0y += a1 * d.y;
        d = bf2dec(h1.y); f1x += a1 * d.x; f1y += a1 * d.y;
        d = bf2dec(h2.x); f0x += a2 * d.x; f0y += a2 * d.y;
        d = bf2dec(h2.y); f1x += a2 * d.x; f1y += a2 * d.y;
        d = bf2dec(h3.x); f0x += a3 * d.x; f0y += a3 * d.y;
        d = bf2dec(h3.y); f1x += a3 * d.x; f1y += a3 * d.y;
        d = bf2dec(h4.x); f0x += a4 * d.x; f0y += a4 * d.y;
        d = bf2dec(h4.y); f1x += a4 * d.x; f1y += a4 * d.y;
        d = bf2dec(h5.x); f0x += a5 * d.x; f0y += a5 * d.y;
        d = bf2dec(h5.y); f1x += a5 * d.x; f1y += a5 * d.y;
        d = bf2dec(h6.x); f0x += a6 * d.x; f0y += a6 * d.y;
        d = bf2dec(h6.y); f1x += a6 * d.x; f1y += a6 * d.y;
        d = bf2dec(h7.x); f0x += a7 * d.x; f0y += a7 * d.y;
        d = bf2dec(h7.y); f1x += a7 * d.x; f1y += a7 * d.y;
        xd[0] = cvtpk(f0x, f0y);
        xd[1] = cvtpk(f1x, f1y);
    }
    // dense level 2 (65^3 bf16)
    {
        const unsigned qx = kx >> 3, qy = ky >> 3, qz = kz >> 3;
        const float fx = (float)(kx & 7u) * 0.125f;
        const float fy = (float)(ky & 7u) * 0.125f;
        const float fz = (float)(kz & 7u) * 0.125f;
        const unsigned x0 = qx, x1 = (qx + 1u > 64u) ? 64u : qx + 1u;
        const unsigned y0 = qy * 65u, y1 = ((qy + 1u > 64u) ? 64u : qy + 1u) * 65u;
        const unsigned z0 = qz * 4225u, z1 = ((qz + 1u > 64u) ? 64u : qz + 1u) * 4225u;
        const unsigned* __restrict__ b2 = tbx + D2;
        const float2 g0 = bf2dec(b2[x0 + y0 + z0]), g1 = bf2dec(b2[x1 + y0 + z0]);
        const float2 g2 = bf2dec(b2[x0 + y1 + z0]), g3 = bf2dec(b2[x1 + y1 + z0]);
        const float2 g4 = bf2dec(b2[x0 + y0 + z1]), g5 = bf2dec(b2[x1 + y0 + z1]);
        const float2 g6 = bf2dec(b2[x0 + y1 + z1]), g7 = bf2dec(b2[x1 + y1 + z1]);
        const float wx1 = fx, wx0 = 1.0f - fx;
        const float wy1 = fy, wy0 = 1.0f - fy;
        const float wz1 = fz, wz0 = 1.0f - fz;
        const float w00 = wx0 * wy0, w10 = wx1 * wy0, w01 = wx0 * wy1, w11 = wx1 * wy1;
        const float a0 = w00 * wz0, a1 = w10 * wz0, a2 = w01 * wz0, a3 = w11 * wz0;
        const float a4 = w00 * wz1, a5 = w10 * wz1, a6 = w01 * wz1, a7 = w11 * wz1;
        const float vx = a0 * g0.x + a1 * g1.x + a2 * g2.x + a3 * g3.x
                       + a4 * g4.x + a5 * g5.x + a6 * g6.x + a7 * g7.x;
        const float vy = a0 * g0.y + a1 * g1.y + a2 * g2.y + a3 * g3.y
                       + a4 * g4.y + a5 * g5.y + a6 * g6.y + a7 * g7.y;
        xd[2] = cvtpk(vx, vy);
    }
    xd[3] = (unsigned)pv;
    xd[4] = (unsigned)(pv >> 32);
    #pragma unroll
    for (int l = 5; l < 16; ++l) xd[l] = gfu[l - 5];

    // swizzled x write: quad k at position k^swz (row = tid)
    {
        uint4* xrow = (uint4*)(lds + tid * 16);
        xrow[swz]     = make_uint4(xd[0],  xd[1],  xd[2],  xd[3]);
        xrow[swz ^ 1] = make_uint4(xd[4],  xd[5],  xd[6],  xd[7]);
        xrow[swz ^ 2] = make_uint4(xd[8],  xd[9],  xd[10], xd[11]);
        xrow[swz ^ 3] = make_uint4(xd[12], xd[13], xd[14], xd[15]);
    }

    // x exchange is within-wave (ev = wv*64+...) -> wave-local fence only.
    // Memory clobber pins the weight loads below (phase-split pressure).
    asm volatile("s_waitcnt lgkmcnt(0)" ::: "memory");
    __builtin_amdgcn_sched_barrier(0);

    // ---- weights -> 56 VGPRs (same addresses all waves: L1/L2 broadcast)
    short8_t w[14];
    {
        const short8_t* __restrict__ wfr = (const short8_t*)wsw;
        #pragma unroll
        for (int t = 0; t < 14; ++t) w[t] = wfr[t * 64 + lane];
    }

    // ================= MLP (transposed MFMA, weights in regs) =========
    #pragma unroll 1
    for (int g = 0; g < 4; ++g) {
        const int ev  = wv * 64 + g * 16 + col;
        const int esw = ((ev ^ (ev >> 2) ^ (ev >> 4)) & 3) ^ q;
        const short8_t xb = *(const short8_t*)(lds + ev * 16 + esw * 4);
        const float wbv = __shfl(wb, g * 16 + col, 64);

        unsigned hp0[4], hp1[4];
        // layer 1
        #pragma unroll
        for (int mt = 0; mt < 4; ++mt) {
            f32x4 a = mfma16(w[mt], xb, zero);
            hp0[mt] = cvtpk(fmaxf(a[0], 0.0f), fmaxf(a[1], 0.0f));
            hp1[mt] = cvtpk(fmaxf(a[2], 0.0f), fmaxf(a[3], 0.0f));
        }
        uint4 u0 = make_uint4(hp0[0], hp1[0], hp0[1], hp1[1]);
        uint4 u1 = make_uint4(hp0[2], hp1[2], hp0[3], hp1[3]);
        short8_t bk0 = *(short8_t*)&u0;
        short8_t bk1 = *(short8_t*)&u1;

        // layer 2
        #pragma unroll
        for (int mt = 0; mt < 4; ++mt) {
            f32x4 a = mfma16(w[4 + mt * 2], bk0, zero);
            a = mfma16(w[5 + mt * 2], bk1, a);
            hp0[mt] = cvtpk(fmaxf(a[0], 0.0f), fmaxf(a[1], 0.0f));
            hp1[mt] = cvtpk(fmaxf(a[2], 0.0f), fmaxf(a[3], 0.0f));
        }
        u0 = make_uint4(hp0[0], hp1[0], hp0[1], hp1[1]);
        u1 = make_uint4(hp0[2], hp1[2], hp0[3], hp1[3]);
        bk0 = *(short8_t*)&u0;
        bk1 = *(short8_t*)&u1;

        // layer 3
        f32x4 a3 = mfma16(w[12], bk0, zero);
        a3 = mfma16(w[13], bk1, a3);

        // weight by wb and reduce over the 8 corners (eval low 3 bits)
        float v0 = wbv * a3[0], v1 = wbv * a3[1], v2 = wbv * a3[2], v3 = wbv * a3[3];
        #pragma unroll
        for (int s = 1; s < 8; s <<= 1) {
            v0 += __shfl_xor(v0, s);
            v1 += __shfl_xor(v1, s);
            v2 += __shfl_xor(v2, s);
            v3 += __shfl_xor(v3, s);
        }
        if (((lane & 7) == 0) && q < 2) {
            const int p = (blockIdx.x * BLOCK + ev) >> 3;
            ull* op = (ull*)(out + p * 8 + q * 4);
            __builtin_nontemporal_store(
                (ull)__float_as_uint(v0) | ((ull)__float_as_uint(v1) << 32), op);
            __builtin_nontemporal_store(
                (ull)__float_as_uint(v2) | ((ull)__float_as_uint(v3) << 32), op + 1);
        }
    }
}

// ---- R13 single-kernel fallback (ws too small for the two-pass split) ----
template<bool BT>
__global__ __launch_bounds__(BLOCK, 5)
void ngp_mfma(const float*  __restrict__ xyz,
              const float2* __restrict__ tbl,
              const int*    __restrict__ boundp,
              const unsigned* __restrict__ wsw,
              float*        __restrict__ out,
              int ntiles)
{
    __shared__ __align__(16) unsigned lds[4096];
    const int tid  = threadIdx.x;
    const int lane = tid & 63;
    const int wv   = tid >> 6;
    const int col  = lane & 15;
    const int q    = lane >> 4;
    const int swz  = (tid ^ (tid >> 2) ^ (tid >> 4)) & 3;

    const unsigned* __restrict__ tbx = wsw + TOFF;
    const float bnd = (float)boundp[0];
    const float sc  = 0.5f / bnd;
    const f32x4 zero = {0.0f, 0.0f, 0.0f, 0.0f};

    const int ge = blockIdx.x * BLOCK + tid;
    const int pt = ge >> 3;
    const int b  = ge & 7;

    const float cxf = (xyz[pt * 3 + 0] + bnd) * sc * 512.0f;
    const float cyf = (xyz[pt * 3 + 1] + bnd) * sc * 512.0f;
    const float czf = (xyz[pt * 3 + 2] + bnd) * sc * 512.0f;
    const float c0x = fminf(fmaxf(floorf(cxf), 0.0f), 511.0f);
    const float c0y = fminf(fmaxf(floorf(cyf), 0.0f), 511.0f);
    const float c0z = fminf(fmaxf(floorf(czf), 0.0f), 511.0f);
    const float frx = cxf - c0x;
    const float fry = cyf - c0y;
    const float frz = czf - c0z;

    const unsigned kx = (unsigned)c0x + (unsigned)(b & 1);
    const unsigned ky = (unsigned)c0y + (unsigned)((b >> 1) & 1);
    const unsigned kz = (unsigned)c0z + (unsigned)((b >> 2) & 1);

    const float wb = ((b & 1) ? frx : 1.0f - frx)
                   * ((b & 2) ? fry : 1.0f - fry)
                   * ((b & 4) ? frz : 1.0f - frz);

    const unsigned kyp = ky * cP1;
    const unsigned kzp = kz * cP2;
    const unsigned X   = kx ^ kyp ^ kzp;
    unsigned gfu[11];
    float2   gff[11];
    #pragma unroll
    for (int l = 5; l < 16; ++l) {
        const int s = l - 5;
        if (BT) {
            const unsigned base = (1u << 20) + ((1u << 20) - ((1u << 20) >> s));
            gfu[l - 5] = tbx[base + (X & (kMask >> s))];
        } else {
            const unsigned idx = ((kx << s) ^ (kyp << s) ^ (kzp << s)) & kMask;
            gff[l - 5] = tbl[(size_t)l * kT + idx];
        }
    }

    unsigned gH[2][8];
    float2   gHf[2][8];
    #pragma unroll
    for (int l = 3; l < 5; ++l) {
        const int d = 5 - l;
        const unsigned qx = kx >> d, qy = ky >> d, qz = kz >> d;
        const unsigned hy0 = qy * cP1, hy1 = hy0 + cP1;
        const unsigned hz0 = qz * cP2, hz1 = hz0 + cP2;
        const unsigned x1u = qx + 1u;
        unsigned hidx[8];
        hidx[0] = (qx  ^ hy0 ^ hz0) & kMask;  hidx[1] = (x1u ^ hy0 ^ hz0) & kMask;
        hidx[2] = (qx  ^ hy1 ^ hz0) & kMask;  hidx[3] = (x1u ^ hy1 ^ hz0) & kMask;
        hidx[4] = (qx  ^ hy0 ^ hz1) & kMask;  hidx[5] = (x1u ^ hy0 ^ hz1) & kMask;
        hidx[6] = (qx  ^ hy1 ^ hz1) & kMask;  hidx[7] = (x1u ^ hy1 ^ hz1) & kMask;
        if (BT) {
            const unsigned* __restrict__ base = tbx + (size_t)(l - 3) * kT;
            #pragma unroll
            for (int c = 0; c < 8; ++c) gH[l - 3][c] = base[hidx[c]];
        } else {
            const float2* __restrict__ base = tbl + (size_t)l * kT;
            #pragma unroll
            for (int c = 0; c < 8; ++c) gHf[l - 3][c] = base[hidx[c]];
        }
    }

    float2 gc[5];
    #pragma unroll
    for (int l = 0; l < 5; ++l) {
        const int d = 5 - l;
        const unsigned m = (1u << d) - 1u;
        const float inv = 1.0f / (float)(1 << d);
        const unsigned qx = kx >> d, qy = ky >> d, qz = kz >> d;
        const float fx = (float)(kx & m) * inv;
        const float fy = (float)(ky & m) * inv;
        const float fz = (float)(kz & m) * inv;
        float2 g0, g1, g2, g3, g4, g5, g6, g7;
        if (l < 3) {
            const unsigned res = 16u << l;
            const unsigned R = res + 1u, R2 = R * R;
            const unsigned x0 = (qx < res ? qx : res);
            const unsigned x1 = (qx + 1u < res ? qx + 1u : res);
            const unsigned y0 = (qy < res ? qy : res) * R;
            const unsigned y1 = (qy + 1u < res ? qy + 1u : res) * R;
            const unsigned z0 = (qz < res ? qz : res) * R2;
            const unsigned z1 = (qz + 1u < res ? qz + 1u : res) * R2;
            const float2* __restrict__ base = tbl + (size_t)l * kT;
            g0 = base[x0 + y0 + z0]; g1 = base[x1 + y0 + z0];
            g2 = base[x0 + y1 + z0]; g3 = base[x1 + y1 + z0];
            g4 = base[x0 + y0 + z1]; g5 = base[x1 + y0 + z1];
            g6 = base[x0 + y1 + z1]; g7 = base[x1 + y1 + z1];
        } else if (BT) {
            g0 = bf2dec(gH[l - 3][0]); g1 = bf2dec(gH[l - 3][1]);
            g2 = bf2dec(gH[l - 3][2]); g3 = bf2dec(gH[l - 3][3]);
            g4 = bf2dec(gH[l - 3][4]); g5 = bf2dec(gH[l - 3][5]);
            g6 = bf2dec(gH[l - 3][6]); g7 = bf2dec(gH[l - 3][7]);
        } else {
            g0 = gHf[l - 3][0]; g1 = gHf[l - 3][1]; g2 = gHf[l - 3][2]; g3 = gHf[l - 3][3];
            g4 = gHf[l - 3][4]; g5 = gHf[l - 3][5]; g6 = gHf[l - 3][6]; g7 = gHf[l - 3][7];
        }
        const float wx1 = fx, wx0 = 1.0f - fx;
        const float wy1 = fy, wy0 = 1.0f - fy;
        const float wz1 = fz, wz0 = 1.0f - fz;
        const float w00 = wx0 * wy0, w10 = wx1 * wy0, w01 = wx0 * wy1, w11 = wx1 * wy1;
        const float a0 = w00 * wz0, a1 = w10 * wz0, a2 = w01 * wz0, a3 = w11 * wz0;
        const float a4 = w00 * wz1, a5 = w10 * wz1, a6 = w01 * wz1, a7 = w11 * wz1;
        float vx = a0 * g0.x + a1 * g1.x + a2 * g2.x + a3 * g3.x
                 + a4 * g4.x + a5 * g5.x + a6 * g6.x + a7 * g7.x;
        float vy = a0 * g0.y + a1 * g1.y + a2 * g2.y + a3 * g3.y
                 + a4 * g4.y + a5 * g5.y + a6 * g6.y + a7 * g7.y;
        gc[l] = make_float2(vx, vy);
    }

    unsigned xd[16];
    #pragma unroll
    for (int l = 0; l < 5; ++l)
        xd[l] = cvtpk(gc[l].x, gc[l].y);
    #pragma unroll
    for (int l = 5; l < 16; ++l) {
        if (BT) xd[l] = gfu[l - 5];
        else    xd[l] = cvtpk(gff[l - 5].x, gff[l - 5].y);
    }
    {
        uint4* xrow = (uint4*)(lds + tid * 16);
        xrow[swz]     = make_uint4(xd[0],  xd[1],  xd[2],  xd[3]);
        xrow[swz ^ 1] = make_uint4(xd[4],  xd[5],  xd[6],  xd[7]);
        xrow[swz ^ 2] = make_uint4(xd[8],  xd[9],  xd[10], xd[11]);
        xrow[swz ^ 3] = make_uint4(xd[12], xd[13], xd[14], xd[15]);
    }

    asm volatile("s_waitcnt lgkmcnt(0)" ::: "memory");
    __builtin_amdgcn_sched_barrier(0);

    short8_t w[14];
    {
        const short8_t* __restrict__ wfr = (const short8_t*)wsw;
        #pragma unroll
        for (int t = 0; t < 14; ++t) w[t] = wfr[t * 64 + lane];
    }

    #pragma unroll 1
    for (int g = 0; g < 4; ++g) {
        const int ev  = wv * 64 + g * 16 + col;
        const int esw = ((ev ^ (ev >> 2) ^ (ev >> 4)) & 3) ^ q;
        const short8_t xb = *(const short8_t*)(lds + ev * 16 + esw * 4);
        const float wbv = __shfl(wb, g * 16 + col, 64);

        unsigned hp0[4], hp1[4];
        #pragma unroll
        for (int mt = 0; mt < 4; ++mt) {
            f32x4 a = mfma16(w[mt], xb, zero);
            hp0[mt] = cvtpk(fmaxf(a[0], 0.0f), fmaxf(a[1], 0.0f));
            hp1[mt] = cvtpk(fmaxf(a[2], 0.0f), fmaxf(a[3], 0.0f));
        }
        uint4 u0 = make_uint4(hp0[0], hp1[0], hp0[1], hp1[1]);
        uint4 u1 = make_uint4(hp0[2], hp1[2], hp0[3], hp1[3]);
        short8_t bk0 = *(short8_t*)&u0;
        short8_t bk1 = *(short8_t*)&u1;

        #pragma unroll
        for (int mt = 0; mt < 4; ++mt) {
            f32x4 a = mfma16(w[4 + mt * 2], bk0, zero);
            a = mfma16(w[5 + mt * 2], bk1, a);
            hp0[mt] = cvtpk(fmaxf(a[0], 0.0f), fmaxf(a[1], 0.0f));
            hp1[mt] = cvtpk(fmaxf(a[2], 0.0f), fmaxf(a[3], 0.0f));
        }
        u0 = make_uint4(hp0[0], hp1[0], hp0[1], hp1[1]);
        u1 = make_uint4(hp0[2], hp1[2], hp0[3], hp1[3]);
        bk0 = *(short8_t*)&u0;
        bk1 = *(short8_t*)&u1;

        f32x4 a3 = mfma16(w[12], bk0, zero);
        a3 = mfma16(w[13], bk1, a3);

        float v0 = wbv * a3[0], v1 = wbv * a3[1], v2 = wbv * a3[2], v3 = wbv * a3[3];
        #pragma unroll
        for (int s = 1; s < 8; s <<= 1) {
            v0 += __shfl_xor(v0, s);
            v1 += __shfl_xor(v1, s);
            v2 += __shfl_xor(v2, s);
            v3 += __shfl_xor(v3, s);
        }
        if (((lane & 7) == 0) && q < 2) {
            const int p = (blockIdx.x * BLOCK + ev) >> 3;
            *(float4*)(out + p * 8 + q * 4) = make_float4(v0, v1, v2, v3);
        }
    }
}

extern "C" void kernel_launch(void* const* d_in, const int* in_sizes, int n_in,
                              void* d_out, int out_size, void* d_ws, size_t ws_size,
                              hipStream_t stream) {
    const float*  xyz = (const float*)d_in[0];
    const float2* tbl = (const float2*)d_in[1];
    const float*  W0  = (const float*)d_in[2];
    const float*  W1  = (const float*)d_in[3];
    const float*  W2  = (const float*)d_in[4];
    const int*    bnd = (const int*)d_in[5];
    float* out = (float*)d_out;

    const int npts   = in_sizes[0] / 3;
    const int total  = npts * 8;
    const int ntiles = total / BLOCK;

    const bool big2 = (ws_size >= WS_NEED2);
    const bool big  = (ws_size >= WS_NEED);
    const int ncc  = big ? (1 << 19) / 256 : 0;                  // 2048
    const int ncf  = big ? ((1 << 20) - (1 << 9)) / 256 : 0;     // 4094
    const int ncd  = big2 ? (int)((N2 + 255u) / 256u) : 0;       // 1073
    const int nc01 = big2 ? (int)((N01 + 255u) / 256u) : 0;      // 141

    hipLaunchKernelGGL(prep_all, dim3(ncc + ncf + ncd + nc01 + 4), dim3(256),
                       0, stream, W0, W1, W2, tbl, (unsigned*)d_ws,
                       ncc, ncf, ncd, nc01);

    if (big2) {
        hipLaunchKernelGGL(ngp_pa, dim3(total / 256), dim3(256), 0, stream,
                           xyz, bnd, (unsigned*)d_ws);
        hipLaunchKernelGGL(ngp_pb, dim3(ntiles), dim3(BLOCK), 0, stream,
                           xyz, bnd, (const unsigned*)d_ws, out);
    } else if (big) {
        hipLaunchKernelGGL(ngp_mfma<true>, dim3(ntiles), dim3(BLOCK), 0, stream,
                           xyz, tbl, bnd, (const unsigned*)d_ws, out, ntiles);
    } else {
        hipLaunchKernelGGL(ngp_mfma<false>, dim3(ntiles), dim3(BLOCK), 0, stream,
                           xyz, tbl, bnd, (const unsigned*)d_ws, out, ntiles);
    }
}

// Round 5
// 224.006 us; speedup vs baseline: 1.4771x; 1.4771x over previous
//
#include <hip/hip_runtime.h>

// Instant-NGP hash encode (16 levels, F=2) + 32->64->64->8 MLP via MFMA,
// outer trilinear over 8 corners of a 512^3 grid.
//
// R13: phase-split regs, zero barriers, 133us. Law: dur tracks FETCH
//   (L2-miss path), hot random footprint vs 4MB per-XCD L2.
// R14: two-pass level split (pass A: coarse L3/L4 = 4MB bf16; pass B:
//   dense+fine+MLP ~5.4MB). FETCH 312->91MB, pb 92us.
// R15 FAILED: launch_bounds(256,8) on pb strangled the allocator to
//   32 VGPR -> encode state spilled (WRITE 8->189MB, FETCH 508MB, 204us).
//   nt-streams + L0/L1-merge were innocent bystanders.
// R16: revert pb to launch_bounds(256,5) (VGPR ~44, spill-free regime).
//   Keep: nt loads/stores on all streams (xyz, partials, out, prep) so
//   they bypass L2 and don't evict hot tables; merged L0+L1 33^3 grid.

typedef __attribute__((ext_vector_type(8))) short short8_t;
typedef __attribute__((ext_vector_type(4))) float f32x4;
typedef unsigned long long ull;

static constexpr unsigned kT    = 1u << 19;
static constexpr unsigned kMask = kT - 1u;
static constexpr unsigned cP1   = 2654435761u;
static constexpr unsigned cP2   = 805459861u;
static constexpr int      BLOCK = 256;
static constexpr int      TOFF  = 4096;        // d_ws dword offset of tables
static constexpr unsigned D01   = 1u << 21;    // tbx dwords: L0+L1 uint2[33^3]
static constexpr unsigned N01   = 35937u;      // 33^3
static constexpr unsigned D2    = D01 + 72000u;// tbx dwords: L2 dword[65^3]
static constexpr unsigned N2    = 274625u;     // 65^3
static constexpr unsigned PARTO = 2621440u;    // dword offset of partials
static constexpr size_t   WS_NEED  = ((size_t)TOFF + (1u << 21)) * 4;   // 8MB+
static constexpr size_t   WS_NEED2 = ((size_t)PARTO + (1u << 22)) * 4;  // 26MB+

static __device__ __forceinline__ unsigned bf16_rn(float x) {
    unsigned u = __float_as_uint(x);
    return (u + 0x7fffu + ((u >> 16) & 1u)) >> 16;   // round-to-nearest-even
}

static __device__ __forceinline__ float2 bf2dec(unsigned u) {
    return make_float2(__uint_as_float(u << 16),
                       __uint_as_float(u & 0xffff0000u));
}

// packed f32x2 -> bf16x2, RNE (bit-identical to bf16_rn pair). lo in low 16.
static __device__ __forceinline__ unsigned cvtpk(float lo, float hi) {
    unsigned r;
    asm("v_cvt_pk_bf16_f32 %0, %1, %2" : "=v"(r) : "v"(lo), "v"(hi));
    return r;
}

static __device__ __forceinline__ f32x4 mfma16(short8_t a, short8_t b, f32x4 c) {
    return __builtin_amdgcn_mfma_f32_16x16x32_bf16(a, b, c, 0, 0, 0);
}

// ---- fused prep: [0,ncc) coarse bf16; [+ncf) fine compact; [+ncd) dense L2;
// [+nc01) merged L0+L1 grid; tail 4 blocks = weight pre-swizzle.
__global__ __launch_bounds__(256)
void prep_all(const float* __restrict__ W0, const float* __restrict__ W1,
              const float* __restrict__ W2, const float2* __restrict__ tbl,
              unsigned* __restrict__ ws, int ncc, int ncf, int ncd, int nc01)
{
    const int bx = blockIdx.x, tid = threadIdx.x;
    if (bx < ncc) {
        // coarse levels 3,4: fp32x2 -> packed bf16x2 (pairs of entries)
        const int i = bx * 256 + tid;                // < 2^19
        const ull* __restrict__ p = (const ull*)(tbl + (size_t)3 * kT);
        const ull a = __builtin_nontemporal_load(p + 2 * (size_t)i);
        const ull b = __builtin_nontemporal_load(p + 2 * (size_t)i + 1);
        const ull o = (ull)(bf16_rn(__uint_as_float((unsigned)a))
                          | (bf16_rn(__uint_as_float((unsigned)(a >> 32))) << 16))
                    | ((ull)(bf16_rn(__uint_as_float((unsigned)b))
                          | (bf16_rn(__uint_as_float((unsigned)(b >> 32))) << 16)) << 32);
        __builtin_nontemporal_store(o, (ull*)(ws + TOFF) + i);
    } else if (bx < ncc + ncf) {
        // fine level 5+s entry (j<<s) -> compact slot j at fineOff(s)
        const int i = (bx - ncc) * 256 + tid;        // < 2^20 - 2^9
        const unsigned vv = (1u << 20) - 1u - (unsigned)i;
        const int s = __clz((int)vv) - 12;           // 0..10
        const unsigned fo = (1u << 20) - ((1u << 20) >> s);
        const unsigned j = (unsigned)i - fo;
        const ull e = __builtin_nontemporal_load(
            (const ull*)tbl + ((size_t)(5 + s) << 19) + ((size_t)j << s));
        const unsigned o = bf16_rn(__uint_as_float((unsigned)e))
                         | (bf16_rn(__uint_as_float((unsigned)(e >> 32))) << 16);
        __builtin_nontemporal_store(o, ws + TOFF + (1u << 20) + i);
    } else if (bx < ncc + ncf + ncd) {
        // dense level 2: fp32x2 -> bf16x2 dword, contiguous 65^3
        const int i = (bx - ncc - ncf) * 256 + tid;
        if (i < (int)N2) {
            const ull e = __builtin_nontemporal_load(
                (const ull*)tbl + (size_t)2 * kT + i);
            const unsigned o = bf16_rn(__uint_as_float((unsigned)e))
                             | (bf16_rn(__uint_as_float((unsigned)(e >> 32))) << 16);
            __builtin_nontemporal_store(o, ws + TOFF + D2 + i);
        }
    } else if (bx < ncc + ncf + ncd + nc01) {
        // merged L0+L1 grid: per level-1 vertex v (33^3), store
        // (bf16 f0(v), bf16 f1(v)) where f0 = level-0 trilinear at v/2.
        const int i = (bx - ncc - ncf - ncd) * 256 + tid;
        if (i < (int)N01) {
            const int vz = i / 1089;
            const int r  = i - vz * 1089;
            const int vy = r / 33;
            const int vx = r - vy * 33;
            const float2 f1 = tbl[(size_t)kT + i];   // level-1 value (gather)
            const int x0 = vx >> 1, y0 = vy >> 1, z0 = vz >> 1;
            const int x1 = (x0 + 1 > 16) ? 16 : x0 + 1;
            const int y1 = (y0 + 1 > 16) ? 16 : y0 + 1;
            const int z1 = (z0 + 1 > 16) ? 16 : z0 + 1;
            const float fx = (vx & 1) ? 0.5f : 0.0f;
            const float fy = (vy & 1) ? 0.5f : 0.0f;
            const float fz = (vz & 1) ? 0.5f : 0.0f;
            const int Y0 = y0 * 17, Y1 = y1 * 17, Z0 = z0 * 289, Z1 = z1 * 289;
            const float2 g0 = tbl[x0 + Y0 + Z0], g1 = tbl[x1 + Y0 + Z0];
            const float2 g2 = tbl[x0 + Y1 + Z0], g3 = tbl[x1 + Y1 + Z0];
            const float2 g4 = tbl[x0 + Y0 + Z1], g5 = tbl[x1 + Y0 + Z1];
            const float2 g6 = tbl[x0 + Y1 + Z1], g7 = tbl[x1 + Y1 + Z1];
            const float wx1 = fx, wx0 = 1.0f - fx;
            const float wy1 = fy, wy0 = 1.0f - fy;
            const float wz1 = fz, wz0 = 1.0f - fz;
            const float w00 = wx0 * wy0, w10 = wx1 * wy0, w01 = wx0 * wy1, w11 = wx1 * wy1;
            const float a0 = w00 * wz0, a1 = w10 * wz0, a2 = w01 * wz0, a3 = w11 * wz0;
            const float a4 = w00 * wz1, a5 = w10 * wz1, a6 = w01 * wz1, a7 = w11 * wz1;
            const float f0x = a0 * g0.x + a1 * g1.x + a2 * g2.x + a3 * g3.x
                            + a4 * g4.x + a5 * g5.x + a6 * g6.x + a7 * g7.x;
            const float f0y = a0 * g0.y + a1 * g1.y + a2 * g2.y + a3 * g3.y
                            + a4 * g4.y + a5 * g5.y + a6 * g6.y + a7 * g7.y;
            const ull o = (ull)cvtpk(f0x, f0y) | ((ull)cvtpk(f1.x, f1.y) << 32);
            __builtin_nontemporal_store(o, (ull*)(ws + TOFF + D01) + i);
        }
    } else {
        // weights: A-frag order, bf16 RNE. tiles 0..3 = W0; 4..11 = W1
        // (mt=(t-4)>>1, kt=(t-4)&1, K pi-permuted); 12..13 = W2 (cols>=8 zero)
        const int t = (bx - ncc - ncf - ncd - nc01) * 4 + (tid >> 6);
        if (t >= 14) return;
        const int lane = tid & 63;
        const int n = lane & 15, q = lane >> 4;
        unsigned hi[4];
        #pragma unroll
        for (int d = 0; d < 4; ++d) {
            unsigned h2[2];
            #pragma unroll
            for (int s = 0; s < 2; ++s) {
                const int j = d * 2 + s;
                float v;
                if (t < 4) {
                    v = W0[(q * 8 + j) * 64 + t * 16 + n];
                } else {
                    const int kp = (j < 4) ? (q * 4 + j) : (16 + q * 4 + (j - 4));
                    if (t < 12) v = W1[(((t - 4) & 1) * 32 + kp) * 64 + ((t - 4) >> 1) * 16 + n];
                    else        v = (n < 8) ? W2[((t - 12) * 32 + kp) * 8 + n] : 0.0f;
                }
                h2[s] = bf16_rn(v);
            }
            hi[d] = h2[0] | (h2[1] << 16);
        }
        ((uint4*)ws)[t * 64 + lane] = make_uint4(hi[0], hi[1], hi[2], hi[3]);
    }
}

// ---- pass A: coarse levels 3,4 only (4MB working set = per-XCD L2).
// Streams (xyz in, partial out) are non-temporal: tables own the L2.
__global__ __launch_bounds__(256, 8)
void ngp_pa(const float* __restrict__ xyz, const int* __restrict__ boundp,
            unsigned* __restrict__ ws)
{
    const int tid = threadIdx.x;
    const int ge  = blockIdx.x * 256 + tid;
    const int pt  = ge >> 3;
    const int b   = ge & 7;

    const float bnd = (float)boundp[0];
    const float sc  = 0.5f / bnd;
    const float pxv = __builtin_nontemporal_load(xyz + pt * 3 + 0);
    const float pyv = __builtin_nontemporal_load(xyz + pt * 3 + 1);
    const float pzv = __builtin_nontemporal_load(xyz + pt * 3 + 2);
    const float cxf = (pxv + bnd) * sc * 512.0f;
    const float cyf = (pyv + bnd) * sc * 512.0f;
    const float czf = (pzv + bnd) * sc * 512.0f;
    const float c0x = fminf(fmaxf(floorf(cxf), 0.0f), 511.0f);
    const float c0y = fminf(fmaxf(floorf(cyf), 0.0f), 511.0f);
    const float c0z = fminf(fmaxf(floorf(czf), 0.0f), 511.0f);
    const unsigned kx = (unsigned)c0x + (unsigned)(b & 1);
    const unsigned ky = (unsigned)c0y + (unsigned)((b >> 1) & 1);
    const unsigned kz = (unsigned)c0z + (unsigned)((b >> 2) & 1);

    const unsigned* __restrict__ tbx = ws + TOFF;
    unsigned gH[2][8];
    #pragma unroll
    for (int l = 3; l < 5; ++l) {
        const int d = 5 - l;
        const unsigned qx = kx >> d, qy = ky >> d, qz = kz >> d;
        const unsigned hy0 = qy * cP1, hy1 = hy0 + cP1;
        const unsigned hz0 = qz * cP2, hz1 = hz0 + cP2;
        const unsigned x1u = qx + 1u;
        unsigned hidx[8];
        hidx[0] = (qx  ^ hy0 ^ hz0) & kMask;  hidx[1] = (x1u ^ hy0 ^ hz0) & kMask;
        hidx[2] = (qx  ^ hy1 ^ hz0) & kMask;  hidx[3] = (x1u ^ hy1 ^ hz0) & kMask;
        hidx[4] = (qx  ^ hy0 ^ hz1) & kMask;  hidx[5] = (x1u ^ hy0 ^ hz1) & kMask;
        hidx[6] = (qx  ^ hy1 ^ hz1) & kMask;  hidx[7] = (x1u ^ hy1 ^ hz1) & kMask;
        const unsigned* __restrict__ base = tbx + (size_t)(l - 3) * kT;
        #pragma unroll
        for (int c = 0; c < 8; ++c) gH[l - 3][c] = base[hidx[c]];
    }

    unsigned xd34[2];
    #pragma unroll
    for (int l = 3; l < 5; ++l) {
        const int d = 5 - l;
        const unsigned m = (1u << d) - 1u;
        const float inv = 1.0f / (float)(1 << d);
        const float fx = (float)(kx & m) * inv;
        const float fy = (float)(ky & m) * inv;
        const float fz = (float)(kz & m) * inv;
        const float2 g0 = bf2dec(gH[l - 3][0]), g1 = bf2dec(gH[l - 3][1]);
        const float2 g2 = bf2dec(gH[l - 3][2]), g3 = bf2dec(gH[l - 3][3]);
        const float2 g4 = bf2dec(gH[l - 3][4]), g5 = bf2dec(gH[l - 3][5]);
        const float2 g6 = bf2dec(gH[l - 3][6]), g7 = bf2dec(gH[l - 3][7]);
        const float wx1 = fx, wx0 = 1.0f - fx;
        const float wy1 = fy, wy0 = 1.0f - fy;
        const float wz1 = fz, wz0 = 1.0f - fz;
        const float w00 = wx0 * wy0, w10 = wx1 * wy0, w01 = wx0 * wy1, w11 = wx1 * wy1;
        const float a0 = w00 * wz0, a1 = w10 * wz0, a2 = w01 * wz0, a3 = w11 * wz0;
        const float a4 = w00 * wz1, a5 = w10 * wz1, a6 = w01 * wz1, a7 = w11 * wz1;
        const float vx = a0 * g0.x + a1 * g1.x + a2 * g2.x + a3 * g3.x
                       + a4 * g4.x + a5 * g5.x + a6 * g6.x + a7 * g7.x;
        const float vy = a0 * g0.y + a1 * g1.y + a2 * g2.y + a3 * g3.y
                       + a4 * g4.y + a5 * g5.y + a6 * g6.y + a7 * g7.y;
        xd34[l - 3] = cvtpk(vx, vy);
    }
    const ull o = (ull)xd34[0] | ((ull)xd34[1] << 32);
    __builtin_nontemporal_store(o, (ull*)(ws + PARTO) + ge);
}

// ---- pass B: dense (L01 merged + L2) + fine + partial + MLP. Hot ~5.4MB,
// all streams non-temporal. launch_bounds(256,5): spill-free VGPR regime.
__global__ __launch_bounds__(BLOCK, 5)
void ngp_pb(const float*  __restrict__ xyz,
            const int*    __restrict__ boundp,
            const unsigned* __restrict__ wsw,
            float*        __restrict__ out)
{
    // LDS: x only. row = eval (16 dw = 32 bf16 feats), quad XOR-swizzled.
    __shared__ __align__(16) unsigned lds[4096];
    const int tid  = threadIdx.x;
    const int lane = tid & 63;
    const int wv   = tid >> 6;
    const int col  = lane & 15;
    const int q    = lane >> 4;
    const int swz  = (tid ^ (tid >> 2) ^ (tid >> 4)) & 3;

    const unsigned* __restrict__ tbx = wsw + TOFF;
    const float bnd = (float)boundp[0];
    const float sc  = 0.5f / bnd;
    const f32x4 zero = {0.0f, 0.0f, 0.0f, 0.0f};

    // ================= encode (no weights live) =================
    const int ge = blockIdx.x * BLOCK + tid;
    const int pt = ge >> 3;
    const int b  = ge & 7;

    const float pxv = __builtin_nontemporal_load(xyz + pt * 3 + 0);
    const float pyv = __builtin_nontemporal_load(xyz + pt * 3 + 1);
    const float pzv = __builtin_nontemporal_load(xyz + pt * 3 + 2);
    const float cxf = (pxv + bnd) * sc * 512.0f;
    const float cyf = (pyv + bnd) * sc * 512.0f;
    const float czf = (pzv + bnd) * sc * 512.0f;
    const float c0x = fminf(fmaxf(floorf(cxf), 0.0f), 511.0f);
    const float c0y = fminf(fmaxf(floorf(cyf), 0.0f), 511.0f);
    const float c0z = fminf(fmaxf(floorf(czf), 0.0f), 511.0f);
    const float frx = cxf - c0x;
    const float fry = cyf - c0y;
    const float frz = czf - c0z;

    const unsigned kx = (unsigned)c0x + (unsigned)(b & 1);
    const unsigned ky = (unsigned)c0y + (unsigned)((b >> 1) & 1);
    const unsigned kz = (unsigned)c0z + (unsigned)((b >> 2) & 1);

    const float wb = ((b & 1) ? frx : 1.0f - frx)
                   * ((b & 2) ? fry : 1.0f - fry)
                   * ((b & 4) ? frz : 1.0f - frz);

    // fine levels (l=5..15): frac==0, single gather each (compacted).
    const unsigned kyp = ky * cP1;
    const unsigned kzp = kz * cP2;
    const unsigned X   = kx ^ kyp ^ kzp;
    unsigned gfu[11];
    #pragma unroll
    for (int l = 5; l < 16; ++l) {
        const int s = l - 5;
        const unsigned base = (1u << 20) + ((1u << 20) - ((1u << 20) >> s));
        gfu[l - 5] = tbx[base + (X & (kMask >> s))];
    }

    // coarse partial (written by pass A): non-temporal stream read
    const ull pv = __builtin_nontemporal_load((const ull*)(wsw + PARTO) + ge);

    unsigned xd[16];
    // merged levels 0+1 on the 33^3 level-1 grid (4 feats/vertex)
    {
        const unsigned qx = kx >> 4, qy = ky >> 4, qz = kz >> 4;
        const float fx = (float)(kx & 15u) * 0.0625f;
        const float fy = (float)(ky & 15u) * 0.0625f;
        const float fz = (float)(kz & 15u) * 0.0625f;
        const unsigned x0 = qx, x1 = (qx + 1u > 32u) ? 32u : qx + 1u;
        const unsigned y0 = qy * 33u, y1 = ((qy + 1u > 32u) ? 32u : qy + 1u) * 33u;
        const unsigned z0 = qz * 1089u, z1 = ((qz + 1u > 32u) ? 32u : qz + 1u) * 1089u;
        const uint2* __restrict__ b01 = (const uint2*)(tbx + D01);
        const uint2 h0 = b01[x0 + y0 + z0], h1 = b01[x1 + y0 + z0];
        const uint2 h2 = b01[x0 + y1 + z0], h3 = b01[x1 + y1 + z0];
        const uint2 h4 = b01[x0 + y0 + z1], h5 = b01[x1 + y0 + z1];
        const uint2 h6 = b01[x0 + y1 + z1], h7 = b01[x1 + y1 + z1];
        const float wx1 = fx, wx0 = 1.0f - fx;
        const float wy1 = fy, wy0 = 1.0f - fy;
        const float wz1 = fz, wz0 = 1.0f - fz;
        const float w00 = wx0 * wy0, w10 = wx1 * wy0, w01 = wx0 * wy1, w11 = wx1 * wy1;
        const float a0 = w00 * wz0, a1 = w10 * wz0, a2 = w01 * wz0, a3 = w11 * wz0;
        const float a4 = w00 * wz1, a5 = w10 * wz1, a6 = w01 * wz1, a7 = w11 * wz1;
        float f0x, f0y, f1x, f1y;
        float2 d;
        d = bf2dec(h0.x); f0x  = a0 * d.x; f0y  = a0 * d.y;
        d = bf2dec(h0.y); f1x  = a0 * d.x; f1y  = a0 * d.y;
        d = bf2dec(h1.x); f0x += a1 * d.x; f0y += a1 * d.y;
        d = bf2dec(h1.y); f1x += a1 * d.x; f1y += a1 * d.y;
        d = bf2dec(h2.x); f0x += a2 * d.x; f0y += a2 * d.y;
        d = bf2dec(h2.y); f1x += a2 * d.x; f1y += a2 * d.y;
        d = bf2dec(h3.x); f0x += a3 * d.x; f0y += a3 * d.y;
        d = bf2dec(h3.y); f1x += a3 * d.x; f1y += a3 * d.y;
        d = bf2dec(h4.x); f0x += a4 * d.x; f0y += a4 * d.y;
        d = bf2dec(h4.y); f1x += a4 * d.x; f1y += a4 * d.y;
        d = bf2dec(h5.x); f0x += a5 * d.x; f0y += a5 * d.y;
        d = bf2dec(h5.y); f1x += a5 * d.x; f1y += a5 * d.y;
        d = bf2dec(h6.x); f0x += a6 * d.x; f0y += a6 * d.y;
        d = bf2dec(h6.y); f1x += a6 * d.x; f1y += a6 * d.y;
        d = bf2dec(h7.x); f0x += a7 * d.x; f0y += a7 * d.y;
        d = bf2dec(h7.y); f1x += a7 * d.x; f1y += a7 * d.y;
        xd[0] = cvtpk(f0x, f0y);
        xd[1] = cvtpk(f1x, f1y);
    }
    // dense level 2 (65^3 bf16)
    {
        const unsigned qx = kx >> 3, qy = ky >> 3, qz = kz >> 3;
        const float fx = (float)(kx & 7u) * 0.125f;
        const float fy = (float)(ky & 7u) * 0.125f;
        const float fz = (float)(kz & 7u) * 0.125f;
        const unsigned x0 = qx, x1 = (qx + 1u > 64u) ? 64u : qx + 1u;
        const unsigned y0 = qy * 65u, y1 = ((qy + 1u > 64u) ? 64u : qy + 1u) * 65u;
        const unsigned z0 = qz * 4225u, z1 = ((qz + 1u > 64u) ? 64u : qz + 1u) * 4225u;
        const unsigned* __restrict__ b2 = tbx + D2;
        const float2 g0 = bf2dec(b2[x0 + y0 + z0]), g1 = bf2dec(b2[x1 + y0 + z0]);
        const float2 g2 = bf2dec(b2[x0 + y1 + z0]), g3 = bf2dec(b2[x1 + y1 + z0]);
        const float2 g4 = bf2dec(b2[x0 + y0 + z1]), g5 = bf2dec(b2[x1 + y0 + z1]);
        const float2 g6 = bf2dec(b2[x0 + y1 + z1]), g7 = bf2dec(b2[x1 + y1 + z1]);
        const float wx1 = fx, wx0 = 1.0f - fx;
        const float wy1 = fy, wy0 = 1.0f - fy;
        const float wz1 = fz, wz0 = 1.0f - fz;
        const float w00 = wx0 * wy0, w10 = wx1 * wy0, w01 = wx0 * wy1, w11 = wx1 * wy1;
        const float a0 = w00 * wz0, a1 = w10 * wz0, a2 = w01 * wz0, a3 = w11 * wz0;
        const float a4 = w00 * wz1, a5 = w10 * wz1, a6 = w01 * wz1, a7 = w11 * wz1;
        const float vx = a0 * g0.x + a1 * g1.x + a2 * g2.x + a3 * g3.x
                       + a4 * g4.x + a5 * g5.x + a6 * g6.x + a7 * g7.x;
        const float vy = a0 * g0.y + a1 * g1.y + a2 * g2.y + a3 * g3.y
                       + a4 * g4.y + a5 * g5.y + a6 * g6.y + a7 * g7.y;
        xd[2] = cvtpk(vx, vy);
    }
    xd[3] = (unsigned)pv;
    xd[4] = (unsigned)(pv >> 32);
    #pragma unroll
    for (int l = 5; l < 16; ++l) xd[l] = gfu[l - 5];

    // swizzled x write: quad k at position k^swz (row = tid)
    {
        uint4* xrow = (uint4*)(lds + tid * 16);
        xrow[swz]     = make_uint4(xd[0],  xd[1],  xd[2],  xd[3]);
        xrow[swz ^ 1] = make_uint4(xd[4],  xd[5],  xd[6],  xd[7]);
        xrow[swz ^ 2] = make_uint4(xd[8],  xd[9],  xd[10], xd[11]);
        xrow[swz ^ 3] = make_uint4(xd[12], xd[13], xd[14], xd[15]);
    }

    // x exchange is within-wave (ev = wv*64+...) -> wave-local fence only.
    // Memory clobber pins the weight loads below (phase-split pressure).
    asm volatile("s_waitcnt lgkmcnt(0)" ::: "memory");
    __builtin_amdgcn_sched_barrier(0);

    // ---- weights -> 56 VGPRs (same addresses all waves: L1/L2 broadcast)
    short8_t w[14];
    {
        const short8_t* __restrict__ wfr = (const short8_t*)wsw;
        #pragma unroll
        for (int t = 0; t < 14; ++t) w[t] = wfr[t * 64 + lane];
    }

    // ================= MLP (transposed MFMA, weights in regs) =========
    #pragma unroll 1
    for (int g = 0; g < 4; ++g) {
        const int ev  = wv * 64 + g * 16 + col;
        const int esw = ((ev ^ (ev >> 2) ^ (ev >> 4)) & 3) ^ q;
        const short8_t xb = *(const short8_t*)(lds + ev * 16 + esw * 4);
        const float wbv = __shfl(wb, g * 16 + col, 64);

        unsigned hp0[4], hp1[4];
        // layer 1
        #pragma unroll
        for (int mt = 0; mt < 4; ++mt) {
            f32x4 a = mfma16(w[mt], xb, zero);
            hp0[mt] = cvtpk(fmaxf(a[0], 0.0f), fmaxf(a[1], 0.0f));
            hp1[mt] = cvtpk(fmaxf(a[2], 0.0f), fmaxf(a[3], 0.0f));
        }
        uint4 u0 = make_uint4(hp0[0], hp1[0], hp0[1], hp1[1]);
        uint4 u1 = make_uint4(hp0[2], hp1[2], hp0[3], hp1[3]);
        short8_t bk0 = *(short8_t*)&u0;
        short8_t bk1 = *(short8_t*)&u1;

        // layer 2
        #pragma unroll
        for (int mt = 0; mt < 4; ++mt) {
            f32x4 a = mfma16(w[4 + mt * 2], bk0, zero);
            a = mfma16(w[5 + mt * 2], bk1, a);
            hp0[mt] = cvtpk(fmaxf(a[0], 0.0f), fmaxf(a[1], 0.0f));
            hp1[mt] = cvtpk(fmaxf(a[2], 0.0f), fmaxf(a[3], 0.0f));
        }
        u0 = make_uint4(hp0[0], hp1[0], hp0[1], hp1[1]);
        u1 = make_uint4(hp0[2], hp1[2], hp0[3], hp1[3]);
        bk0 = *(short8_t*)&u0;
        bk1 = *(short8_t*)&u1;

        // layer 3
        f32x4 a3 = mfma16(w[12], bk0, zero);
        a3 = mfma16(w[13], bk1, a3);

        // weight by wb and reduce over the 8 corners (eval low 3 bits)
        float v0 = wbv * a3[0], v1 = wbv * a3[1], v2 = wbv * a3[2], v3 = wbv * a3[3];
        #pragma unroll
        for (int s = 1; s < 8; s <<= 1) {
            v0 += __shfl_xor(v0, s);
            v1 += __shfl_xor(v1, s);
            v2 += __shfl_xor(v2, s);
            v3 += __shfl_xor(v3, s);
        }
        if (((lane & 7) == 0) && q < 2) {
            const int p = (blockIdx.x * BLOCK + ev) >> 3;
            ull* op = (ull*)(out + p * 8 + q * 4);
            __builtin_nontemporal_store(
                (ull)__float_as_uint(v0) | ((ull)__float_as_uint(v1) << 32), op);
            __builtin_nontemporal_store(
                (ull)__float_as_uint(v2) | ((ull)__float_as_uint(v3) << 32), op + 1);
        }
    }
}

// ---- R13 single-kernel fallback (ws too small for the two-pass split) ----
template<bool BT>
__global__ __launch_bounds__(BLOCK, 5)
void ngp_mfma(const float*  __restrict__ xyz,
              const float2* __restrict__ tbl,
              const int*    __restrict__ boundp,
              const unsigned* __restrict__ wsw,
              float*        __restrict__ out,
              int ntiles)
{
    __shared__ __align__(16) unsigned lds[4096];
    const int tid  = threadIdx.x;
    const int lane = tid & 63;
    const int wv   = tid >> 6;
    const int col  = lane & 15;
    const int q    = lane >> 4;
    const int swz  = (tid ^ (tid >> 2) ^ (tid >> 4)) & 3;

    const unsigned* __restrict__ tbx = wsw + TOFF;
    const float bnd = (float)boundp[0];
    const float sc  = 0.5f / bnd;
    const f32x4 zero = {0.0f, 0.0f, 0.0f, 0.0f};

    const int ge = blockIdx.x * BLOCK + tid;
    const int pt = ge >> 3;
    const int b  = ge & 7;

    const float cxf = (xyz[pt * 3 + 0] + bnd) * sc * 512.0f;
    const float cyf = (xyz[pt * 3 + 1] + bnd) * sc * 512.0f;
    const float czf = (xyz[pt * 3 + 2] + bnd) * sc * 512.0f;
    const float c0x = fminf(fmaxf(floorf(cxf), 0.0f), 511.0f);
    const float c0y = fminf(fmaxf(floorf(cyf), 0.0f), 511.0f);
    const float c0z = fminf(fmaxf(floorf(czf), 0.0f), 511.0f);
    const float frx = cxf - c0x;
    const float fry = cyf - c0y;
    const float frz = czf - c0z;

    const unsigned kx = (unsigned)c0x + (unsigned)(b & 1);
    const unsigned ky = (unsigned)c0y + (unsigned)((b >> 1) & 1);
    const unsigned kz = (unsigned)c0z + (unsigned)((b >> 2) & 1);

    const float wb = ((b & 1) ? frx : 1.0f - frx)
                   * ((b & 2) ? fry : 1.0f - fry)
                   * ((b & 4) ? frz : 1.0f - frz);

    const unsigned kyp = ky * cP1;
    const unsigned kzp = kz * cP2;
    const unsigned X   = kx ^ kyp ^ kzp;
    unsigned gfu[11];
    float2   gff[11];
    #pragma unroll
    for (int l = 5; l < 16; ++l) {
        const int s = l - 5;
        if (BT) {
            const unsigned base = (1u << 20) + ((1u << 20) - ((1u << 20) >> s));
            gfu[l - 5] = tbx[base + (X & (kMask >> s))];
        } else {
            const unsigned idx = ((kx << s) ^ (kyp << s) ^ (kzp << s)) & kMask;
            gff[l - 5] = tbl[(size_t)l * kT + idx];
        }
    }

    unsigned gH[2][8];
    float2   gHf[2][8];
    #pragma unroll
    for (int l = 3; l < 5; ++l) {
        const int d = 5 - l;
        const unsigned qx = kx >> d, qy = ky >> d, qz = kz >> d;
        const unsigned hy0 = qy * cP1, hy1 = hy0 + cP1;
        const unsigned hz0 = qz * cP2, hz1 = hz0 + cP2;
        const unsigned x1u = qx + 1u;
        unsigned hidx[8];
        hidx[0] = (qx  ^ hy0 ^ hz0) & kMask;  hidx[1] = (x1u ^ hy0 ^ hz0) & kMask;
        hidx[2] = (qx  ^ hy1 ^ hz0) & kMask;  hidx[3] = (x1u ^ hy1 ^ hz0) & kMask;
        hidx[4] = (qx  ^ hy0 ^ hz1) & kMask;  hidx[5] = (x1u ^ hy0 ^ hz1) & kMask;
        hidx[6] = (qx  ^ hy1 ^ hz1) & kMask;  hidx[7] = (x1u ^ hy1 ^ hz1) & kMask;
        if (BT) {
            const unsigned* __restrict__ base = tbx + (size_t)(l - 3) * kT;
            #pragma unroll
            for (int c = 0; c < 8; ++c) gH[l - 3][c] = base[hidx[c]];
        } else {
            const float2* __restrict__ base = tbl + (size_t)l * kT;
            #pragma unroll
            for (int c = 0; c < 8; ++c) gHf[l - 3][c] = base[hidx[c]];
        }
    }

    float2 gc[5];
    #pragma unroll
    for (int l = 0; l < 5; ++l) {
        const int d = 5 - l;
        const unsigned m = (1u << d) - 1u;
        const float inv = 1.0f / (float)(1 << d);
        const unsigned qx = kx >> d, qy = ky >> d, qz = kz >> d;
        const float fx = (float)(kx & m) * inv;
        const float fy = (float)(ky & m) * inv;
        const float fz = (float)(kz & m) * inv;
        float2 g0, g1, g2, g3, g4, g5, g6, g7;
        if (l < 3) {
            const unsigned res = 16u << l;
            const unsigned R = res + 1u, R2 = R * R;
            const unsigned x0 = (qx < res ? qx : res);
            const unsigned x1 = (qx + 1u < res ? qx + 1u : res);
            const unsigned y0 = (qy < res ? qy : res) * R;
            const unsigned y1 = (qy + 1u < res ? qy + 1u : res) * R;
            const unsigned z0 = (qz < res ? qz : res) * R2;
            const unsigned z1 = (qz + 1u < res ? qz + 1u : res) * R2;
            const float2* __restrict__ base = tbl + (size_t)l * kT;
            g0 = base[x0 + y0 + z0]; g1 = base[x1 + y0 + z0];
            g2 = base[x0 + y1 + z0]; g3 = base[x1 + y1 + z0];
            g4 = base[x0 + y0 + z1]; g5 = base[x1 + y0 + z1];
            g6 = base[x0 + y1 + z1]; g7 = base[x1 + y1 + z1];
        } else if (BT) {
            g0 = bf2dec(gH[l - 3][0]); g1 = bf2dec(gH[l - 3][1]);
            g2 = bf2dec(gH[l - 3][2]); g3 = bf2dec(gH[l - 3][3]);
            g4 = bf2dec(gH[l - 3][4]); g5 = bf2dec(gH[l - 3][5]);
            g6 = bf2dec(gH[l - 3][6]); g7 = bf2dec(gH[l - 3][7]);
        } else {
            g0 = gHf[l - 3][0]; g1 = gHf[l - 3][1]; g2 = gHf[l - 3][2]; g3 = gHf[l - 3][3];
            g4 = gHf[l - 3][4]; g5 = gHf[l - 3][5]; g6 = gHf[l - 3][6]; g7 = gHf[l - 3][7];
        }
        const float wx1 = fx, wx0 = 1.0f - fx;
        const float wy1 = fy, wy0 = 1.0f - fy;
        const float wz1 = fz, wz0 = 1.0f - fz;
        const float w00 = wx0 * wy0, w10 = wx1 * wy0, w01 = wx0 * wy1, w11 = wx1 * wy1;
        const float a0 = w00 * wz0, a1 = w10 * wz0, a2 = w01 * wz0, a3 = w11 * wz0;
        const float a4 = w00 * wz1, a5 = w10 * wz1, a6 = w01 * wz1, a7 = w11 * wz1;
        float vx = a0 * g0.x + a1 * g1.x + a2 * g2.x + a3 * g3.x
                 + a4 * g4.x + a5 * g5.x + a6 * g6.x + a7 * g7.x;
        float vy = a0 * g0.y + a1 * g1.y + a2 * g2.y + a3 * g3.y
                 + a4 * g4.y + a5 * g5.y + a6 * g6.y + a7 * g7.y;
        gc[l] = make_float2(vx, vy);
    }

    unsigned xd[16];
    #pragma unroll
    for (int l = 0; l < 5; ++l)
        xd[l] = cvtpk(gc[l].x, gc[l].y);
    #pragma unroll
    for (int l = 5; l < 16; ++l) {
        if (BT) xd[l] = gfu[l - 5];
        else    xd[l] = cvtpk(gff[l - 5].x, gff[l - 5].y);
    }
    {
        uint4* xrow = (uint4*)(lds + tid * 16);
        xrow[swz]     = make_uint4(xd[0],  xd[1],  xd[2],  xd[3]);
        xrow[swz ^ 1] = make_uint4(xd[4],  xd[5],  xd[6],  xd[7]);
        xrow[swz ^ 2] = make_uint4(xd[8],  xd[9],  xd[10], xd[11]);
        xrow[swz ^ 3] = make_uint4(xd[12], xd[13], xd[14], xd[15]);
    }

    asm volatile("s_waitcnt lgkmcnt(0)" ::: "memory");
    __builtin_amdgcn_sched_barrier(0);

    short8_t w[14];
    {
        const short8_t* __restrict__ wfr = (const short8_t*)wsw;
        #pragma unroll
        for (int t = 0; t < 14; ++t) w[t] = wfr[t * 64 + lane];
    }

    #pragma unroll 1
    for (int g = 0; g < 4; ++g) {
        const int ev  = wv * 64 + g * 16 + col;
        const int esw = ((ev ^ (ev >> 2) ^ (ev >> 4)) & 3) ^ q;
        const short8_t xb = *(const short8_t*)(lds + ev * 16 + esw * 4);
        const float wbv = __shfl(wb, g * 16 + col, 64);

        unsigned hp0[4], hp1[4];
        #pragma unroll
        for (int mt = 0; mt < 4; ++mt) {
            f32x4 a = mfma16(w[mt], xb, zero);
            hp0[mt] = cvtpk(fmaxf(a[0], 0.0f), fmaxf(a[1], 0.0f));
            hp1[mt] = cvtpk(fmaxf(a[2], 0.0f), fmaxf(a[3], 0.0f));
        }
        uint4 u0 = make_uint4(hp0[0], hp1[0], hp0[1], hp1[1]);
        uint4 u1 = make_uint4(hp0[2], hp1[2], hp0[3], hp1[3]);
        short8_t bk0 = *(short8_t*)&u0;
        short8_t bk1 = *(short8_t*)&u1;

        #pragma unroll
        for (int mt = 0; mt < 4; ++mt) {
            f32x4 a = mfma16(w[4 + mt * 2], bk0, zero);
            a = mfma16(w[5 + mt * 2], bk1, a);
            hp0[mt] = cvtpk(fmaxf(a[0], 0.0f), fmaxf(a[1], 0.0f));
            hp1[mt] = cvtpk(fmaxf(a[2], 0.0f), fmaxf(a[3], 0.0f));
        }
        u0 = make_uint4(hp0[0], hp1[0], hp0[1], hp1[1]);
        u1 = make_uint4(hp0[2], hp1[2], hp0[3], hp1[3]);
        bk0 = *(short8_t*)&u0;
        bk1 = *(short8_t*)&u1;

        f32x4 a3 = mfma16(w[12], bk0, zero);
        a3 = mfma16(w[13], bk1, a3);

        float v0 = wbv * a3[0], v1 = wbv * a3[1], v2 = wbv * a3[2], v3 = wbv * a3[3];
        #pragma unroll
        for (int s = 1; s < 8; s <<= 1) {
            v0 += __shfl_xor(v0, s);
            v1 += __shfl_xor(v1, s);
            v2 += __shfl_xor(v2, s);
            v3 += __shfl_xor(v3, s);
        }
        if (((lane & 7) == 0) && q < 2) {
            const int p = (blockIdx.x * BLOCK + ev) >> 3;
            *(float4*)(out + p * 8 + q * 4) = make_float4(v0, v1, v2, v3);
        }
    }
}

extern "C" void kernel_launch(void* const* d_in, const int* in_sizes, int n_in,
                              void* d_out, int out_size, void* d_ws, size_t ws_size,
                              hipStream_t stream) {
    const float*  xyz = (const float*)d_in[0];
    const float2* tbl = (const float2*)d_in[1];
    const float*  W0  = (const float*)d_in[2];
    const float*  W1  = (const float*)d_in[3];
    const float*  W2  = (const float*)d_in[4];
    const int*    bnd = (const int*)d_in[5];
    float* out = (float*)d_out;

    const int npts   = in_sizes[0] / 3;
    const int total  = npts * 8;
    const int ntiles = total / BLOCK;

    const bool big2 = (ws_size >= WS_NEED2);
    const bool big  = (ws_size >= WS_NEED);
    const int ncc  = big ? (1 << 19) / 256 : 0;                  // 2048
    const int ncf  = big ? ((1 << 20) - (1 << 9)) / 256 : 0;     // 4094
    const int ncd  = big2 ? (int)((N2 + 255u) / 256u) : 0;       // 1073
    const int nc01 = big2 ? (int)((N01 + 255u) / 256u) : 0;      // 141

    hipLaunchKernelGGL(prep_all, dim3(ncc + ncf + ncd + nc01 + 4), dim3(256),
                       0, stream, W0, W1, W2, tbl, (unsigned*)d_ws,
                       ncc, ncf, ncd, nc01);

    if (big2) {
        hipLaunchKernelGGL(ngp_pa, dim3(total / 256), dim3(256), 0, stream,
                           xyz, bnd, (unsigned*)d_ws);
        hipLaunchKernelGGL(ngp_pb, dim3(ntiles), dim3(BLOCK), 0, stream,
                           xyz, bnd, (const unsigned*)d_ws, out);
    } else if (big) {
        hipLaunchKernelGGL(ngp_mfma<true>, dim3(ntiles), dim3(BLOCK), 0, stream,
                           xyz, tbl, bnd, (const unsigned*)d_ws, out, ntiles);
    } else {
        hipLaunchKernelGGL(ngp_mfma<false>, dim3(ntiles), dim3(BLOCK), 0, stream,
                           xyz, tbl, bnd, (const unsigned*)d_ws, out, ntiles);
    }
}

// Round 7
// 219.365 us; speedup vs baseline: 1.5084x; 1.0212x over previous
//
#include <hip/hip_runtime.h>

// Instant-NGP hash encode (16 levels, F=2) + 32->64->64->8 MLP via MFMA,
// outer trilinear over 8 corners of a 512^3 grid.
//
// R13: phase-split regs, zero barriers, 133us. dur tracks FETCH (L2-miss).
// R14: two-pass level split (coarse 4MB | fine+dense 5.4MB). FETCH 312->91MB,
//   pb 92us, total 214.5us (best so far).
// R15 FAILED: launch_bounds(256,8) spill. R16: L01-merge + bf16 dense OK,
//   but nt partials killed pa->pb same-XCD L2 carry (pb 92->98us).
// R17 FAILED: hipLaunchCooperativeKernel doesn't land under graph capture
//   (out stayed zero). Cooperative path removed.
// R19: proven two-kernel structure + validated wins only:
//   prep(nt loads/regular stores) -> pa(nt xyz, REGULAR partial store)
//   -> pb(L01 merge, bf16 dense, regular partial read, nt xyz/out, lb(256,5)).

typedef __attribute__((ext_vector_type(8))) short short8_t;
typedef __attribute__((ext_vector_type(4))) float f32x4;
typedef unsigned long long ull;

static constexpr unsigned kT    = 1u << 19;
static constexpr unsigned kMask = kT - 1u;
static constexpr unsigned cP1   = 2654435761u;
static constexpr unsigned cP2   = 805459861u;
static constexpr int      BLOCK = 256;
static constexpr int      TOFF  = 4096;        // d_ws dword offset of tables
static constexpr unsigned D01   = 1u << 21;    // tbx dwords: L0+L1 uint2[33^3]
static constexpr unsigned N01   = 35937u;      // 33^3
static constexpr unsigned D2    = D01 + 72000u;// tbx dwords: L2 dword[65^3]
static constexpr unsigned N2    = 274625u;     // 65^3
static constexpr unsigned PARTO = 2621440u;    // dword offset of partials
static constexpr size_t   WS_NEED  = ((size_t)TOFF + (1u << 21)) * 4;   // 8MB+
static constexpr size_t   WS_NEED2 = ((size_t)PARTO + (1u << 22)) * 4;  // 26MB+

static __device__ __forceinline__ unsigned bf16_rn(float x) {
    unsigned u = __float_as_uint(x);
    return (u + 0x7fffu + ((u >> 16) & 1u)) >> 16;   // round-to-nearest-even
}

static __device__ __forceinline__ float2 bf2dec(unsigned u) {
    return make_float2(__uint_as_float(u << 16),
                       __uint_as_float(u & 0xffff0000u));
}

// packed f32x2 -> bf16x2, RNE (bit-identical to bf16_rn pair). lo in low 16.
static __device__ __forceinline__ unsigned cvtpk(float lo, float hi) {
    unsigned r;
    asm("v_cvt_pk_bf16_f32 %0, %1, %2" : "=v"(r) : "v"(lo), "v"(hi));
    return r;
}

static __device__ __forceinline__ f32x4 mfma16(short8_t a, short8_t b, f32x4 c) {
    return __builtin_amdgcn_mfma_f32_16x16x32_bf16(a, b, c, 0, 0, 0);
}

// ---- fused prep: [0,ncc) coarse bf16; [+ncf) fine compact; [+ncd) dense L2;
// [+nc01) merged L0+L1 grid; tail 4 blocks = weight pre-swizzle.
// nt loads (don't thrash L2), regular stores (tables land cache-warm).
__global__ __launch_bounds__(256)
void prep_all(const float* __restrict__ W0, const float* __restrict__ W1,
              const float* __restrict__ W2, const float2* __restrict__ tbl,
              unsigned* __restrict__ ws, int ncc, int ncf, int ncd, int nc01)
{
    const int bx = blockIdx.x, tid = threadIdx.x;
    if (bx < ncc) {
        // coarse levels 3,4: fp32x2 -> packed bf16x2 (pairs of entries)
        const int i = bx * 256 + tid;                // < 2^19
        const ull* __restrict__ p = (const ull*)(tbl + (size_t)3 * kT);
        const ull a = __builtin_nontemporal_load(p + 2 * (size_t)i);
        const ull b = __builtin_nontemporal_load(p + 2 * (size_t)i + 1);
        ((ull*)(ws + TOFF))[i] =
              (ull)(bf16_rn(__uint_as_float((unsigned)a))
                  | (bf16_rn(__uint_as_float((unsigned)(a >> 32))) << 16))
            | ((ull)(bf16_rn(__uint_as_float((unsigned)b))
                  | (bf16_rn(__uint_as_float((unsigned)(b >> 32))) << 16)) << 32);
    } else if (bx < ncc + ncf) {
        // fine level 5+s entry (j<<s) -> compact slot j at fineOff(s)
        const int i = (bx - ncc) * 256 + tid;        // < 2^20 - 2^9
        const unsigned vv = (1u << 20) - 1u - (unsigned)i;
        const int s = __clz((int)vv) - 12;           // 0..10
        const unsigned fo = (1u << 20) - ((1u << 20) >> s);
        const unsigned j = (unsigned)i - fo;
        const ull e = __builtin_nontemporal_load(
            (const ull*)tbl + ((size_t)(5 + s) << 19) + ((size_t)j << s));
        ws[TOFF + (1u << 20) + i] = bf16_rn(__uint_as_float((unsigned)e))
            | (bf16_rn(__uint_as_float((unsigned)(e >> 32))) << 16);
    } else if (bx < ncc + ncf + ncd) {
        // dense level 2: fp32x2 -> bf16x2 dword, contiguous 65^3
        const int i = (bx - ncc - ncf) * 256 + tid;
        if (i < (int)N2) {
            const ull e = __builtin_nontemporal_load(
                (const ull*)tbl + (size_t)2 * kT + i);
            ws[TOFF + D2 + i] = bf16_rn(__uint_as_float((unsigned)e))
                | (bf16_rn(__uint_as_float((unsigned)(e >> 32))) << 16);
        }
    } else if (bx < ncc + ncf + ncd + nc01) {
        // merged L0+L1 grid: per level-1 vertex v (33^3), store
        // (bf16 f0(v), bf16 f1(v)) where f0 = level-0 trilinear at v/2.
        const int i = (bx - ncc - ncf - ncd) * 256 + tid;
        if (i < (int)N01) {
            const int vz = i / 1089;
            const int r  = i - vz * 1089;
            const int vy = r / 33;
            const int vx = r - vy * 33;
            const float2 f1 = tbl[(size_t)kT + i];   // level-1 value (gather)
            const int x0 = vx >> 1, y0 = vy >> 1, z0 = vz >> 1;
            const int x1 = (x0 + 1 > 16) ? 16 : x0 + 1;
            const int y1 = (y0 + 1 > 16) ? 16 : y0 + 1;
            const int z1 = (z0 + 1 > 16) ? 16 : z0 + 1;
            const float fx = (vx & 1) ? 0.5f : 0.0f;
            const float fy = (vy & 1) ? 0.5f : 0.0f;
            const float fz = (vz & 1) ? 0.5f : 0.0f;
            const int Y0 = y0 * 17, Y1 = y1 * 17, Z0 = z0 * 289, Z1 = z1 * 289;
            const float2 g0 = tbl[x0 + Y0 + Z0], g1 = tbl[x1 + Y0 + Z0];
            const float2 g2 = tbl[x0 + Y1 + Z0], g3 = tbl[x1 + Y1 + Z0];
            const float2 g4 = tbl[x0 + Y0 + Z1], g5 = tbl[x1 + Y0 + Z1];
            const float2 g6 = tbl[x0 + Y1 + Z1], g7 = tbl[x1 + Y1 + Z1];
            const float wx1 = fx, wx0 = 1.0f - fx;
            const float wy1 = fy, wy0 = 1.0f - fy;
            const float wz1 = fz, wz0 = 1.0f - fz;
            const float w00 = wx0 * wy0, w10 = wx1 * wy0, w01 = wx0 * wy1, w11 = wx1 * wy1;
            const float a0 = w00 * wz0, a1 = w10 * wz0, a2 = w01 * wz0, a3 = w11 * wz0;
            const float a4 = w00 * wz1, a5 = w10 * wz1, a6 = w01 * wz1, a7 = w11 * wz1;
            const float f0x = a0 * g0.x + a1 * g1.x + a2 * g2.x + a3 * g3.x
                            + a4 * g4.x + a5 * g5.x + a6 * g6.x + a7 * g7.x;
            const float f0y = a0 * g0.y + a1 * g1.y + a2 * g2.y + a3 * g3.y
                            + a4 * g4.y + a5 * g5.y + a6 * g6.y + a7 * g7.y;
            ((ull*)(ws + TOFF + D01))[i] =
                (ull)cvtpk(f0x, f0y) | ((ull)cvtpk(f1.x, f1.y) << 32);
        }
    } else {
        // weights: A-frag order, bf16 RNE. tiles 0..3 = W0; 4..11 = W1
        // (mt=(t-4)>>1, kt=(t-4)&1, K pi-permuted); 12..13 = W2 (cols>=8 zero)
        const int t = (bx - ncc - ncf - ncd - nc01) * 4 + (tid >> 6);
        if (t >= 14) return;
        const int lane = tid & 63;
        const int n = lane & 15, q = lane >> 4;
        unsigned hi[4];
        #pragma unroll
        for (int d = 0; d < 4; ++d) {
            unsigned h2[2];
            #pragma unroll
            for (int s = 0; s < 2; ++s) {
                const int j = d * 2 + s;
                float v;
                if (t < 4) {
                    v = W0[(q * 8 + j) * 64 + t * 16 + n];
                } else {
                    const int kp = (j < 4) ? (q * 4 + j) : (16 + q * 4 + (j - 4));
                    if (t < 12) v = W1[(((t - 4) & 1) * 32 + kp) * 64 + ((t - 4) >> 1) * 16 + n];
                    else        v = (n < 8) ? W2[((t - 12) * 32 + kp) * 8 + n] : 0.0f;
                }
                h2[s] = bf16_rn(v);
            }
            hi[d] = h2[0] | (h2[1] << 16);
        }
        ((uint4*)ws)[t * 64 + lane] = make_uint4(hi[0], hi[1], hi[2], hi[3]);
    }
}

// ---- pass A: coarse levels 3,4 only (4MB working set = per-XCD L2).
// Partial store is REGULAR: it lands in this XCD's L2 and pb's same-index
// block reads it back warm (R16 lesson: nt here costs ~6us).
__global__ __launch_bounds__(256, 8)
void ngp_pa(const float* __restrict__ xyz, const int* __restrict__ boundp,
            unsigned* __restrict__ ws)
{
    const int tid = threadIdx.x;
    const int ge  = blockIdx.x * 256 + tid;
    const int pt  = ge >> 3;
    const int b   = ge & 7;

    const float bnd = (float)boundp[0];
    const float sc  = 0.5f / bnd;
    const float pxv = __builtin_nontemporal_load(xyz + pt * 3 + 0);
    const float pyv = __builtin_nontemporal_load(xyz + pt * 3 + 1);
    const float pzv = __builtin_nontemporal_load(xyz + pt * 3 + 2);
    const float cxf = (pxv + bnd) * sc * 512.0f;
    const float cyf = (pyv + bnd) * sc * 512.0f;
    const float czf = (pzv + bnd) * sc * 512.0f;
    const float c0x = fminf(fmaxf(floorf(cxf), 0.0f), 511.0f);
    const float c0y = fminf(fmaxf(floorf(cyf), 0.0f), 511.0f);
    const float c0z = fminf(fmaxf(floorf(czf), 0.0f), 511.0f);
    const unsigned kx = (unsigned)c0x + (unsigned)(b & 1);
    const unsigned ky = (unsigned)c0y + (unsigned)((b >> 1) & 1);
    const unsigned kz = (unsigned)c0z + (unsigned)((b >> 2) & 1);

    const unsigned* __restrict__ tbx = ws + TOFF;
    unsigned gH[2][8];
    #pragma unroll
    for (int l = 3; l < 5; ++l) {
        const int d = 5 - l;
        const unsigned qx = kx >> d, qy = ky >> d, qz = kz >> d;
        const unsigned hy0 = qy * cP1, hy1 = hy0 + cP1;
        const unsigned hz0 = qz * cP2, hz1 = hz0 + cP2;
        const unsigned x1u = qx + 1u;
        unsigned hidx[8];
        hidx[0] = (qx  ^ hy0 ^ hz0) & kMask;  hidx[1] = (x1u ^ hy0 ^ hz0) & kMask;
        hidx[2] = (qx  ^ hy1 ^ hz0) & kMask;  hidx[3] = (x1u ^ hy1 ^ hz0) & kMask;
        hidx[4] = (qx  ^ hy0 ^ hz1) & kMask;  hidx[5] = (x1u ^ hy0 ^ hz1) & kMask;
        hidx[6] = (qx  ^ hy1 ^ hz1) & kMask;  hidx[7] = (x1u ^ hy1 ^ hz1) & kMask;
        const unsigned* __restrict__ base = tbx + (size_t)(l - 3) * kT;
        #pragma unroll
        for (int c = 0; c < 8; ++c) gH[l - 3][c] = base[hidx[c]];
    }

    unsigned xd34[2];
    #pragma unroll
    for (int l = 3; l < 5; ++l) {
        const int d = 5 - l;
        const unsigned m = (1u << d) - 1u;
        const float inv = 1.0f / (float)(1 << d);
        const float fx = (float)(kx & m) * inv;
        const float fy = (float)(ky & m) * inv;
        const float fz = (float)(kz & m) * inv;
        const float2 g0 = bf2dec(gH[l - 3][0]), g1 = bf2dec(gH[l - 3][1]);
        const float2 g2 = bf2dec(gH[l - 3][2]), g3 = bf2dec(gH[l - 3][3]);
        const float2 g4 = bf2dec(gH[l - 3][4]), g5 = bf2dec(gH[l - 3][5]);
        const float2 g6 = bf2dec(gH[l - 3][6]), g7 = bf2dec(gH[l - 3][7]);
        const float wx1 = fx, wx0 = 1.0f - fx;
        const float wy1 = fy, wy0 = 1.0f - fy;
        const float wz1 = fz, wz0 = 1.0f - fz;
        const float w00 = wx0 * wy0, w10 = wx1 * wy0, w01 = wx0 * wy1, w11 = wx1 * wy1;
        const float a0 = w00 * wz0, a1 = w10 * wz0, a2 = w01 * wz0, a3 = w11 * wz0;
        const float a4 = w00 * wz1, a5 = w10 * wz1, a6 = w01 * wz1, a7 = w11 * wz1;
        const float vx = a0 * g0.x + a1 * g1.x + a2 * g2.x + a3 * g3.x
                       + a4 * g4.x + a5 * g5.x + a6 * g6.x + a7 * g7.x;
        const float vy = a0 * g0.y + a1 * g1.y + a2 * g2.y + a3 * g3.y
                       + a4 * g4.y + a5 * g5.y + a6 * g6.y + a7 * g7.y;
        xd34[l - 3] = cvtpk(vx, vy);
    }
    ((ull*)(ws + PARTO))[ge] = (ull)xd34[0] | ((ull)xd34[1] << 32);
}

// ---- pass B: dense (L01 merged + L2 bf16) + fine + partial + MLP.
// Hot ~5.4MB. nt: xyz loads + out stores. Partial read REGULAR (L2-warm).
__global__ __launch_bounds__(BLOCK, 5)
void ngp_pb(const float*  __restrict__ xyz,
            const int*    __restrict__ boundp,
            const unsigned* __restrict__ wsw,
            float*        __restrict__ out)
{
    // LDS: x only. row = eval (16 dw = 32 bf16 feats), quad XOR-swizzled.
    __shared__ __align__(16) unsigned lds[4096];
    const int tid  = threadIdx.x;
    const int lane = tid & 63;
    const int wv   = tid >> 6;
    const int col  = lane & 15;
    const int q    = lane >> 4;
    const int swz  = (tid ^ (tid >> 2) ^ (tid >> 4)) & 3;

    const unsigned* __restrict__ tbx = wsw + TOFF;
    const float bnd = (float)boundp[0];
    const float sc  = 0.5f / bnd;
    const f32x4 zero = {0.0f, 0.0f, 0.0f, 0.0f};

    // ================= encode (no weights live) =================
    const int ge = blockIdx.x * BLOCK + tid;
    const int pt = ge >> 3;
    const int b  = ge & 7;

    const float pxv = __builtin_nontemporal_load(xyz + pt * 3 + 0);
    const float pyv = __builtin_nontemporal_load(xyz + pt * 3 + 1);
    const float pzv = __builtin_nontemporal_load(xyz + pt * 3 + 2);
    const float cxf = (pxv + bnd) * sc * 512.0f;
    const float cyf = (pyv + bnd) * sc * 512.0f;
    const float czf = (pzv + bnd) * sc * 512.0f;
    const float c0x = fminf(fmaxf(floorf(cxf), 0.0f), 511.0f);
    const float c0y = fminf(fmaxf(floorf(cyf), 0.0f), 511.0f);
    const float c0z = fminf(fmaxf(floorf(czf), 0.0f), 511.0f);
    const float frx = cxf - c0x;
    const float fry = cyf - c0y;
    const float frz = czf - c0z;

    const unsigned kx = (unsigned)c0x + (unsigned)(b & 1);
    const unsigned ky = (unsigned)c0y + (unsigned)((b >> 1) & 1);
    const unsigned kz = (unsigned)c0z + (unsigned)((b >> 2) & 1);

    const float wb = ((b & 1) ? frx : 1.0f - frx)
                   * ((b & 2) ? fry : 1.0f - fry)
                   * ((b & 4) ? frz : 1.0f - frz);

    // fine levels (l=5..15): frac==0, single gather each (compacted).
    const unsigned kyp = ky * cP1;
    const unsigned kzp = kz * cP2;
    const unsigned X   = kx ^ kyp ^ kzp;
    unsigned gfu[11];
    #pragma unroll
    for (int l = 5; l < 16; ++l) {
        const int s = l - 5;
        const unsigned base = (1u << 20) + ((1u << 20) - ((1u << 20) >> s));
        gfu[l - 5] = tbx[base + (X & (kMask >> s))];
    }

    // coarse partial (written by pass A, same block index -> same XCD L2)
    const ull pv = ((const ull*)(wsw + PARTO))[ge];

    unsigned xd[16];
    // merged levels 0+1 on the 33^3 level-1 grid (4 feats/vertex)
    {
        const unsigned qx = kx >> 4, qy = ky >> 4, qz = kz >> 4;
        const float fx = (float)(kx & 15u) * 0.0625f;
        const float fy = (float)(ky & 15u) * 0.0625f;
        const float fz = (float)(kz & 15u) * 0.0625f;
        const unsigned x0 = qx, x1 = (qx + 1u > 32u) ? 32u : qx + 1u;
        const unsigned y0 = qy * 33u, y1 = ((qy + 1u > 32u) ? 32u : qy + 1u) * 33u;
        const unsigned z0 = qz * 1089u, z1 = ((qz + 1u > 32u) ? 32u : qz + 1u) * 1089u;
        const uint2* __restrict__ b01 = (const uint2*)(tbx + D01);
        const uint2 h0 = b01[x0 + y0 + z0], h1 = b01[x1 + y0 + z0];
        const uint2 h2 = b01[x0 + y1 + z0], h3 = b01[x1 + y1 + z0];
        const uint2 h4 = b01[x0 + y0 + z1], h5 = b01[x1 + y0 + z1];
        const uint2 h6 = b01[x0 + y1 + z1], h7 = b01[x1 + y1 + z1];
        const float wx1 = fx, wx0 = 1.0f - fx;
        const float wy1 = fy, wy0 = 1.0f - fy;
        const float wz1 = fz, wz0 = 1.0f - fz;
        const float w00 = wx0 * wy0, w10 = wx1 * wy0, w01 = wx0 * wy1, w11 = wx1 * wy1;
        const float a0 = w00 * wz0, a1 = w10 * wz0, a2 = w01 * wz0, a3 = w11 * wz0;
        const float a4 = w00 * wz1, a5 = w10 * wz1, a6 = w01 * wz1, a7 = w11 * wz1;
        float f0x, f0y, f1x, f1y;
        float2 d;
        d = bf2dec(h0.x); f0x  = a0 * d.x; f0y  = a0 * d.y;
        d = bf2dec(h0.y); f1x  = a0 * d.x; f1y  = a0 * d.y;
        d = bf2dec(h1.x); f0x += a1 * d.x; f0y += a1 * d.y;
        d = bf2dec(h1.y); f1x += a1 * d.x; f1y += a1 * d.y;
        d = bf2dec(h2.x); f0x += a2 * d.x; f0y += a2 * d.y;
        d = bf2dec(h2.y); f1x += a2 * d.x; f1y += a2 * d.y;
        d = bf2dec(h3.x); f0x += a3 * d.x; f0y += a3 * d.y;
        d = bf2dec(h3.y); f1x += a3 * d.x; f1y += a3 * d.y;
        d = bf2dec(h4.x); f0x += a4 * d.x; f0y += a4 * d.y;
        d = bf2dec(h4.y); f1x += a4 * d.x; f1y += a4 * d.y;
        d = bf2dec(h5.x); f0x += a5 * d.x; f0y += a5 * d.y;
        d = bf2dec(h5.y); f1x += a5 * d.x; f1y += a5 * d.y;
        d = bf2dec(h6.x); f0x += a6 * d.x; f0y += a6 * d.y;
        d = bf2dec(h6.y); f1x += a6 * d.x; f1y += a6 * d.y;
        d = bf2dec(h7.x); f0x += a7 * d.x; f0y += a7 * d.y;
        d = bf2dec(h7.y); f1x += a7 * d.x; f1y += a7 * d.y;
        xd[0] = cvtpk(f0x, f0y);
        xd[1] = cvtpk(f1x, f1y);
    }
    // dense level 2 (65^3 bf16)
    {
        const unsigned qx = kx >> 3, qy = ky >> 3, qz = kz >> 3;
        const float fx = (float)(kx & 7u) * 0.125f;
        const float fy = (float)(ky & 7u) * 0.125f;
        const float fz = (float)(kz & 7u) * 0.125f;
        const unsigned x0 = qx, x1 = (qx + 1u > 64u) ? 64u : qx + 1u;
        const unsigned y0 = qy * 65u, y1 = ((qy + 1u > 64u) ? 64u : qy + 1u) * 65u;
        const unsigned z0 = qz * 4225u, z1 = ((qz + 1u > 64u) ? 64u : qz + 1u) * 4225u;
        const unsigned* __restrict__ b2 = tbx + D2;
        const float2 g0 = bf2dec(b2[x0 + y0 + z0]), g1 = bf2dec(b2[x1 + y0 + z0]);
        const float2 g2 = bf2dec(b2[x0 + y1 + z0]), g3 = bf2dec(b2[x1 + y1 + z0]);
        const float2 g4 = bf2dec(b2[x0 + y0 + z1]), g5 = bf2dec(b2[x1 + y0 + z1]);
        const float2 g6 = bf2dec(b2[x0 + y1 + z1]), g7 = bf2dec(b2[x1 + y1 + z1]);
        const float wx1 = fx, wx0 = 1.0f - fx;
        const float wy1 = fy, wy0 = 1.0f - fy;
        const float wz1 = fz, wz0 = 1.0f - fz;
        const float w00 = wx0 * wy0, w10 = wx1 * wy0, w01 = wx0 * wy1, w11 = wx1 * wy1;
        const float a0 = w00 * wz0, a1 = w10 * wz0, a2 = w01 * wz0, a3 = w11 * wz0;
        const float a4 = w00 * wz1, a5 = w10 * wz1, a6 = w01 * wz1, a7 = w11 * wz1;
        const float vx = a0 * g0.x + a1 * g1.x + a2 * g2.x + a3 * g3.x
                       + a4 * g4.x + a5 * g5.x + a6 * g6.x + a7 * g7.x;
        const float vy = a0 * g0.y + a1 * g1.y + a2 * g2.y + a3 * g3.y
                       + a4 * g4.y + a5 * g5.y + a6 * g6.y + a7 * g7.y;
        xd[2] = cvtpk(vx, vy);
    }
    xd[3] = (unsigned)pv;
    xd[4] = (unsigned)(pv >> 32);
    #pragma unroll
    for (int l = 5; l < 16; ++l) xd[l] = gfu[l - 5];

    // swizzled x write: quad k at position k^swz (row = tid)
    {
        uint4* xrow = (uint4*)(lds + tid * 16);
        xrow[swz]     = make_uint4(xd[0],  xd[1],  xd[2],  xd[3]);
        xrow[swz ^ 1] = make_uint4(xd[4],  xd[5],  xd[6],  xd[7]);
        xrow[swz ^ 2] = make_uint4(xd[8],  xd[9],  xd[10], xd[11]);
        xrow[swz ^ 3] = make_uint4(xd[12], xd[13], xd[14], xd[15]);
    }

    // x exchange is within-wave (ev = wv*64+...) -> wave-local fence only.
    // Memory clobber pins the weight loads below (phase-split pressure).
    asm volatile("s_waitcnt lgkmcnt(0)" ::: "memory");
    __builtin_amdgcn_sched_barrier(0);

    // ---- weights -> 56 VGPRs (same addresses all waves: L1/L2 broadcast)
    short8_t w[14];
    {
        const short8_t* __restrict__ wfr = (const short8_t*)wsw;
        #pragma unroll
        for (int t = 0; t < 14; ++t) w[t] = wfr[t * 64 + lane];
    }

    // ================= MLP (transposed MFMA, weights in regs) =========
    #pragma unroll 1
    for (int g = 0; g < 4; ++g) {
        const int ev  = wv * 64 + g * 16 + col;
        const int esw = ((ev ^ (ev >> 2) ^ (ev >> 4)) & 3) ^ q;
        const short8_t xb = *(const short8_t*)(lds + ev * 16 + esw * 4);
        const float wbv = __shfl(wb, g * 16 + col, 64);

        unsigned hp0[4], hp1[4];
        // layer 1
        #pragma unroll
        for (int mt = 0; mt < 4; ++mt) {
            f32x4 a = mfma16(w[mt], xb, zero);
            hp0[mt] = cvtpk(fmaxf(a[0], 0.0f), fmaxf(a[1], 0.0f));
            hp1[mt] = cvtpk(fmaxf(a[2], 0.0f), fmaxf(a[3], 0.0f));
        }
        uint4 u0 = make_uint4(hp0[0], hp1[0], hp0[1], hp1[1]);
        uint4 u1 = make_uint4(hp0[2], hp1[2], hp0[3], hp1[3]);
        short8_t bk0 = *(short8_t*)&u0;
        short8_t bk1 = *(short8_t*)&u1;

        // layer 2
        #pragma unroll
        for (int mt = 0; mt < 4; ++mt) {
            f32x4 a = mfma16(w[4 + mt * 2], bk0, zero);
            a = mfma16(w[5 + mt * 2], bk1, a);
            hp0[mt] = cvtpk(fmaxf(a[0], 0.0f), fmaxf(a[1], 0.0f));
            hp1[mt] = cvtpk(fmaxf(a[2], 0.0f), fmaxf(a[3], 0.0f));
        }
        u0 = make_uint4(hp0[0], hp1[0], hp0[1], hp1[1]);
        u1 = make_uint4(hp0[2], hp1[2], hp0[3], hp1[3]);
        bk0 = *(short8_t*)&u0;
        bk1 = *(short8_t*)&u1;

        // layer 3
        f32x4 a3 = mfma16(w[12], bk0, zero);
        a3 = mfma16(w[13], bk1, a3);

        // weight by wb and reduce over the 8 corners (eval low 3 bits)
        float v0 = wbv * a3[0], v1 = wbv * a3[1], v2 = wbv * a3[2], v3 = wbv * a3[3];
        #pragma unroll
        for (int s = 1; s < 8; s <<= 1) {
            v0 += __shfl_xor(v0, s);
            v1 += __shfl_xor(v1, s);
            v2 += __shfl_xor(v2, s);
            v3 += __shfl_xor(v3, s);
        }
        if (((lane & 7) == 0) && q < 2) {
            const int p = (blockIdx.x * BLOCK + ev) >> 3;
            ull* op = (ull*)(out + p * 8 + q * 4);
            __builtin_nontemporal_store(
                (ull)__float_as_uint(v0) | ((ull)__float_as_uint(v1) << 32), op);
            __builtin_nontemporal_store(
                (ull)__float_as_uint(v2) | ((ull)__float_as_uint(v3) << 32), op + 1);
        }
    }
}

// ---- R13 single-kernel fallback (ws too small for the two-pass split) ----
template<bool BT>
__global__ __launch_bounds__(BLOCK, 5)
void ngp_mfma(const float*  __restrict__ xyz,
              const float2* __restrict__ tbl,
              const int*    __restrict__ boundp,
              const unsigned* __restrict__ wsw,
              float*        __restrict__ out,
              int ntiles)
{
    __shared__ __align__(16) unsigned lds[4096];
    const int tid  = threadIdx.x;
    const int lane = tid & 63;
    const int wv   = tid >> 6;
    const int col  = lane & 15;
    const int q    = lane >> 4;
    const int swz  = (tid ^ (tid >> 2) ^ (tid >> 4)) & 3;

    const unsigned* __restrict__ tbx = wsw + TOFF;
    const float bnd = (float)boundp[0];
    const float sc  = 0.5f / bnd;
    const f32x4 zero = {0.0f, 0.0f, 0.0f, 0.0f};

    const int ge = blockIdx.x * BLOCK + tid;
    const int pt = ge >> 3;
    const int b  = ge & 7;

    const float cxf = (xyz[pt * 3 + 0] + bnd) * sc * 512.0f;
    const float cyf = (xyz[pt * 3 + 1] + bnd) * sc * 512.0f;
    const float czf = (xyz[pt * 3 + 2] + bnd) * sc * 512.0f;
    const float c0x = fminf(fmaxf(floorf(cxf), 0.0f), 511.0f);
    const float c0y = fminf(fmaxf(floorf(cyf), 0.0f), 511.0f);
    const float c0z = fminf(fmaxf(floorf(czf), 0.0f), 511.0f);
    const float frx = cxf - c0x;
    const float fry = cyf - c0y;
    const float frz = czf - c0z;

    const unsigned kx = (unsigned)c0x + (unsigned)(b & 1);
    const unsigned ky = (unsigned)c0y + (unsigned)((b >> 1) & 1);
    const unsigned kz = (unsigned)c0z + (unsigned)((b >> 2) & 1);

    const float wb = ((b & 1) ? frx : 1.0f - frx)
                   * ((b & 2) ? fry : 1.0f - fry)
                   * ((b & 4) ? frz : 1.0f - frz);

    const unsigned kyp = ky * cP1;
    const unsigned kzp = kz * cP2;
    const unsigned X   = kx ^ kyp ^ kzp;
    unsigned gfu[11];
    float2   gff[11];
    #pragma unroll
    for (int l = 5; l < 16; ++l) {
        const int s = l - 5;
        if (BT) {
            const unsigned base = (1u << 20) + ((1u << 20) - ((1u << 20) >> s));
            gfu[l - 5] = tbx[base + (X & (kMask >> s))];
        } else {
            const unsigned idx = ((kx << s) ^ (kyp << s) ^ (kzp << s)) & kMask;
            gff[l - 5] = tbl[(size_t)l * kT + idx];
        }
    }

    unsigned gH[2][8];
    float2   gHf[2][8];
    #pragma unroll
    for (int l = 3; l < 5; ++l) {
        const int d = 5 - l;
        const unsigned qx = kx >> d, qy = ky >> d, qz = kz >> d;
        const unsigned hy0 = qy * cP1, hy1 = hy0 + cP1;
        const unsigned hz0 = qz * cP2, hz1 = hz0 + cP2;
        const unsigned x1u = qx + 1u;
        unsigned hidx[8];
        hidx[0] = (qx  ^ hy0 ^ hz0) & kMask;  hidx[1] = (x1u ^ hy0 ^ hz0) & kMask;
        hidx[2] = (qx  ^ hy1 ^ hz0) & kMask;  hidx[3] = (x1u ^ hy1 ^ hz0) & kMask;
        hidx[4] = (qx  ^ hy0 ^ hz1) & kMask;  hidx[5] = (x1u ^ hy0 ^ hz1) & kMask;
        hidx[6] = (qx  ^ hy1 ^ hz1) & kMask;  hidx[7] = (x1u ^ hy1 ^ hz1) & kMask;
        if (BT) {
            const unsigned* __restrict__ base = tbx + (size_t)(l - 3) * kT;
            #pragma unroll
            for (int c = 0; c < 8; ++c) gH[l - 3][c] = base[hidx[c]];
        } else {
            const float2* __restrict__ base = tbl + (size_t)l * kT;
            #pragma unroll
            for (int c = 0; c < 8; ++c) gHf[l - 3][c] = base[hidx[c]];
        }
    }

    float2 gc[5];
    #pragma unroll
    for (int l = 0; l < 5; ++l) {
        const int d = 5 - l;
        const unsigned m = (1u << d) - 1u;
        const float inv = 1.0f / (float)(1 << d);
        const unsigned qx = kx >> d, qy = ky >> d, qz = kz >> d;
        const float fx = (float)(kx & m) * inv;
        const float fy = (float)(ky & m) * inv;
        const float fz = (float)(kz & m) * inv;
        float2 g0, g1, g2, g3, g4, g5, g6, g7;
        if (l < 3) {
            const unsigned res = 16u << l;
            const unsigned R = res + 1u, R2 = R * R;
            const unsigned x0 = (qx < res ? qx : res);
            const unsigned x1 = (qx + 1u < res ? qx + 1u : res);
            const unsigned y0 = (qy < res ? qy : res) * R;
            const unsigned y1 = (qy + 1u < res ? qy + 1u : res) * R;
            const unsigned z0 = (qz < res ? qz : res) * R2;
            const unsigned z1 = (qz + 1u < res ? qz + 1u : res) * R2;
            const float2* __restrict__ base = tbl + (size_t)l * kT;
            g0 = base[x0 + y0 + z0]; g1 = base[x1 + y0 + z0];
            g2 = base[x0 + y1 + z0]; g3 = base[x1 + y1 + z0];
            g4 = base[x0 + y0 + z1]; g5 = base[x1 + y0 + z1];
            g6 = base[x0 + y1 + z1]; g7 = base[x1 + y1 + z1];
        } else if (BT) {
            g0 = bf2dec(gH[l - 3][0]); g1 = bf2dec(gH[l - 3][1]);
            g2 = bf2dec(gH[l - 3][2]); g3 = bf2dec(gH[l - 3][3]);
            g4 = bf2dec(gH[l - 3][4]); g5 = bf2dec(gH[l - 3][5]);
            g6 = bf2dec(gH[l - 3][6]); g7 = bf2dec(gH[l - 3][7]);
        } else {
            g0 = gHf[l - 3][0]; g1 = gHf[l - 3][1]; g2 = gHf[l - 3][2]; g3 = gHf[l - 3][3];
            g4 = gHf[l - 3][4]; g5 = gHf[l - 3][5]; g6 = gHf[l - 3][6]; g7 = gHf[l - 3][7];
        }
        const float wx1 = fx, wx0 = 1.0f - fx;
        const float wy1 = fy, wy0 = 1.0f - fy;
        const float wz1 = fz, wz0 = 1.0f - fz;
        const float w00 = wx0 * wy0, w10 = wx1 * wy0, w01 = wx0 * wy1, w11 = wx1 * wy1;
        const float a0 = w00 * wz0, a1 = w10 * wz0, a2 = w01 * wz0, a3 = w11 * wz0;
        const float a4 = w00 * wz1, a5 = w10 * wz1, a6 = w01 * wz1, a7 = w11 * wz1;
        float vx = a0 * g0.x + a1 * g1.x + a2 * g2.x + a3 * g3.x
                 + a4 * g4.x + a5 * g5.x + a6 * g6.x + a7 * g7.x;
        float vy = a0 * g0.y + a1 * g1.y + a2 * g2.y + a3 * g3.y
                 + a4 * g4.y + a5 * g5.y + a6 * g6.y + a7 * g7.y;
        gc[l] = make_float2(vx, vy);
    }

    unsigned xd[16];
    #pragma unroll
    for (int l = 0; l < 5; ++l)
        xd[l] = cvtpk(gc[l].x, gc[l].y);
    #pragma unroll
    for (int l = 5; l < 16; ++l) {
        if (BT) xd[l] = gfu[l - 5];
        else    xd[l] = cvtpk(gff[l - 5].x, gff[l - 5].y);
    }
    {
        uint4* xrow = (uint4*)(lds + tid * 16);
        xrow[swz]     = make_uint4(xd[0],  xd[1],  xd[2],  xd[3]);
        xrow[swz ^ 1] = make_uint4(xd[4],  xd[5],  xd[6],  xd[7]);
        xrow[swz ^ 2] = make_uint4(xd[8],  xd[9],  xd[10], xd[11]);
        xrow[swz ^ 3] = make_uint4(xd[12], xd[13], xd[14], xd[15]);
    }

    asm volatile("s_waitcnt lgkmcnt(0)" ::: "memory");
    __builtin_amdgcn_sched_barrier(0);

    short8_t w[14];
    {
        const short8_t* __restrict__ wfr = (const short8_t*)wsw;
        #pragma unroll
        for (int t = 0; t < 14; ++t) w[t] = wfr[t * 64 + lane];
    }

    #pragma unroll 1
    for (int g = 0; g < 4; ++g) {
        const int ev  = wv * 64 + g * 16 + col;
        const int esw = ((ev ^ (ev >> 2) ^ (ev >> 4)) & 3) ^ q;
        const short8_t xb = *(const short8_t*)(lds + ev * 16 + esw * 4);
        const float wbv = __shfl(wb, g * 16 + col, 64);

        unsigned hp0[4], hp1[4];
        #pragma unroll
        for (int mt = 0; mt < 4; ++mt) {
            f32x4 a = mfma16(w[mt], xb, zero);
            hp0[mt] = cvtpk(fmaxf(a[0], 0.0f), fmaxf(a[1], 0.0f));
            hp1[mt] = cvtpk(fmaxf(a[2], 0.0f), fmaxf(a[3], 0.0f));
        }
        uint4 u0 = make_uint4(hp0[0], hp1[0], hp0[1], hp1[1]);
        uint4 u1 = make_uint4(hp0[2], hp1[2], hp0[3], hp1[3]);
        short8_t bk0 = *(short8_t*)&u0;
        short8_t bk1 = *(short8_t*)&u1;

        #pragma unroll
        for (int mt = 0; mt < 4; ++mt) {
            f32x4 a = mfma16(w[4 + mt * 2], bk0, zero);
            a = mfma16(w[5 + mt * 2], bk1, a);
            hp0[mt] = cvtpk(fmaxf(a[0], 0.0f), fmaxf(a[1], 0.0f));
            hp1[mt] = cvtpk(fmaxf(a[2], 0.0f), fmaxf(a[3], 0.0f));
        }
        u0 = make_uint4(hp0[0], hp1[0], hp0[1], hp1[1]);
        u1 = make_uint4(hp0[2], hp1[2], hp0[3], hp1[3]);
        bk0 = *(short8_t*)&u0;
        bk1 = *(short8_t*)&u1;

        f32x4 a3 = mfma16(w[12], bk0, zero);
        a3 = mfma16(w[13], bk1, a3);

        float v0 = wbv * a3[0], v1 = wbv * a3[1], v2 = wbv * a3[2], v3 = wbv * a3[3];
        #pragma unroll
        for (int s = 1; s < 8; s <<= 1) {
            v0 += __shfl_xor(v0, s);
            v1 += __shfl_xor(v1, s);
            v2 += __shfl_xor(v2, s);
            v3 += __shfl_xor(v3, s);
        }
        if (((lane & 7) == 0) && q < 2) {
            const int p = (blockIdx.x * BLOCK + ev) >> 3;
            *(float4*)(out + p * 8 + q * 4) = make_float4(v0, v1, v2, v3);
        }
    }
}

extern "C" void kernel_launch(void* const* d_in, const int* in_sizes, int n_in,
                              void* d_out, int out_size, void* d_ws, size_t ws_size,
                              hipStream_t stream) {
    const float*  xyz = (const float*)d_in[0];
    const float2* tbl = (const float2*)d_in[1];
    const float*  W0  = (const float*)d_in[2];
    const float*  W1  = (const float*)d_in[3];
    const float*  W2  = (const float*)d_in[4];
    const int*    bnd = (const int*)d_in[5];
    float* out = (float*)d_out;

    const int npts   = in_sizes[0] / 3;
    const int total  = npts * 8;
    const int ntiles = total / BLOCK;

    const bool big2 = (ws_size >= WS_NEED2);
    const bool big  = (ws_size >= WS_NEED);
    const int ncc  = big ? (1 << 19) / 256 : 0;                  // 2048
    const int ncf  = big ? ((1 << 20) - (1 << 9)) / 256 : 0;     // 4094
    const int ncd  = big2 ? (int)((N2 + 255u) / 256u) : 0;       // 1073
    const int nc01 = big2 ? (int)((N01 + 255u) / 256u) : 0;      // 141

    hipLaunchKernelGGL(prep_all, dim3(ncc + ncf + ncd + nc01 + 4), dim3(256),
                       0, stream, W0, W1, W2, tbl, (unsigned*)d_ws,
                       ncc, ncf, ncd, nc01);

    if (big2) {
        hipLaunchKernelGGL(ngp_pa, dim3(total / 256), dim3(256), 0, stream,
                           xyz, bnd, (unsigned*)d_ws);
        hipLaunchKernelGGL(ngp_pb, dim3(ntiles), dim3(BLOCK), 0, stream,
                           xyz, bnd, (const unsigned*)d_ws, out);
    } else if (big) {
        hipLaunchKernelGGL(ngp_mfma<true>, dim3(ntiles), dim3(BLOCK), 0, stream,
                           xyz, tbl, bnd, (const unsigned*)d_ws, out, ntiles);
    } else {
        hipLaunchKernelGGL(ngp_mfma<false>, dim3(ntiles), dim3(BLOCK), 0, stream,
                           xyz, tbl, bnd, (const unsigned*)d_ws, out, ntiles);
    }
}

// Round 8
// 215.842 us; speedup vs baseline: 1.5330x; 1.0163x over previous
//
#include <hip/hip_runtime.h>

// Instant-NGP hash encode (16 levels, F=2) + 32->64->64->8 MLP via MFMA,
// outer trilinear over 8 corners of a 512^3 grid.
//
// R13: phase-split regs, zero barriers. dur tracks FETCH (L2-miss path).
// R14: two-pass level split (coarse 4MB | fine+dense 5.4MB). FETCH 312->91MB.
// R15 FAILED: lb(256,8) spill. R16: L01-merge+bf16 dense OK; nt partials bad.
// R17 FAILED: cooperative launch doesn't land under graph capture.
// R19: proven two-pass + validated wins. pb 93.5us, FETCH 92.6MB, occ 48%,
//   nothing saturated -> latency/L2-request bound. The random traffic is
//   fine L5/6/7: 24 random 64B lines per point for 4B payloads each.
// R20: COMBO RECORD for L5/6/7. Indices are X&(2^19-1), X&(2^18-1),
//   X&(2^17-1) -> all determined by j=X&(2^17-1) + 2 bits. Pack per j a
//   32B record {L5[j|b<<17] b=0..3, L6[j|b<<17] b=0..1, L7[j], pad}:
//   ONE line fetch replaces THREE random lines (3x fewer L2/HBM random
//   requests). Bit-identical values. Levels 8-15 -> small compact region.

typedef __attribute__((ext_vector_type(8))) short short8_t;
typedef __attribute__((ext_vector_type(4))) float f32x4;
typedef unsigned long long ull;

static constexpr unsigned kT    = 1u << 19;
static constexpr unsigned kMask = kT - 1u;
static constexpr unsigned cP1   = 2654435761u;
static constexpr unsigned cP2   = 805459861u;
static constexpr int      BLOCK = 256;
static constexpr int      TOFF  = 4096;          // d_ws dword offset of tables
// tbx dword layout: coarse L3/L4 [0,2^20) | combo L5-7 [2^20,2^21) 8dw/rec
//   | small fine L8-15 [2^21, 2^21+130560) | L0+L1 uint2[33^3] | L2 dword[65^3]
static constexpr unsigned CMB   = 1u << 20;
static constexpr unsigned SMF   = 1u << 21;
static constexpr unsigned D01   = (1u << 21) + (1u << 17);   // 2228224
static constexpr unsigned N01   = 35937u;        // 33^3
static constexpr unsigned D2    = D01 + 72000u;  // 2300224
static constexpr unsigned N2    = 274625u;       // 65^3 (end 2574849 < PARTO)
static constexpr unsigned PARTO = 2621440u;      // dword offset of partials
static constexpr size_t   WS_NEED2 = ((size_t)PARTO + (1u << 22)) * 4;  // 26MB+

static __device__ __forceinline__ unsigned bf16_rn(float x) {
    unsigned u = __float_as_uint(x);
    return (u + 0x7fffu + ((u >> 16) & 1u)) >> 16;   // round-to-nearest-even
}

static __device__ __forceinline__ float2 bf2dec(unsigned u) {
    return make_float2(__uint_as_float(u << 16),
                       __uint_as_float(u & 0xffff0000u));
}

// packed f32x2 -> bf16x2, RNE (bit-identical to bf16_rn pair). lo in low 16.
static __device__ __forceinline__ unsigned cvtpk(float lo, float hi) {
    unsigned r;
    asm("v_cvt_pk_bf16_f32 %0, %1, %2" : "=v"(r) : "v"(lo), "v"(hi));
    return r;
}

static __device__ __forceinline__ unsigned pkbf(ull e) {
    return bf16_rn(__uint_as_float((unsigned)e))
         | (bf16_rn(__uint_as_float((unsigned)(e >> 32))) << 16);
}

static __device__ __forceinline__ f32x4 mfma16(short8_t a, short8_t b, f32x4 c) {
    return __builtin_amdgcn_mfma_f32_16x16x32_bf16(a, b, c, 0, 0, 0);
}

// ---- fused prep: [0,ncc) coarse bf16; [+ncb) combo L5-7; [+nsf) small fine
// L8-15; [+ncd) dense L2; [+nc01) merged L0+L1; tail 4 = weight pre-swizzle.
// nt loads (don't thrash L2), regular stores (tables land cache-warm).
__global__ __launch_bounds__(256)
void prep_all(const float* __restrict__ W0, const float* __restrict__ W1,
              const float* __restrict__ W2, const float2* __restrict__ tbl,
              unsigned* __restrict__ ws, int ncc, int ncb, int nsf, int ncd,
              int nc01)
{
    const int bx = blockIdx.x, tid = threadIdx.x;
    if (bx < ncc) {
        // coarse levels 3,4: fp32x2 -> packed bf16x2 (pairs of entries)
        const int i = bx * 256 + tid;                // < 2^19
        const ull* __restrict__ p = (const ull*)(tbl + (size_t)3 * kT);
        const ull a = __builtin_nontemporal_load(p + 2 * (size_t)i);
        const ull b = __builtin_nontemporal_load(p + 2 * (size_t)i + 1);
        ((ull*)(ws + TOFF))[i] = (ull)pkbf(a) | ((ull)pkbf(b) << 32);
    } else if (bx < ncc + ncb) {
        // combo record j: {L5[j|b17<<17] b=0..3, L6[j|b<<17] b=0..1, L7[j], 0}
        const unsigned j = (unsigned)((bx - ncc) * 256 + tid);   // < 2^17
        unsigned dw[8];
        #pragma unroll
        for (int b = 0; b < 4; ++b) {
            const ull e = __builtin_nontemporal_load(
                (const ull*)tbl + (size_t)5 * kT + (j | ((unsigned)b << 17)));
            dw[b] = pkbf(e);
        }
        #pragma unroll
        for (int b = 0; b < 2; ++b) {
            const ull e = __builtin_nontemporal_load(
                (const ull*)tbl + (size_t)6 * kT
                + ((size_t)(j | ((unsigned)b << 17)) << 1));
            dw[4 + b] = pkbf(e);
        }
        {
            const ull e = __builtin_nontemporal_load(
                (const ull*)tbl + (size_t)7 * kT + ((size_t)j << 2));
            dw[6] = pkbf(e);
            dw[7] = 0u;
        }
        uint4* dst = (uint4*)(ws + TOFF + CMB + j * 8);
        dst[0] = make_uint4(dw[0], dw[1], dw[2], dw[3]);
        dst[1] = make_uint4(dw[4], dw[5], dw[6], dw[7]);
    } else if (bx < ncc + ncb + nsf) {
        // small fine levels 8..15 compact: fo(s) = 2^17 - 2^(20-s)
        const int i = (bx - ncc - ncb) * 256 + tid;  // < 130560
        const unsigned v = 131071u - (unsigned)i;
        const int s = __clz((int)v) - 12;            // 3..10
        const unsigned fo = (1u << 17) - (1u << (20 - s));
        const unsigned j = (unsigned)i - fo;
        const ull e = __builtin_nontemporal_load(
            (const ull*)tbl + ((size_t)(5 + s) << 19) + ((size_t)j << s));
        ws[TOFF + SMF + i] = pkbf(e);
    } else if (bx < ncc + ncb + nsf + ncd) {
        // dense level 2: fp32x2 -> bf16x2 dword, contiguous 65^3
        const int i = (bx - ncc - ncb - nsf) * 256 + tid;
        if (i < (int)N2) {
            const ull e = __builtin_nontemporal_load(
                (const ull*)tbl + (size_t)2 * kT + i);
            ws[TOFF + D2 + i] = pkbf(e);
        }
    } else if (bx < ncc + ncb + nsf + ncd + nc01) {
        // merged L0+L1 grid: per level-1 vertex v (33^3), store
        // (bf16 f0(v), bf16 f1(v)) where f0 = level-0 trilinear at v/2.
        const int i = (bx - ncc - ncb - nsf - ncd) * 256 + tid;
        if (i < (int)N01) {
            const int vz = i / 1089;
            const int r  = i - vz * 1089;
            const int vy = r / 33;
            const int vx = r - vy * 33;
            const float2 f1 = tbl[(size_t)kT + i];   // level-1 value
            const int x0 = vx >> 1, y0 = vy >> 1, z0 = vz >> 1;
            const int x1 = (x0 + 1 > 16) ? 16 : x0 + 1;
            const int y1 = (y0 + 1 > 16) ? 16 : y0 + 1;
            const int z1 = (z0 + 1 > 16) ? 16 : z0 + 1;
            const float fx = (vx & 1) ? 0.5f : 0.0f;
            const float fy = (vy & 1) ? 0.5f : 0.0f;
            const float fz = (vz & 1) ? 0.5f : 0.0f;
            const int Y0 = y0 * 17, Y1 = y1 * 17, Z0 = z0 * 289, Z1 = z1 * 289;
            const float2 g0 = tbl[x0 + Y0 + Z0], g1 = tbl[x1 + Y0 + Z0];
            const float2 g2 = tbl[x0 + Y1 + Z0], g3 = tbl[x1 + Y1 + Z0];
            const float2 g4 = tbl[x0 + Y0 + Z1], g5 = tbl[x1 + Y0 + Z1];
            const float2 g6 = tbl[x0 + Y1 + Z1], g7 = tbl[x1 + Y1 + Z1];
            const float wx1 = fx, wx0 = 1.0f - fx;
            const float wy1 = fy, wy0 = 1.0f - fy;
            const float wz1 = fz, wz0 = 1.0f - fz;
            const float w00 = wx0 * wy0, w10 = wx1 * wy0, w01 = wx0 * wy1, w11 = wx1 * wy1;
            const float a0 = w00 * wz0, a1 = w10 * wz0, a2 = w01 * wz0, a3 = w11 * wz0;
            const float a4 = w00 * wz1, a5 = w10 * wz1, a6 = w01 * wz1, a7 = w11 * wz1;
            const float f0x = a0 * g0.x + a1 * g1.x + a2 * g2.x + a3 * g3.x
                            + a4 * g4.x + a5 * g5.x + a6 * g6.x + a7 * g7.x;
            const float f0y = a0 * g0.y + a1 * g1.y + a2 * g2.y + a3 * g3.y
                            + a4 * g4.y + a5 * g5.y + a6 * g6.y + a7 * g7.y;
            ((ull*)(ws + TOFF + D01))[i] =
                (ull)cvtpk(f0x, f0y) | ((ull)cvtpk(f1.x, f1.y) << 32);
        }
    } else {
        // weights: A-frag order, bf16 RNE. tiles 0..3 = W0; 4..11 = W1
        // (mt=(t-4)>>1, kt=(t-4)&1, K pi-permuted); 12..13 = W2 (cols>=8 zero)
        const int t = (bx - ncc - ncb - nsf - ncd - nc01) * 4 + (tid >> 6);
        if (t >= 14) return;
        const int lane = tid & 63;
        const int n = lane & 15, q = lane >> 4;
        unsigned hi[4];
        #pragma unroll
        for (int d = 0; d < 4; ++d) {
            unsigned h2[2];
            #pragma unroll
            for (int s = 0; s < 2; ++s) {
                const int j = d * 2 + s;
                float v;
                if (t < 4) {
                    v = W0[(q * 8 + j) * 64 + t * 16 + n];
                } else {
                    const int kp = (j < 4) ? (q * 4 + j) : (16 + q * 4 + (j - 4));
                    if (t < 12) v = W1[(((t - 4) & 1) * 32 + kp) * 64 + ((t - 4) >> 1) * 16 + n];
                    else        v = (n < 8) ? W2[((t - 12) * 32 + kp) * 8 + n] : 0.0f;
                }
                h2[s] = bf16_rn(v);
            }
            hi[d] = h2[0] | (h2[1] << 16);
        }
        ((uint4*)ws)[t * 64 + lane] = make_uint4(hi[0], hi[1], hi[2], hi[3]);
    }
}

// ---- pass A: coarse levels 3,4 only (4MB working set = per-XCD L2).
// Partial store REGULAR (same-XCD L2 carry to pb, R16 lesson).
__global__ __launch_bounds__(256, 8)
void ngp_pa(const float* __restrict__ xyz, const int* __restrict__ boundp,
            unsigned* __restrict__ ws)
{
    const int tid = threadIdx.x;
    const int ge  = blockIdx.x * 256 + tid;
    const int pt  = ge >> 3;
    const int b   = ge & 7;

    const float bnd = (float)boundp[0];
    const float sc  = 0.5f / bnd;
    const float pxv = __builtin_nontemporal_load(xyz + pt * 3 + 0);
    const float pyv = __builtin_nontemporal_load(xyz + pt * 3 + 1);
    const float pzv = __builtin_nontemporal_load(xyz + pt * 3 + 2);
    const float cxf = (pxv + bnd) * sc * 512.0f;
    const float cyf = (pyv + bnd) * sc * 512.0f;
    const float czf = (pzv + bnd) * sc * 512.0f;
    const float c0x = fminf(fmaxf(floorf(cxf), 0.0f), 511.0f);
    const float c0y = fminf(fmaxf(floorf(cyf), 0.0f), 511.0f);
    const float c0z = fminf(fmaxf(floorf(czf), 0.0f), 511.0f);
    const unsigned kx = (unsigned)c0x + (unsigned)(b & 1);
    const unsigned ky = (unsigned)c0y + (unsigned)((b >> 1) & 1);
    const unsigned kz = (unsigned)c0z + (unsigned)((b >> 2) & 1);

    const unsigned* __restrict__ tbx = ws + TOFF;
    unsigned gH[2][8];
    #pragma unroll
    for (int l = 3; l < 5; ++l) {
        const int d = 5 - l;
        const unsigned qx = kx >> d, qy = ky >> d, qz = kz >> d;
        const unsigned hy0 = qy * cP1, hy1 = hy0 + cP1;
        const unsigned hz0 = qz * cP2, hz1 = hz0 + cP2;
        const unsigned x1u = qx + 1u;
        unsigned hidx[8];
        hidx[0] = (qx  ^ hy0 ^ hz0) & kMask;  hidx[1] = (x1u ^ hy0 ^ hz0) & kMask;
        hidx[2] = (qx  ^ hy1 ^ hz0) & kMask;  hidx[3] = (x1u ^ hy1 ^ hz0) & kMask;
        hidx[4] = (qx  ^ hy0 ^ hz1) & kMask;  hidx[5] = (x1u ^ hy0 ^ hz1) & kMask;
        hidx[6] = (qx  ^ hy1 ^ hz1) & kMask;  hidx[7] = (x1u ^ hy1 ^ hz1) & kMask;
        const unsigned* __restrict__ base = tbx + (size_t)(l - 3) * kT;
        #pragma unroll
        for (int c = 0; c < 8; ++c) gH[l - 3][c] = base[hidx[c]];
    }

    unsigned xd34[2];
    #pragma unroll
    for (int l = 3; l < 5; ++l) {
        const int d = 5 - l;
        const unsigned m = (1u << d) - 1u;
        const float inv = 1.0f / (float)(1 << d);
        const float fx = (float)(kx & m) * inv;
        const float fy = (float)(ky & m) * inv;
        const float fz = (float)(kz & m) * inv;
        const float2 g0 = bf2dec(gH[l - 3][0]), g1 = bf2dec(gH[l - 3][1]);
        const float2 g2 = bf2dec(gH[l - 3][2]), g3 = bf2dec(gH[l - 3][3]);
        const float2 g4 = bf2dec(gH[l - 3][4]), g5 = bf2dec(gH[l - 3][5]);
        const float2 g6 = bf2dec(gH[l - 3][6]), g7 = bf2dec(gH[l - 3][7]);
        const float wx1 = fx, wx0 = 1.0f - fx;
        const float wy1 = fy, wy0 = 1.0f - fy;
        const float wz1 = fz, wz0 = 1.0f - fz;
        const float w00 = wx0 * wy0, w10 = wx1 * wy0, w01 = wx0 * wy1, w11 = wx1 * wy1;
        const float a0 = w00 * wz0, a1 = w10 * wz0, a2 = w01 * wz0, a3 = w11 * wz0;
        const float a4 = w00 * wz1, a5 = w10 * wz1, a6 = w01 * wz1, a7 = w11 * wz1;
        const float vx = a0 * g0.x + a1 * g1.x + a2 * g2.x + a3 * g3.x
                       + a4 * g4.x + a5 * g5.x + a6 * g6.x + a7 * g7.x;
        const float vy = a0 * g0.y + a1 * g1.y + a2 * g2.y + a3 * g3.y
                       + a4 * g4.y + a5 * g5.y + a6 * g6.y + a7 * g7.y;
        xd34[l - 3] = cvtpk(vx, vy);
    }
    ((ull*)(ws + PARTO))[ge] = (ull)xd34[0] | ((ull)xd34[1] << 32);
}

// ---- pass B: combo fine + small fine + dense + partial + MLP.
__global__ __launch_bounds__(BLOCK, 5)
void ngp_pb(const float*  __restrict__ xyz,
            const int*    __restrict__ boundp,
            const unsigned* __restrict__ wsw,
            float*        __restrict__ out)
{
    // LDS: x only. row = eval (16 dw = 32 bf16 feats), quad XOR-swizzled.
    __shared__ __align__(16) unsigned lds[4096];
    const int tid  = threadIdx.x;
    const int lane = tid & 63;
    const int wv   = tid >> 6;
    const int col  = lane & 15;
    const int q    = lane >> 4;
    const int swz  = (tid ^ (tid >> 2) ^ (tid >> 4)) & 3;

    const unsigned* __restrict__ tbx = wsw + TOFF;
    const float bnd = (float)boundp[0];
    const float sc  = 0.5f / bnd;
    const f32x4 zero = {0.0f, 0.0f, 0.0f, 0.0f};

    // ================= encode (no weights live) =================
    const int ge = blockIdx.x * BLOCK + tid;
    const int pt = ge >> 3;
    const int b  = ge & 7;

    const float pxv = __builtin_nontemporal_load(xyz + pt * 3 + 0);
    const float pyv = __builtin_nontemporal_load(xyz + pt * 3 + 1);
    const float pzv = __builtin_nontemporal_load(xyz + pt * 3 + 2);
    const float cxf = (pxv + bnd) * sc * 512.0f;
    const float cyf = (pyv + bnd) * sc * 512.0f;
    const float czf = (pzv + bnd) * sc * 512.0f;
    const float c0x = fminf(fmaxf(floorf(cxf), 0.0f), 511.0f);
    const float c0y = fminf(fmaxf(floorf(cyf), 0.0f), 511.0f);
    const float c0z = fminf(fmaxf(floorf(czf), 0.0f), 511.0f);
    const float frx = cxf - c0x;
    const float fry = cyf - c0y;
    const float frz = czf - c0z;

    const unsigned kx = (unsigned)c0x + (unsigned)(b & 1);
    const unsigned ky = (unsigned)c0y + (unsigned)((b >> 1) & 1);
    const unsigned kz = (unsigned)c0z + (unsigned)((b >> 2) & 1);

    const float wb = ((b & 1) ? frx : 1.0f - frx)
                   * ((b & 2) ? fry : 1.0f - fry)
                   * ((b & 4) ? frz : 1.0f - frz);

    const unsigned kyp = ky * cP1;
    const unsigned kzp = kz * cP2;
    const unsigned X   = kx ^ kyp ^ kzp;

    // fine L5-7: ONE 32B combo record (single 64B line) + 2-bit selects
    const unsigned j17 = X & ((1u << 17) - 1u);
    const uint4 rc0 = *(const uint4*)(tbx + CMB + j17 * 8);
    const uint4 rc1 = *(const uint4*)(tbx + CMB + j17 * 8 + 4);

    // small fine levels 8..15 (0.5MB compact region, high reuse)
    unsigned gsm[8];
    #pragma unroll
    for (int l = 8; l < 16; ++l) {
        const int s = l - 5;
        const unsigned fo = (1u << 17) - (1u << (20 - s));
        gsm[l - 8] = tbx[SMF + fo + (X & ((1u << (19 - s)) - 1u))];
    }

    // coarse partial (written by pass A, same block index -> same XCD L2)
    const ull pv = ((const ull*)(wsw + PARTO))[ge];

    unsigned xd[16];
    // merged levels 0+1 on the 33^3 level-1 grid (4 feats/vertex)
    {
        const unsigned qx = kx >> 4, qy = ky >> 4, qz = kz >> 4;
        const float fx = (float)(kx & 15u) * 0.0625f;
        const float fy = (float)(ky & 15u) * 0.0625f;
        const float fz = (float)(kz & 15u) * 0.0625f;
        const unsigned x0 = qx, x1 = (qx + 1u > 32u) ? 32u : qx + 1u;
        const unsigned y0 = qy * 33u, y1 = ((qy + 1u > 32u) ? 32u : qy + 1u) * 33u;
        const unsigned z0 = qz * 1089u, z1 = ((qz + 1u > 32u) ? 32u : qz + 1u) * 1089u;
        const uint2* __restrict__ b01 = (const uint2*)(tbx + D01);
        const uint2 h0 = b01[x0 + y0 + z0], h1 = b01[x1 + y0 + z0];
        const uint2 h2 = b01[x0 + y1 + z0], h3 = b01[x1 + y1 + z0];
        const uint2 h4 = b01[x0 + y0 + z1], h5 = b01[x1 + y0 + z1];
        const uint2 h6 = b01[x0 + y1 + z1], h7 = b01[x1 + y1 + z1];
        const float wx1 = fx, wx0 = 1.0f - fx;
        const float wy1 = fy, wy0 = 1.0f - fy;
        const float wz1 = fz, wz0 = 1.0f - fz;
        const float w00 = wx0 * wy0, w10 = wx1 * wy0, w01 = wx0 * wy1, w11 = wx1 * wy1;
        const float a0 = w00 * wz0, a1 = w10 * wz0, a2 = w01 * wz0, a3 = w11 * wz0;
        const float a4 = w00 * wz1, a5 = w10 * wz1, a6 = w01 * wz1, a7 = w11 * wz1;
        float f0x, f0y, f1x, f1y;
        float2 d;
        d = bf2dec(h0.x); f0x  = a0 * d.x; f0y  = a0 * d.y;
        d = bf2dec(h0.y); f1x  = a0 * d.x; f1y  = a0 * d.y;
        d = bf2dec(h1.x); f0x += a1 * d.x; f0y += a1 * d.y;
        d = bf2dec(h1.y); f1x += a1 * d.x; f1y += a1 * d.y;
        d = bf2dec(h2.x); f0x += a2 * d.x; f0y += a2 * d.y;
        d = bf2dec(h2.y); f1x += a2 * d.x; f1y += a2 * d.y;
        d = bf2dec(h3.x); f0x += a3 * d.x; f0y += a3 * d.y;
        d = bf2dec(h3.y); f1x += a3 * d.x; f1y += a3 * d.y;
        d = bf2dec(h4.x); f0x += a4 * d.x; f0y += a4 * d.y;
        d = bf2dec(h4.y); f1x += a4 * d.x; f1y += a4 * d.y;
        d = bf2dec(h5.x); f0x += a5 * d.x; f0y += a5 * d.y;
        d = bf2dec(h5.y); f1x += a5 * d.x; f1y += a5 * d.y;
        d = bf2dec(h6.x); f0x += a6 * d.x; f0y += a6 * d.y;
        d = bf2dec(h6.y); f1x += a6 * d.x; f1y += a6 * d.y;
        d = bf2dec(h7.x); f0x += a7 * d.x; f0y += a7 * d.y;
        d = bf2dec(h7.y); f1x += a7 * d.x; f1y += a7 * d.y;
        xd[0] = cvtpk(f0x, f0y);
        xd[1] = cvtpk(f1x, f1y);
    }
    // dense level 2 (65^3 bf16)
    {
        const unsigned qx = kx >> 3, qy = ky >> 3, qz = kz >> 3;
        const float fx = (float)(kx & 7u) * 0.125f;
        const float fy = (float)(ky & 7u) * 0.125f;
        const float fz = (float)(kz & 7u) * 0.125f;
        const unsigned x0 = qx, x1 = (qx + 1u > 64u) ? 64u : qx + 1u;
        const unsigned y0 = qy * 65u, y1 = ((qy + 1u > 64u) ? 64u : qy + 1u) * 65u;
        const unsigned z0 = qz * 4225u, z1 = ((qz + 1u > 64u) ? 64u : qz + 1u) * 4225u;
        const unsigned* __restrict__ b2 = tbx + D2;
        const float2 g0 = bf2dec(b2[x0 + y0 + z0]), g1 = bf2dec(b2[x1 + y0 + z0]);
        const float2 g2 = bf2dec(b2[x0 + y1 + z0]), g3 = bf2dec(b2[x1 + y1 + z0]);
        const float2 g4 = bf2dec(b2[x0 + y0 + z1]), g5 = bf2dec(b2[x1 + y0 + z1]);
        const float2 g6 = bf2dec(b2[x0 + y1 + z1]), g7 = bf2dec(b2[x1 + y1 + z1]);
        const float wx1 = fx, wx0 = 1.0f - fx;
        const float wy1 = fy, wy0 = 1.0f - fy;
        const float wz1 = fz, wz0 = 1.0f - fz;
        const float w00 = wx0 * wy0, w10 = wx1 * wy0, w01 = wx0 * wy1, w11 = wx1 * wy1;
        const float a0 = w00 * wz0, a1 = w10 * wz0, a2 = w01 * wz0, a3 = w11 * wz0;
        const float a4 = w00 * wz1, a5 = w10 * wz1, a6 = w01 * wz1, a7 = w11 * wz1;
        const float vx = a0 * g0.x + a1 * g1.x + a2 * g2.x + a3 * g3.x
                       + a4 * g4.x + a5 * g5.x + a6 * g6.x + a7 * g7.x;
        const float vy = a0 * g0.y + a1 * g1.y + a2 * g2.y + a3 * g3.y
                       + a4 * g4.y + a5 * g5.y + a6 * g6.y + a7 * g7.y;
        xd[2] = cvtpk(vx, vy);
    }
    xd[3] = (unsigned)pv;
    xd[4] = (unsigned)(pv >> 32);
    // combo selects: L5 by (X>>17)&3, L6 by (X>>17)&1, L7 fixed
    {
        const unsigned b56 = (X >> 17) & 3u;
        xd[5] = (b56 & 2u) ? ((b56 & 1u) ? rc0.w : rc0.z)
                           : ((b56 & 1u) ? rc0.y : rc0.x);
        xd[6] = ((X >> 17) & 1u) ? rc1.y : rc1.x;
        xd[7] = rc1.z;
    }
    #pragma unroll
    for (int l = 8; l < 16; ++l) xd[l] = gsm[l - 8];

    // swizzled x write: quad k at position k^swz (row = tid)
    {
        uint4* xrow = (uint4*)(lds + tid * 16);
        xrow[swz]     = make_uint4(xd[0],  xd[1],  xd[2],  xd[3]);
        xrow[swz ^ 1] = make_uint4(xd[4],  xd[5],  xd[6],  xd[7]);
        xrow[swz ^ 2] = make_uint4(xd[8],  xd[9],  xd[10], xd[11]);
        xrow[swz ^ 3] = make_uint4(xd[12], xd[13], xd[14], xd[15]);
    }

    // x exchange is within-wave (ev = wv*64+...) -> wave-local fence only.
    // Memory clobber pins the weight loads below (phase-split pressure).
    asm volatile("s_waitcnt lgkmcnt(0)" ::: "memory");
    __builtin_amdgcn_sched_barrier(0);

    // ---- weights -> 56 VGPRs (same addresses all waves: L1/L2 broadcast)
    short8_t w[14];
    {
        const short8_t* __restrict__ wfr = (const short8_t*)wsw;
        #pragma unroll
        for (int t = 0; t < 14; ++t) w[t] = wfr[t * 64 + lane];
    }

    // ================= MLP (transposed MFMA, weights in regs) =========
    #pragma unroll 1
    for (int g = 0; g < 4; ++g) {
        const int ev  = wv * 64 + g * 16 + col;
        const int esw = ((ev ^ (ev >> 2) ^ (ev >> 4)) & 3) ^ q;
        const short8_t xb = *(const short8_t*)(lds + ev * 16 + esw * 4);
        const float wbv = __shfl(wb, g * 16 + col, 64);

        unsigned hp0[4], hp1[4];
        // layer 1
        #pragma unroll
        for (int mt = 0; mt < 4; ++mt) {
            f32x4 a = mfma16(w[mt], xb, zero);
            hp0[mt] = cvtpk(fmaxf(a[0], 0.0f), fmaxf(a[1], 0.0f));
            hp1[mt] = cvtpk(fmaxf(a[2], 0.0f), fmaxf(a[3], 0.0f));
        }
        uint4 u0 = make_uint4(hp0[0], hp1[0], hp0[1], hp1[1]);
        uint4 u1 = make_uint4(hp0[2], hp1[2], hp0[3], hp1[3]);
        short8_t bk0 = *(short8_t*)&u0;
        short8_t bk1 = *(short8_t*)&u1;

        // layer 2
        #pragma unroll
        for (int mt = 0; mt < 4; ++mt) {
            f32x4 a = mfma16(w[4 + mt * 2], bk0, zero);
            a = mfma16(w[5 + mt * 2], bk1, a);
            hp0[mt] = cvtpk(fmaxf(a[0], 0.0f), fmaxf(a[1], 0.0f));
            hp1[mt] = cvtpk(fmaxf(a[2], 0.0f), fmaxf(a[3], 0.0f));
        }
        u0 = make_uint4(hp0[0], hp1[0], hp0[1], hp1[1]);
        u1 = make_uint4(hp0[2], hp1[2], hp0[3], hp1[3]);
        bk0 = *(short8_t*)&u0;
        bk1 = *(short8_t*)&u1;

        // layer 3
        f32x4 a3 = mfma16(w[12], bk0, zero);
        a3 = mfma16(w[13], bk1, a3);

        // weight by wb and reduce over the 8 corners (eval low 3 bits)
        float v0 = wbv * a3[0], v1 = wbv * a3[1], v2 = wbv * a3[2], v3 = wbv * a3[3];
        #pragma unroll
        for (int s = 1; s < 8; s <<= 1) {
            v0 += __shfl_xor(v0, s);
            v1 += __shfl_xor(v1, s);
            v2 += __shfl_xor(v2, s);
            v3 += __shfl_xor(v3, s);
        }
        if (((lane & 7) == 0) && q < 2) {
            const int p = (blockIdx.x * BLOCK + ev) >> 3;
            ull* op = (ull*)(out + p * 8 + q * 4);
            __builtin_nontemporal_store(
                (ull)__float_as_uint(v0) | ((ull)__float_as_uint(v1) << 32), op);
            __builtin_nontemporal_store(
                (ull)__float_as_uint(v2) | ((ull)__float_as_uint(v3) << 32), op + 1);
        }
    }
}

// ---- tbl-only single-kernel fallback (ws too small for the split) --------
__global__ __launch_bounds__(BLOCK, 5)
void ngp_mfma(const float*  __restrict__ xyz,
              const float2* __restrict__ tbl,
              const int*    __restrict__ boundp,
              const unsigned* __restrict__ wsw,
              float*        __restrict__ out,
              int ntiles)
{
    __shared__ __align__(16) unsigned lds[4096];
    const int tid  = threadIdx.x;
    const int lane = tid & 63;
    const int wv   = tid >> 6;
    const int col  = lane & 15;
    const int q    = lane >> 4;
    const int swz  = (tid ^ (tid >> 2) ^ (tid >> 4)) & 3;

    const float bnd = (float)boundp[0];
    const float sc  = 0.5f / bnd;
    const f32x4 zero = {0.0f, 0.0f, 0.0f, 0.0f};

    const int ge = blockIdx.x * BLOCK + tid;
    const int pt = ge >> 3;
    const int b  = ge & 7;

    const float cxf = (xyz[pt * 3 + 0] + bnd) * sc * 512.0f;
    const float cyf = (xyz[pt * 3 + 1] + bnd) * sc * 512.0f;
    const float czf = (xyz[pt * 3 + 2] + bnd) * sc * 512.0f;
    const float c0x = fminf(fmaxf(floorf(cxf), 0.0f), 511.0f);
    const float c0y = fminf(fmaxf(floorf(cyf), 0.0f), 511.0f);
    const float c0z = fminf(fmaxf(floorf(czf), 0.0f), 511.0f);
    const float frx = cxf - c0x;
    const float fry = cyf - c0y;
    const float frz = czf - c0z;

    const unsigned kx = (unsigned)c0x + (unsigned)(b & 1);
    const unsigned ky = (unsigned)c0y + (unsigned)((b >> 1) & 1);
    const unsigned kz = (unsigned)c0z + (unsigned)((b >> 2) & 1);

    const float wb = ((b & 1) ? frx : 1.0f - frx)
                   * ((b & 2) ? fry : 1.0f - fry)
                   * ((b & 4) ? frz : 1.0f - frz);

    const unsigned kyp = ky * cP1;
    const unsigned kzp = kz * cP2;
    unsigned gfu_dummy;
    (void)gfu_dummy;
    float2 gff[11];
    #pragma unroll
    for (int l = 5; l < 16; ++l) {
        const int s = l - 5;
        const unsigned idx = ((kx << s) ^ (kyp << s) ^ (kzp << s)) & kMask;
        gff[l - 5] = tbl[(size_t)l * kT + idx];
    }

    float2 gHf[2][8];
    #pragma unroll
    for (int l = 3; l < 5; ++l) {
        const int d = 5 - l;
        const unsigned qx = kx >> d, qy = ky >> d, qz = kz >> d;
        const unsigned hy0 = qy * cP1, hy1 = hy0 + cP1;
        const unsigned hz0 = qz * cP2, hz1 = hz0 + cP2;
        const unsigned x1u = qx + 1u;
        unsigned hidx[8];
        hidx[0] = (qx  ^ hy0 ^ hz0) & kMask;  hidx[1] = (x1u ^ hy0 ^ hz0) & kMask;
        hidx[2] = (qx  ^ hy1 ^ hz0) & kMask;  hidx[3] = (x1u ^ hy1 ^ hz0) & kMask;
        hidx[4] = (qx  ^ hy0 ^ hz1) & kMask;  hidx[5] = (x1u ^ hy0 ^ hz1) & kMask;
        hidx[6] = (qx  ^ hy1 ^ hz1) & kMask;  hidx[7] = (x1u ^ hy1 ^ hz1) & kMask;
        const float2* __restrict__ base = tbl + (size_t)l * kT;
        #pragma unroll
        for (int c = 0; c < 8; ++c) gHf[l - 3][c] = base[hidx[c]];
    }

    float2 gc[5];
    #pragma unroll
    for (int l = 0; l < 5; ++l) {
        const int d = 5 - l;
        const unsigned m = (1u << d) - 1u;
        const float inv = 1.0f / (float)(1 << d);
        const unsigned qx = kx >> d, qy = ky >> d, qz = kz >> d;
        const float fx = (float)(kx & m) * inv;
        const float fy = (float)(ky & m) * inv;
        const float fz = (float)(kz & m) * inv;
        float2 g0, g1, g2, g3, g4, g5, g6, g7;
        if (l < 3) {
            const unsigned res = 16u << l;
            const unsigned R = res + 1u, R2 = R * R;
            const unsigned x0 = (qx < res ? qx : res);
            const unsigned x1 = (qx + 1u < res ? qx + 1u : res);
            const unsigned y0 = (qy < res ? qy : res) * R;
            const unsigned y1 = (qy + 1u < res ? qy + 1u : res) * R;
            const unsigned z0 = (qz < res ? qz : res) * R2;
            const unsigned z1 = (qz + 1u < res ? qz + 1u : res) * R2;
            const float2* __restrict__ base = tbl + (size_t)l * kT;
            g0 = base[x0 + y0 + z0]; g1 = base[x1 + y0 + z0];
            g2 = base[x0 + y1 + z0]; g3 = base[x1 + y1 + z0];
            g4 = base[x0 + y0 + z1]; g5 = base[x1 + y0 + z1];
            g6 = base[x0 + y1 + z1]; g7 = base[x1 + y1 + z1];
        } else {
            g0 = gHf[l - 3][0]; g1 = gHf[l - 3][1]; g2 = gHf[l - 3][2]; g3 = gHf[l - 3][3];
            g4 = gHf[l - 3][4]; g5 = gHf[l - 3][5]; g6 = gHf[l - 3][6]; g7 = gHf[l - 3][7];
        }
        const float wx1 = fx, wx0 = 1.0f - fx;
        const float wy1 = fy, wy0 = 1.0f - fy;
        const float wz1 = fz, wz0 = 1.0f - fz;
        const float w00 = wx0 * wy0, w10 = wx1 * wy0, w01 = wx0 * wy1, w11 = wx1 * wy1;
        const float a0 = w00 * wz0, a1 = w10 * wz0, a2 = w01 * wz0, a3 = w11 * wz0;
        const float a4 = w00 * wz1, a5 = w10 * wz1, a6 = w01 * wz1, a7 = w11 * wz1;
        float vx = a0 * g0.x + a1 * g1.x + a2 * g2.x + a3 * g3.x
                 + a4 * g4.x + a5 * g5.x + a6 * g6.x + a7 * g7.x;
        float vy = a0 * g0.y + a1 * g1.y + a2 * g2.y + a3 * g3.y
                 + a4 * g4.y + a5 * g5.y + a6 * g6.y + a7 * g7.y;
        gc[l] = make_float2(vx, vy);
    }

    unsigned xd[16];
    #pragma unroll
    for (int l = 0; l < 5; ++l)
        xd[l] = cvtpk(gc[l].x, gc[l].y);
    #pragma unroll
    for (int l = 5; l < 16; ++l)
        xd[l] = cvtpk(gff[l - 5].x, gff[l - 5].y);
    {
        uint4* xrow = (uint4*)(lds + tid * 16);
        xrow[swz]     = make_uint4(xd[0],  xd[1],  xd[2],  xd[3]);
        xrow[swz ^ 1] = make_uint4(xd[4],  xd[5],  xd[6],  xd[7]);
        xrow[swz ^ 2] = make_uint4(xd[8],  xd[9],  xd[10], xd[11]);
        xrow[swz ^ 3] = make_uint4(xd[12], xd[13], xd[14], xd[15]);
    }

    asm volatile("s_waitcnt lgkmcnt(0)" ::: "memory");
    __builtin_amdgcn_sched_barrier(0);

    short8_t w[14];
    {
        const short8_t* __restrict__ wfr = (const short8_t*)wsw;
        #pragma unroll
        for (int t = 0; t < 14; ++t) w[t] = wfr[t * 64 + lane];
    }

    #pragma unroll 1
    for (int g = 0; g < 4; ++g) {
        const int ev  = wv * 64 + g * 16 + col;
        const int esw = ((ev ^ (ev >> 2) ^ (ev >> 4)) & 3) ^ q;
        const short8_t xb = *(const short8_t*)(lds + ev * 16 + esw * 4);
        const float wbv = __shfl(wb, g * 16 + col, 64);

        unsigned hp0[4], hp1[4];
        #pragma unroll
        for (int mt = 0; mt < 4; ++mt) {
            f32x4 a = mfma16(w[mt], xb, zero);
            hp0[mt] = cvtpk(fmaxf(a[0], 0.0f), fmaxf(a[1], 0.0f));
            hp1[mt] = cvtpk(fmaxf(a[2], 0.0f), fmaxf(a[3], 0.0f));
        }
        uint4 u0 = make_uint4(hp0[0], hp1[0], hp0[1], hp1[1]);
        uint4 u1 = make_uint4(hp0[2], hp1[2], hp0[3], hp1[3]);
        short8_t bk0 = *(short8_t*)&u0;
        short8_t bk1 = *(short8_t*)&u1;

        #pragma unroll
        for (int mt = 0; mt < 4; ++mt) {
            f32x4 a = mfma16(w[4 + mt * 2], bk0, zero);
            a = mfma16(w[5 + mt * 2], bk1, a);
            hp0[mt] = cvtpk(fmaxf(a[0], 0.0f), fmaxf(a[1], 0.0f));
            hp1[mt] = cvtpk(fmaxf(a[2], 0.0f), fmaxf(a[3], 0.0f));
        }
        u0 = make_uint4(hp0[0], hp1[0], hp0[1], hp1[1]);
        u1 = make_uint4(hp0[2], hp1[2], hp0[3], hp1[3]);
        bk0 = *(short8_t*)&u0;
        bk1 = *(short8_t*)&u1;

        f32x4 a3 = mfma16(w[12], bk0, zero);
        a3 = mfma16(w[13], bk1, a3);

        float v0 = wbv * a3[0], v1 = wbv * a3[1], v2 = wbv * a3[2], v3 = wbv * a3[3];
        #pragma unroll
        for (int s = 1; s < 8; s <<= 1) {
            v0 += __shfl_xor(v0, s);
            v1 += __shfl_xor(v1, s);
            v2 += __shfl_xor(v2, s);
            v3 += __shfl_xor(v3, s);
        }
        if (((lane & 7) == 0) && q < 2) {
            const int p = (blockIdx.x * BLOCK + ev) >> 3;
            *(float4*)(out + p * 8 + q * 4) = make_float4(v0, v1, v2, v3);
        }
    }
}

extern "C" void kernel_launch(void* const* d_in, const int* in_sizes, int n_in,
                              void* d_out, int out_size, void* d_ws, size_t ws_size,
                              hipStream_t stream) {
    const float*  xyz = (const float*)d_in[0];
    const float2* tbl = (const float2*)d_in[1];
    const float*  W0  = (const float*)d_in[2];
    const float*  W1  = (const float*)d_in[3];
    const float*  W2  = (const float*)d_in[4];
    const int*    bnd = (const int*)d_in[5];
    float* out = (float*)d_out;

    const int npts   = in_sizes[0] / 3;
    const int total  = npts * 8;
    const int ntiles = total / BLOCK;

    const bool big2 = (ws_size >= WS_NEED2);
    const int ncc  = big2 ? (1 << 19) / 256 : 0;                 // 2048
    const int ncb  = big2 ? (1 << 17) / 256 : 0;                 // 512
    const int nsf  = big2 ? 130560 / 256 : 0;                    // 510
    const int ncd  = big2 ? (int)((N2 + 255u) / 256u) : 0;       // 1073
    const int nc01 = big2 ? (int)((N01 + 255u) / 256u) : 0;      // 141

    hipLaunchKernelGGL(prep_all, dim3(ncc + ncb + nsf + ncd + nc01 + 4),
                       dim3(256), 0, stream, W0, W1, W2, tbl, (unsigned*)d_ws,
                       ncc, ncb, nsf, ncd, nc01);

    if (big2) {
        hipLaunchKernelGGL(ngp_pa, dim3(total / 256), dim3(256), 0, stream,
                           xyz, bnd, (unsigned*)d_ws);
        hipLaunchKernelGGL(ngp_pb, dim3(ntiles), dim3(BLOCK), 0, stream,
                           xyz, bnd, (const unsigned*)d_ws, out);
    } else {
        hipLaunchKernelGGL(ngp_mfma, dim3(ntiles), dim3(BLOCK), 0, stream,
                           xyz, tbl, bnd, (const unsigned*)d_ws, out, ntiles);
    }
}

// Round 10
// 198.794 us; speedup vs baseline: 1.6644x; 1.0858x over previous
//
#include <hip/hip_runtime.h>

// Instant-NGP hash encode (16 levels, F=2) + 32->64->64->8 MLP via MFMA,
// outer trilinear over 8 corners of a 512^3 grid.
//
// R14: two-pass level split (coarse 4MB | rest). R19: proven structure,
//   pb 93.5us. R20: combo record L5-7 (3 random lines -> 1), pb 87.6us.
// MODEL: pb is TA REQUEST-RATE bound (~1 divergent line-req/cyc/CU):
//   25 divergent gathers/thread x 2M thr / 614G req/s = 85us ~= measured.
// R21 FAILED (absmax 1.8e-5): PARTO overlapped the P2 table tail by 2822
//   dwords (forgot TOFF in the ws-space bound). Design was correct.
// R22: R21 with PARTO = 2949120 >= TOFF+P2+2*N2 = 2943750. Divergent
//   gathers 25 -> 12, all bit-identical relocations:
//   - combo records: A={L5x4,L6x2,L7}/j17, B={L8x4,L9x2,L10}/j14,
//     C={L11x4,L12x2,L13}/j11, D={L14x2,L15}/j9  (11 fine levels -> 4 lines)
//   - x-pair dense grids: P01 16B recs, P2 8B recs (edge-clamped): 8->4 each.

typedef __attribute__((ext_vector_type(8))) short short8_t;
typedef __attribute__((ext_vector_type(4))) float f32x4;
typedef unsigned long long ull;

static constexpr unsigned kT    = 1u << 19;
static constexpr unsigned kMask = kT - 1u;
static constexpr unsigned cP1   = 2654435761u;
static constexpr unsigned cP2   = 805459861u;
static constexpr int      BLOCK = 256;
static constexpr int      TOFF  = 4096;          // d_ws dword offset of tables
// tbx dword layout:
//   [0, 2^20)            coarse L3/L4 bf16x2
//   CMB=2^20, 8dw x 2^17 combo A: {L5 b=0..3, L6 b=0..1, L7, pad} per j17
//   GB =2^21, 8dw x 2^14 combo B: {L8 b=0..3, L9 b=0..1, L10, pad} per j14
//   GC, 8dw x 2^11       combo C: {L11 b=0..3, L12 b=0..1, L13, pad} per j11
//   GD, 4dw x 2^9        combo D: {L14 b=0..1, L15, pad} per j9
//   P01, 4dw x 33^3      dense L0+L1 x-pairs {F(x), F(x+1c)} (F = 2 bf16x2)
//   P2,  2dw x 65^3      dense L2 x-pairs {v[x], v[x+1c]}
// partials live at ws + PARTO (ws-space! table end = TOFF+P2+2*N2 = 2943750)
static constexpr unsigned CMB   = 1u << 20;
static constexpr unsigned GB    = 1u << 21;                  // 2097152
static constexpr unsigned GC    = GB + (1u << 17);           // 2228224
static constexpr unsigned GD    = GC + (1u << 14);           // 2244608
static constexpr unsigned P01   = GD + (1u << 11);           // 2246656
static constexpr unsigned N01   = 35937u;                    // 33^3
static constexpr unsigned P2    = P01 + N01 * 4u;            // 2390404
static constexpr unsigned N2    = 274625u;                   // 65^3
static constexpr unsigned PARTO = 2949120u;                  // >= 2943750 (R21 fix)
static constexpr size_t   WS_NEED2 = ((size_t)PARTO + (1u << 22)) * 4;  // ~28.6MB

static __device__ __forceinline__ unsigned bf16_rn(float x) {
    unsigned u = __float_as_uint(x);
    return (u + 0x7fffu + ((u >> 16) & 1u)) >> 16;   // round-to-nearest-even
}

static __device__ __forceinline__ float2 bf2dec(unsigned u) {
    return make_float2(__uint_as_float(u << 16),
                       __uint_as_float(u & 0xffff0000u));
}

// packed f32x2 -> bf16x2, RNE (bit-identical to bf16_rn pair). lo in low 16.
static __device__ __forceinline__ unsigned cvtpk(float lo, float hi) {
    unsigned r;
    asm("v_cvt_pk_bf16_f32 %0, %1, %2" : "=v"(r) : "v"(lo), "v"(hi));
    return r;
}

static __device__ __forceinline__ unsigned pkbf(ull e) {
    return bf16_rn(__uint_as_float((unsigned)e))
         | (bf16_rn(__uint_as_float((unsigned)(e >> 32))) << 16);
}

static __device__ __forceinline__ unsigned sel4(uint4 v, unsigned b) {
    const unsigned lo = (b & 1u) ? v.y : v.x;
    const unsigned hi = (b & 1u) ? v.w : v.z;
    return (b & 2u) ? hi : lo;
}

static __device__ __forceinline__ f32x4 mfma16(short8_t a, short8_t b, f32x4 c) {
    return __builtin_amdgcn_mfma_f32_16x16x32_bf16(a, b, c, 0, 0, 0);
}

// merged L0+L1 value at level-1 vertex (vx,vy,vz): (bf16 f0, bf16 f1) packed.
static __device__ uint2 f01_vert(const float2* __restrict__ tbl,
                                 int vx, int vy, int vz)
{
    const float2 f1 = tbl[(size_t)kT + vz * 1089 + vy * 33 + vx];
    const int x0 = vx >> 1, y0 = vy >> 1, z0 = vz >> 1;
    const int x1 = (x0 + 1 > 16) ? 16 : x0 + 1;
    const int y1 = (y0 + 1 > 16) ? 16 : y0 + 1;
    const int z1 = (z0 + 1 > 16) ? 16 : z0 + 1;
    const float fx = (vx & 1) ? 0.5f : 0.0f;
    const float fy = (vy & 1) ? 0.5f : 0.0f;
    const float fz = (vz & 1) ? 0.5f : 0.0f;
    const int Y0 = y0 * 17, Y1 = y1 * 17, Z0 = z0 * 289, Z1 = z1 * 289;
    const float2 g0 = tbl[x0 + Y0 + Z0], g1 = tbl[x1 + Y0 + Z0];
    const float2 g2 = tbl[x0 + Y1 + Z0], g3 = tbl[x1 + Y1 + Z0];
    const float2 g4 = tbl[x0 + Y0 + Z1], g5 = tbl[x1 + Y0 + Z1];
    const float2 g6 = tbl[x0 + Y1 + Z1], g7 = tbl[x1 + Y1 + Z1];
    const float wx1 = fx, wx0 = 1.0f - fx;
    const float wy1 = fy, wy0 = 1.0f - fy;
    const float wz1 = fz, wz0 = 1.0f - fz;
    const float w00 = wx0 * wy0, w10 = wx1 * wy0, w01 = wx0 * wy1, w11 = wx1 * wy1;
    const float a0 = w00 * wz0, a1 = w10 * wz0, a2 = w01 * wz0, a3 = w11 * wz0;
    const float a4 = w00 * wz1, a5 = w10 * wz1, a6 = w01 * wz1, a7 = w11 * wz1;
    const float f0x = a0 * g0.x + a1 * g1.x + a2 * g2.x + a3 * g3.x
                    + a4 * g4.x + a5 * g5.x + a6 * g6.x + a7 * g7.x;
    const float f0y = a0 * g0.y + a1 * g1.y + a2 * g2.y + a3 * g3.y
                    + a4 * g4.y + a5 * g5.y + a6 * g6.y + a7 * g7.y;
    return make_uint2(cvtpk(f0x, f0y), cvtpk(f1.x, f1.y));
}

// ---- fused prep. nt loads (don't thrash), regular stores (land warm).
// segments: coarse | comboA | comboB | comboC | comboD | P01 | P2 | weights
__global__ __launch_bounds__(256)
void prep_all(const float* __restrict__ W0, const float* __restrict__ W1,
              const float* __restrict__ W2, const float2* __restrict__ tbl,
              unsigned* __restrict__ ws,
              int ncc, int ncA, int ncB, int ncC, int ncD, int nP01, int nP2)
{
    const int bx = blockIdx.x, tid = threadIdx.x;
    const ull* __restrict__ t8 = (const ull*)tbl;
    if (bx < ncc) {
        // coarse levels 3,4: fp32x2 -> packed bf16x2 (pairs of entries)
        const int i = bx * 256 + tid;                // < 2^19
        const ull* __restrict__ p = t8 + (size_t)3 * kT;
        const ull a = __builtin_nontemporal_load(p + 2 * (size_t)i);
        const ull b = __builtin_nontemporal_load(p + 2 * (size_t)i + 1);
        ((ull*)(ws + TOFF))[i] = (ull)pkbf(a) | ((ull)pkbf(b) << 32);
    } else if (bx < ncc + ncA) {
        // combo A (L5-7) per j17
        const unsigned j = (unsigned)((bx - ncc) * 256 + tid);   // < 2^17
        unsigned dw[8];
        #pragma unroll
        for (int b = 0; b < 4; ++b)
            dw[b] = pkbf(__builtin_nontemporal_load(
                t8 + (size_t)5 * kT + (j | ((unsigned)b << 17))));
        #pragma unroll
        for (int b = 0; b < 2; ++b)
            dw[4 + b] = pkbf(__builtin_nontemporal_load(
                t8 + (size_t)6 * kT + ((size_t)(j | ((unsigned)b << 17)) << 1)));
        dw[6] = pkbf(__builtin_nontemporal_load(
                t8 + (size_t)7 * kT + ((size_t)j << 2)));
        dw[7] = 0u;
        uint4* dst = (uint4*)(ws + TOFF + CMB + j * 8);
        dst[0] = make_uint4(dw[0], dw[1], dw[2], dw[3]);
        dst[1] = make_uint4(dw[4], dw[5], dw[6], dw[7]);
    } else if (bx < ncc + ncA + ncB) {
        // combo B (L8-10) per j14
        const unsigned j = (unsigned)((bx - ncc - ncA) * 256 + tid); // < 2^14
        unsigned dw[8];
        #pragma unroll
        for (int b = 0; b < 4; ++b)
            dw[b] = pkbf(__builtin_nontemporal_load(
                t8 + (size_t)8 * kT + ((size_t)(j | ((unsigned)b << 14)) << 3)));
        #pragma unroll
        for (int b = 0; b < 2; ++b)
            dw[4 + b] = pkbf(__builtin_nontemporal_load(
                t8 + (size_t)9 * kT + ((size_t)(j | ((unsigned)b << 14)) << 4)));
        dw[6] = pkbf(__builtin_nontemporal_load(
                t8 + (size_t)10 * kT + ((size_t)j << 5)));
        dw[7] = 0u;
        uint4* dst = (uint4*)(ws + TOFF + GB + j * 8);
        dst[0] = make_uint4(dw[0], dw[1], dw[2], dw[3]);
        dst[1] = make_uint4(dw[4], dw[5], dw[6], dw[7]);
    } else if (bx < ncc + ncA + ncB + ncC) {
        // combo C (L11-13) per j11
        const unsigned j = (unsigned)((bx - ncc - ncA - ncB) * 256 + tid); // <2^11
        unsigned dw[8];
        #pragma unroll
        for (int b = 0; b < 4; ++b)
            dw[b] = pkbf(__builtin_nontemporal_load(
                t8 + (size_t)11 * kT + ((size_t)(j | ((unsigned)b << 11)) << 6)));
        #pragma unroll
        for (int b = 0; b < 2; ++b)
            dw[4 + b] = pkbf(__builtin_nontemporal_load(
                t8 + (size_t)12 * kT + ((size_t)(j | ((unsigned)b << 11)) << 7)));
        dw[6] = pkbf(__builtin_nontemporal_load(
                t8 + (size_t)13 * kT + ((size_t)j << 8)));
        dw[7] = 0u;
        uint4* dst = (uint4*)(ws + TOFF + GC + j * 8);
        dst[0] = make_uint4(dw[0], dw[1], dw[2], dw[3]);
        dst[1] = make_uint4(dw[4], dw[5], dw[6], dw[7]);
    } else if (bx < ncc + ncA + ncB + ncC + ncD) {
        // combo D (L14-15) per j9, 16B records
        const unsigned j = (unsigned)((bx - ncc - ncA - ncB - ncC) * 256 + tid);
        unsigned dw[4];
        #pragma unroll
        for (int b = 0; b < 2; ++b)
            dw[b] = pkbf(__builtin_nontemporal_load(
                t8 + (size_t)14 * kT + ((size_t)(j | ((unsigned)b << 9)) << 9)));
        dw[2] = pkbf(__builtin_nontemporal_load(
                t8 + (size_t)15 * kT + ((size_t)j << 10)));
        dw[3] = 0u;
        ((uint4*)(ws + TOFF + GD))[j] = make_uint4(dw[0], dw[1], dw[2], dw[3]);
    } else if (bx < ncc + ncA + ncB + ncC + ncD + nP01) {
        // dense L0+L1 x-pair records: {F(vx), F(min(vx+1,32))}
        const int i = (bx - ncc - ncA - ncB - ncC - ncD) * 256 + tid;
        if (i < (int)N01) {
            const int vz = i / 1089;
            const int r  = i - vz * 1089;
            const int vy = r / 33;
            const int vx = r - vy * 33;
            const uint2 a = f01_vert(tbl, vx, vy, vz);
            const uint2 b = f01_vert(tbl, (vx + 1 > 32) ? 32 : vx + 1, vy, vz);
            ((uint4*)(ws + TOFF + P01))[i] = make_uint4(a.x, a.y, b.x, b.y);
        }
    } else if (bx < ncc + ncA + ncB + ncC + ncD + nP01 + nP2) {
        // dense L2 x-pair records: {v[i], v[i + (x<64)]}
        const int i = (bx - ncc - ncA - ncB - ncC - ncD - nP01) * 256 + tid;
        if (i < (int)N2) {
            const int x = i % 65;
            const unsigned lo = pkbf(__builtin_nontemporal_load(
                t8 + (size_t)2 * kT + i));
            const unsigned hi = pkbf(__builtin_nontemporal_load(
                t8 + (size_t)2 * kT + i + (x < 64 ? 1 : 0)));
            ((ull*)(ws + TOFF + P2))[i] = (ull)lo | ((ull)hi << 32);
        }
    } else {
        // weights: A-frag order, bf16 RNE. tiles 0..3 = W0; 4..11 = W1
        // (mt=(t-4)>>1, kt=(t-4)&1, K pi-permuted); 12..13 = W2 (cols>=8 zero)
        const int t = (bx - ncc - ncA - ncB - ncC - ncD - nP01 - nP2) * 4
                    + (tid >> 6);
        if (t >= 14) return;
        const int lane = tid & 63;
        const int n = lane & 15, q = lane >> 4;
        unsigned hi[4];
        #pragma unroll
        for (int d = 0; d < 4; ++d) {
            unsigned h2[2];
            #pragma unroll
            for (int s = 0; s < 2; ++s) {
                const int j = d * 2 + s;
                float v;
                if (t < 4) {
                    v = W0[(q * 8 + j) * 64 + t * 16 + n];
                } else {
                    const int kp = (j < 4) ? (q * 4 + j) : (16 + q * 4 + (j - 4));
                    if (t < 12) v = W1[(((t - 4) & 1) * 32 + kp) * 64 + ((t - 4) >> 1) * 16 + n];
                    else        v = (n < 8) ? W2[((t - 12) * 32 + kp) * 8 + n] : 0.0f;
                }
                h2[s] = bf16_rn(v);
            }
            hi[d] = h2[0] | (h2[1] << 16);
        }
        ((uint4*)ws)[t * 64 + lane] = make_uint4(hi[0], hi[1], hi[2], hi[3]);
    }
}

// ---- pass A: coarse levels 3,4 only (4MB working set = per-XCD L2).
// Partial store REGULAR (same-XCD L2 carry to pb, R16 lesson).
__global__ __launch_bounds__(256, 8)
void ngp_pa(const float* __restrict__ xyz, const int* __restrict__ boundp,
            unsigned* __restrict__ ws)
{
    const int tid = threadIdx.x;
    const int ge  = blockIdx.x * 256 + tid;
    const int pt  = ge >> 3;
    const int b   = ge & 7;

    const float bnd = (float)boundp[0];
    const float sc  = 0.5f / bnd;
    const float pxv = __builtin_nontemporal_load(xyz + pt * 3 + 0);
    const float pyv = __builtin_nontemporal_load(xyz + pt * 3 + 1);
    const float pzv = __builtin_nontemporal_load(xyz + pt * 3 + 2);
    const float cxf = (pxv + bnd) * sc * 512.0f;
    const float cyf = (pyv + bnd) * sc * 512.0f;
    const float czf = (pzv + bnd) * sc * 512.0f;
    const float c0x = fminf(fmaxf(floorf(cxf), 0.0f), 511.0f);
    const float c0y = fminf(fmaxf(floorf(cyf), 0.0f), 511.0f);
    const float c0z = fminf(fmaxf(floorf(czf), 0.0f), 511.0f);
    const unsigned kx = (unsigned)c0x + (unsigned)(b & 1);
    const unsigned ky = (unsigned)c0y + (unsigned)((b >> 1) & 1);
    const unsigned kz = (unsigned)c0z + (unsigned)((b >> 2) & 1);

    const unsigned* __restrict__ tbx = ws + TOFF;
    unsigned gH[2][8];
    #pragma unroll
    for (int l = 3; l < 5; ++l) {
        const int d = 5 - l;
        const unsigned qx = kx >> d, qy = ky >> d, qz = kz >> d;
        const unsigned hy0 = qy * cP1, hy1 = hy0 + cP1;
        const unsigned hz0 = qz * cP2, hz1 = hz0 + cP2;
        const unsigned x1u = qx + 1u;
        unsigned hidx[8];
        hidx[0] = (qx  ^ hy0 ^ hz0) & kMask;  hidx[1] = (x1u ^ hy0 ^ hz0) & kMask;
        hidx[2] = (qx  ^ hy1 ^ hz0) & kMask;  hidx[3] = (x1u ^ hy1 ^ hz0) & kMask;
        hidx[4] = (qx  ^ hy0 ^ hz1) & kMask;  hidx[5] = (x1u ^ hy0 ^ hz1) & kMask;
        hidx[6] = (qx  ^ hy1 ^ hz1) & kMask;  hidx[7] = (x1u ^ hy1 ^ hz1) & kMask;
        const unsigned* __restrict__ base = tbx + (size_t)(l - 3) * kT;
        #pragma unroll
        for (int c = 0; c < 8; ++c) gH[l - 3][c] = base[hidx[c]];
    }

    unsigned xd34[2];
    #pragma unroll
    for (int l = 3; l < 5; ++l) {
        const int d = 5 - l;
        const unsigned m = (1u << d) - 1u;
        const float inv = 1.0f / (float)(1 << d);
        const float fx = (float)(kx & m) * inv;
        const float fy = (float)(ky & m) * inv;
        const float fz = (float)(kz & m) * inv;
        const float2 g0 = bf2dec(gH[l - 3][0]), g1 = bf2dec(gH[l - 3][1]);
        const float2 g2 = bf2dec(gH[l - 3][2]), g3 = bf2dec(gH[l - 3][3]);
        const float2 g4 = bf2dec(gH[l - 3][4]), g5 = bf2dec(gH[l - 3][5]);
        const float2 g6 = bf2dec(gH[l - 3][6]), g7 = bf2dec(gH[l - 3][7]);
        const float wx1 = fx, wx0 = 1.0f - fx;
        const float wy1 = fy, wy0 = 1.0f - fy;
        const float wz1 = fz, wz0 = 1.0f - fz;
        const float w00 = wx0 * wy0, w10 = wx1 * wy0, w01 = wx0 * wy1, w11 = wx1 * wy1;
        const float a0 = w00 * wz0, a1 = w10 * wz0, a2 = w01 * wz0, a3 = w11 * wz0;
        const float a4 = w00 * wz1, a5 = w10 * wz1, a6 = w01 * wz1, a7 = w11 * wz1;
        const float vx = a0 * g0.x + a1 * g1.x + a2 * g2.x + a3 * g3.x
                       + a4 * g4.x + a5 * g5.x + a6 * g6.x + a7 * g7.x;
        const float vy = a0 * g0.y + a1 * g1.y + a2 * g2.y + a3 * g3.y
                       + a4 * g4.y + a5 * g5.y + a6 * g6.y + a7 * g7.y;
        xd34[l - 3] = cvtpk(vx, vy);
    }
    ((ull*)(ws + PARTO))[ge] = (ull)xd34[0] | ((ull)xd34[1] << 32);
}

// ---- pass B: 12 divergent gathers (A-D combos, P01 x4, P2 x4) + MLP.
__global__ __launch_bounds__(BLOCK, 5)
void ngp_pb(const float*  __restrict__ xyz,
            const int*    __restrict__ boundp,
            const unsigned* __restrict__ wsw,
            float*        __restrict__ out)
{
    // LDS: x only. row = eval (16 dw = 32 bf16 feats), quad XOR-swizzled.
    __shared__ __align__(16) unsigned lds[4096];
    const int tid  = threadIdx.x;
    const int lane = tid & 63;
    const int wv   = tid >> 6;
    const int col  = lane & 15;
    const int q    = lane >> 4;
    const int swz  = (tid ^ (tid >> 2) ^ (tid >> 4)) & 3;

    const unsigned* __restrict__ tbx = wsw + TOFF;
    const float bnd = (float)boundp[0];
    const float sc  = 0.5f / bnd;
    const f32x4 zero = {0.0f, 0.0f, 0.0f, 0.0f};

    // ================= encode (no weights live) =================
    const int ge = blockIdx.x * BLOCK + tid;
    const int pt = ge >> 3;
    const int b  = ge & 7;

    const float pxv = __builtin_nontemporal_load(xyz + pt * 3 + 0);
    const float pyv = __builtin_nontemporal_load(xyz + pt * 3 + 1);
    const float pzv = __builtin_nontemporal_load(xyz + pt * 3 + 2);
    const float cxf = (pxv + bnd) * sc * 512.0f;
    const float cyf = (pyv + bnd) * sc * 512.0f;
    const float czf = (pzv + bnd) * sc * 512.0f;
    const float c0x = fminf(fmaxf(floorf(cxf), 0.0f), 511.0f);
    const float c0y = fminf(fmaxf(floorf(cyf), 0.0f), 511.0f);
    const float c0z = fminf(fmaxf(floorf(czf), 0.0f), 511.0f);
    const float frx = cxf - c0x;
    const float fry = cyf - c0y;
    const float frz = czf - c0z;

    const unsigned kx = (unsigned)c0x + (unsigned)(b & 1);
    const unsigned ky = (unsigned)c0y + (unsigned)((b >> 1) & 1);
    const unsigned kz = (unsigned)c0z + (unsigned)((b >> 2) & 1);

    const float wb = ((b & 1) ? frx : 1.0f - frx)
                   * ((b & 2) ? fry : 1.0f - fry)
                   * ((b & 4) ? frz : 1.0f - frz);

    const unsigned kyp = ky * cP1;
    const unsigned kzp = kz * cP2;
    const unsigned X   = kx ^ kyp ^ kzp;

    // 4 combo-record gathers cover all 11 fine levels (one line each)
    const unsigned j17 = X & ((1u << 17) - 1u);
    const uint4 rA0 = *(const uint4*)(tbx + CMB + j17 * 8);
    const uint4 rA1 = *(const uint4*)(tbx + CMB + j17 * 8 + 4);
    const unsigned j14 = X & ((1u << 14) - 1u);
    const uint4 rB0 = *(const uint4*)(tbx + GB + j14 * 8);
    const uint4 rB1 = *(const uint4*)(tbx + GB + j14 * 8 + 4);
    const unsigned j11 = X & ((1u << 11) - 1u);
    const uint4 rC0 = *(const uint4*)(tbx + GC + j11 * 8);
    const uint4 rC1 = *(const uint4*)(tbx + GC + j11 * 8 + 4);
    const unsigned j9 = X & ((1u << 9) - 1u);
    const uint4 rD = ((const uint4*)(tbx + GD))[j9];

    // coarse partial (written by pass A, same block index -> same XCD L2)
    const ull pv = ((const ull*)(wsw + PARTO))[ge];

    unsigned xd[16];
    // merged levels 0+1: 4 x-pair gathers (x0,x1 in one 16B record)
    {
        const unsigned qx = kx >> 4, qy = ky >> 4, qz = kz >> 4;
        const float fx = (float)(kx & 15u) * 0.0625f;
        const float fy = (float)(ky & 15u) * 0.0625f;
        const float fz = (float)(kz & 15u) * 0.0625f;
        const unsigned x0 = qx;
        const unsigned y0 = qy * 33u, y1 = ((qy + 1u > 32u) ? 32u : qy + 1u) * 33u;
        const unsigned z0 = qz * 1089u, z1 = ((qz + 1u > 32u) ? 32u : qz + 1u) * 1089u;
        const uint4* __restrict__ p01 = (const uint4*)(tbx + P01);
        const uint4 h00 = p01[x0 + y0 + z0], h10 = p01[x0 + y1 + z0];
        const uint4 h01 = p01[x0 + y0 + z1], h11 = p01[x0 + y1 + z1];
        const float wx1 = fx, wx0 = 1.0f - fx;
        const float wy1 = fy, wy0 = 1.0f - fy;
        const float wz1 = fz, wz0 = 1.0f - fz;
        float f0x = 0.0f, f0y = 0.0f, f1x = 0.0f, f1y = 0.0f;
        #define ACC01(h, wyz) { \
            const float wl = (wyz) * wx0, wh = (wyz) * wx1; \
            float2 d; \
            d = bf2dec((h).x); f0x += wl * d.x; f0y += wl * d.y; \
            d = bf2dec((h).z); f0x += wh * d.x; f0y += wh * d.y; \
            d = bf2dec((h).y); f1x += wl * d.x; f1y += wl * d.y; \
            d = bf2dec((h).w); f1x += wh * d.x; f1y += wh * d.y; }
        ACC01(h00, wy0 * wz0); ACC01(h10, wy1 * wz0);
        ACC01(h01, wy0 * wz1); ACC01(h11, wy1 * wz1);
        #undef ACC01
        xd[0] = cvtpk(f0x, f0y);
        xd[1] = cvtpk(f1x, f1y);
    }
    // dense level 2: 4 x-pair gathers (8B records)
    {
        const unsigned qx = kx >> 3, qy = ky >> 3, qz = kz >> 3;
        const float fx = (float)(kx & 7u) * 0.125f;
        const float fy = (float)(ky & 7u) * 0.125f;
        const float fz = (float)(kz & 7u) * 0.125f;
        const unsigned x0 = qx;
        const unsigned y0 = qy * 65u, y1 = ((qy + 1u > 64u) ? 64u : qy + 1u) * 65u;
        const unsigned z0 = qz * 4225u, z1 = ((qz + 1u > 64u) ? 64u : qz + 1u) * 4225u;
        const ull* __restrict__ p2 = (const ull*)(tbx + P2);
        const ull e00 = p2[x0 + y0 + z0], e10 = p2[x0 + y1 + z0];
        const ull e01 = p2[x0 + y0 + z1], e11 = p2[x0 + y1 + z1];
        const float wx1 = fx, wx0 = 1.0f - fx;
        const float wy1 = fy, wy0 = 1.0f - fy;
        const float wz1 = fz, wz0 = 1.0f - fz;
        float vx_ = 0.0f, vy_ = 0.0f;
        #define ACC2(e, wyz) { \
            const float wl = (wyz) * wx0, wh = (wyz) * wx1; \
            const float2 dl = bf2dec((unsigned)(e)); \
            const float2 dh = bf2dec((unsigned)((e) >> 32)); \
            vx_ += wl * dl.x + wh * dh.x; vy_ += wl * dl.y + wh * dh.y; }
        ACC2(e00, wy0 * wz0); ACC2(e10, wy1 * wz0);
        ACC2(e01, wy0 * wz1); ACC2(e11, wy1 * wz1);
        #undef ACC2
        xd[2] = cvtpk(vx_, vy_);
    }
    xd[3] = (unsigned)pv;
    xd[4] = (unsigned)(pv >> 32);
    // combo selects (bit-identical relocations)
    xd[5]  = sel4(rA0, (X >> 17) & 3u);
    xd[6]  = ((X >> 17) & 1u) ? rA1.y : rA1.x;
    xd[7]  = rA1.z;
    xd[8]  = sel4(rB0, (X >> 14) & 3u);
    xd[9]  = ((X >> 14) & 1u) ? rB1.y : rB1.x;
    xd[10] = rB1.z;
    xd[11] = sel4(rC0, (X >> 11) & 3u);
    xd[12] = ((X >> 11) & 1u) ? rC1.y : rC1.x;
    xd[13] = rC1.z;
    xd[14] = ((X >> 9) & 1u) ? rD.y : rD.x;
    xd[15] = rD.z;

    // swizzled x write: quad k at position k^swz (row = tid)
    {
        uint4* xrow = (uint4*)(lds + tid * 16);
        xrow[swz]     = make_uint4(xd[0],  xd[1],  xd[2],  xd[3]);
        xrow[swz ^ 1] = make_uint4(xd[4],  xd[5],  xd[6],  xd[7]);
        xrow[swz ^ 2] = make_uint4(xd[8],  xd[9],  xd[10], xd[11]);
        xrow[swz ^ 3] = make_uint4(xd[12], xd[13], xd[14], xd[15]);
    }

    // x exchange is within-wave (ev = wv*64+...) -> wave-local fence only.
    // Memory clobber pins the weight loads below (phase-split pressure).
    asm volatile("s_waitcnt lgkmcnt(0)" ::: "memory");
    __builtin_amdgcn_sched_barrier(0);

    // ---- weights -> 56 VGPRs (same addresses all waves: L1/L2 broadcast)
    short8_t w[14];
    {
        const short8_t* __restrict__ wfr = (const short8_t*)wsw;
        #pragma unroll
        for (int t = 0; t < 14; ++t) w[t] = wfr[t * 64 + lane];
    }

    // ================= MLP (transposed MFMA, weights in regs) =========
    #pragma unroll 1
    for (int g = 0; g < 4; ++g) {
        const int ev  = wv * 64 + g * 16 + col;
        const int esw = ((ev ^ (ev >> 2) ^ (ev >> 4)) & 3) ^ q;
        const short8_t xb = *(const short8_t*)(lds + ev * 16 + esw * 4);
        const float wbv = __shfl(wb, g * 16 + col, 64);

        unsigned hp0[4], hp1[4];
        // layer 1
        #pragma unroll
        for (int mt = 0; mt < 4; ++mt) {
            f32x4 a = mfma16(w[mt], xb, zero);
            hp0[mt] = cvtpk(fmaxf(a[0], 0.0f), fmaxf(a[1], 0.0f));
            hp1[mt] = cvtpk(fmaxf(a[2], 0.0f), fmaxf(a[3], 0.0f));
        }
        uint4 u0 = make_uint4(hp0[0], hp1[0], hp0[1], hp1[1]);
        uint4 u1 = make_uint4(hp0[2], hp1[2], hp0[3], hp1[3]);
        short8_t bk0 = *(short8_t*)&u0;
        short8_t bk1 = *(short8_t*)&u1;

        // layer 2
        #pragma unroll
        for (int mt = 0; mt < 4; ++mt) {
            f32x4 a = mfma16(w[4 + mt * 2], bk0, zero);
            a = mfma16(w[5 + mt * 2], bk1, a);
            hp0[mt] = cvtpk(fmaxf(a[0], 0.0f), fmaxf(a[1], 0.0f));
            hp1[mt] = cvtpk(fmaxf(a[2], 0.0f), fmaxf(a[3], 0.0f));
        }
        u0 = make_uint4(hp0[0], hp1[0], hp0[1], hp1[1]);
        u1 = make_uint4(hp0[2], hp1[2], hp0[3], hp1[3]);
        bk0 = *(short8_t*)&u0;
        bk1 = *(short8_t*)&u1;

        // layer 3
        f32x4 a3 = mfma16(w[12], bk0, zero);
        a3 = mfma16(w[13], bk1, a3);

        // weight by wb and reduce over the 8 corners (eval low 3 bits)
        float v0 = wbv * a3[0], v1 = wbv * a3[1], v2 = wbv * a3[2], v3 = wbv * a3[3];
        #pragma unroll
        for (int s = 1; s < 8; s <<= 1) {
            v0 += __shfl_xor(v0, s);
            v1 += __shfl_xor(v1, s);
            v2 += __shfl_xor(v2, s);
            v3 += __shfl_xor(v3, s);
        }
        if (((lane & 7) == 0) && q < 2) {
            const int p = (blockIdx.x * BLOCK + ev) >> 3;
            ull* op = (ull*)(out + p * 8 + q * 4);
            __builtin_nontemporal_store(
                (ull)__float_as_uint(v0) | ((ull)__float_as_uint(v1) << 32), op);
            __builtin_nontemporal_store(
                (ull)__float_as_uint(v2) | ((ull)__float_as_uint(v3) << 32), op + 1);
        }
    }
}

// ---- tbl-only single-kernel fallback (ws too small for the split) --------
__global__ __launch_bounds__(BLOCK, 5)
void ngp_mfma(const float*  __restrict__ xyz,
              const float2* __restrict__ tbl,
              const int*    __restrict__ boundp,
              const unsigned* __restrict__ wsw,
              float*        __restrict__ out,
              int ntiles)
{
    __shared__ __align__(16) unsigned lds[4096];
    const int tid  = threadIdx.x;
    const int lane = tid & 63;
    const int wv   = tid >> 6;
    const int col  = lane & 15;
    const int q    = lane >> 4;
    const int swz  = (tid ^ (tid >> 2) ^ (tid >> 4)) & 3;

    const float bnd = (float)boundp[0];
    const float sc  = 0.5f / bnd;
    const f32x4 zero = {0.0f, 0.0f, 0.0f, 0.0f};

    const int ge = blockIdx.x * BLOCK + tid;
    const int pt = ge >> 3;
    const int b  = ge & 7;

    const float cxf = (xyz[pt * 3 + 0] + bnd) * sc * 512.0f;
    const float cyf = (xyz[pt * 3 + 1] + bnd) * sc * 512.0f;
    const float czf = (xyz[pt * 3 + 2] + bnd) * sc * 512.0f;
    const float c0x = fminf(fmaxf(floorf(cxf), 0.0f), 511.0f);
    const float c0y = fminf(fmaxf(floorf(cyf), 0.0f), 511.0f);
    const float c0z = fminf(fmaxf(floorf(czf), 0.0f), 511.0f);
    const float frx = cxf - c0x;
    const float fry = cyf - c0y;
    const float frz = czf - c0z;

    const unsigned kx = (unsigned)c0x + (unsigned)(b & 1);
    const unsigned ky = (unsigned)c0y + (unsigned)((b >> 1) & 1);
    const unsigned kz = (unsigned)c0z + (unsigned)((b >> 2) & 1);

    const float wb = ((b & 1) ? frx : 1.0f - frx)
                   * ((b & 2) ? fry : 1.0f - fry)
                   * ((b & 4) ? frz : 1.0f - frz);

    const unsigned kyp = ky * cP1;
    const unsigned kzp = kz * cP2;
    float2 gff[11];
    #pragma unroll
    for (int l = 5; l < 16; ++l) {
        const int s = l - 5;
        const unsigned idx = ((kx << s) ^ (kyp << s) ^ (kzp << s)) & kMask;
        gff[l - 5] = tbl[(size_t)l * kT + idx];
    }

    float2 gHf[2][8];
    #pragma unroll
    for (int l = 3; l < 5; ++l) {
        const int d = 5 - l;
        const unsigned qx = kx >> d, qy = ky >> d, qz = kz >> d;
        const unsigned hy0 = qy * cP1, hy1 = hy0 + cP1;
        const unsigned hz0 = qz * cP2, hz1 = hz0 + cP2;
        const unsigned x1u = qx + 1u;
        unsigned hidx[8];
        hidx[0] = (qx  ^ hy0 ^ hz0) & kMask;  hidx[1] = (x1u ^ hy0 ^ hz0) & kMask;
        hidx[2] = (qx  ^ hy1 ^ hz0) & kMask;  hidx[3] = (x1u ^ hy1 ^ hz0) & kMask;
        hidx[4] = (qx  ^ hy0 ^ hz1) & kMask;  hidx[5] = (x1u ^ hy0 ^ hz1) & kMask;
        hidx[6] = (qx  ^ hy1 ^ hz1) & kMask;  hidx[7] = (x1u ^ hy1 ^ hz1) & kMask;
        const float2* __restrict__ base = tbl + (size_t)l * kT;
        #pragma unroll
        for (int c = 0; c < 8; ++c) gHf[l - 3][c] = base[hidx[c]];
    }

    float2 gc[5];
    #pragma unroll
    for (int l = 0; l < 5; ++l) {
        const int d = 5 - l;
        const unsigned m = (1u << d) - 1u;
        const float inv = 1.0f / (float)(1 << d);
        const unsigned qx = kx >> d, qy = ky >> d, qz = kz >> d;
        const float fx = (float)(kx & m) * inv;
        const float fy = (float)(ky & m) * inv;
        const float fz = (float)(kz & m) * inv;
        float2 g0, g1, g2, g3, g4, g5, g6, g7;
        if (l < 3) {
            const unsigned res = 16u << l;
            const unsigned R = res + 1u, R2 = R * R;
            const unsigned x0 = (qx < res ? qx : res);
            const unsigned x1 = (qx + 1u < res ? qx + 1u : res);
            const unsigned y0 = (qy < res ? qy : res) * R;
            const unsigned y1 = (qy + 1u < res ? qy + 1u : res) * R;
            const unsigned z0 = (qz < res ? qz : res) * R2;
            const unsigned z1 = (qz + 1u < res ? qz + 1u : res) * R2;
            const float2* __restrict__ base = tbl + (size_t)l * kT;
            g0 = base[x0 + y0 + z0]; g1 = base[x1 + y0 + z0];
            g2 = base[x0 + y1 + z0]; g3 = base[x1 + y1 + z0];
            g4 = base[x0 + y0 + z1]; g5 = base[x1 + y0 + z1];
            g6 = base[x0 + y1 + z1]; g7 = base[x1 + y1 + z1];
        } else {
            g0 = gHf[l - 3][0]; g1 = gHf[l - 3][1]; g2 = gHf[l - 3][2]; g3 = gHf[l - 3][3];
            g4 = gHf[l - 3][4]; g5 = gHf[l - 3][5]; g6 = gHf[l - 3][6]; g7 = gHf[l - 3][7];
        }
        const float wx1 = fx, wx0 = 1.0f - fx;
        const float wy1 = fy, wy0 = 1.0f - fy;
        const float wz1 = fz, wz0 = 1.0f - fz;
        const float w00 = wx0 * wy0, w10 = wx1 * wy0, w01 = wx0 * wy1, w11 = wx1 * wy1;
        const float a0 = w00 * wz0, a1 = w10 * wz0, a2 = w01 * wz0, a3 = w11 * wz0;
        const float a4 = w00 * wz1, a5 = w10 * wz1, a6 = w01 * wz1, a7 = w11 * wz1;
        float vx = a0 * g0.x + a1 * g1.x + a2 * g2.x + a3 * g3.x
                 + a4 * g4.x + a5 * g5.x + a6 * g6.x + a7 * g7.x;
        float vy = a0 * g0.y + a1 * g1.y + a2 * g2.y + a3 * g3.y
                 + a4 * g4.y + a5 * g5.y + a6 * g6.y + a7 * g7.y;
        gc[l] = make_float2(vx, vy);
    }

    unsigned xd[16];
    #pragma unroll
    for (int l = 0; l < 5; ++l)
        xd[l] = cvtpk(gc[l].x, gc[l].y);
    #pragma unroll
    for (int l = 5; l < 16; ++l)
        xd[l] = cvtpk(gff[l - 5].x, gff[l - 5].y);
    {
        uint4* xrow = (uint4*)(lds + tid * 16);
        xrow[swz]     = make_uint4(xd[0],  xd[1],  xd[2],  xd[3]);
        xrow[swz ^ 1] = make_uint4(xd[4],  xd[5],  xd[6],  xd[7]);
        xrow[swz ^ 2] = make_uint4(xd[8],  xd[9],  xd[10], xd[11]);
        xrow[swz ^ 3] = make_uint4(xd[12], xd[13], xd[14], xd[15]);
    }

    asm volatile("s_waitcnt lgkmcnt(0)" ::: "memory");
    __builtin_amdgcn_sched_barrier(0);

    short8_t w[14];
    {
        const short8_t* __restrict__ wfr = (const short8_t*)wsw;
        #pragma unroll
        for (int t = 0; t < 14; ++t) w[t] = wfr[t * 64 + lane];
    }

    #pragma unroll 1
    for (int g = 0; g < 4; ++g) {
        const int ev  = wv * 64 + g * 16 + col;
        const int esw = ((ev ^ (ev >> 2) ^ (ev >> 4)) & 3) ^ q;
        const short8_t xb = *(const short8_t*)(lds + ev * 16 + esw * 4);
        const float wbv = __shfl(wb, g * 16 + col, 64);

        unsigned hp0[4], hp1[4];
        #pragma unroll
        for (int mt = 0; mt < 4; ++mt) {
            f32x4 a = mfma16(w[mt], xb, zero);
            hp0[mt] = cvtpk(fmaxf(a[0], 0.0f), fmaxf(a[1], 0.0f));
            hp1[mt] = cvtpk(fmaxf(a[2], 0.0f), fmaxf(a[3], 0.0f));
        }
        uint4 u0 = make_uint4(hp0[0], hp1[0], hp0[1], hp1[1]);
        uint4 u1 = make_uint4(hp0[2], hp1[2], hp0[3], hp1[3]);
        short8_t bk0 = *(short8_t*)&u0;
        short8_t bk1 = *(short8_t*)&u1;

        #pragma unroll
        for (int mt = 0; mt < 4; ++mt) {
            f32x4 a = mfma16(w[4 + mt * 2], bk0, zero);
            a = mfma16(w[5 + mt * 2], bk1, a);
            hp0[mt] = cvtpk(fmaxf(a[0], 0.0f), fmaxf(a[1], 0.0f));
            hp1[mt] = cvtpk(fmaxf(a[2], 0.0f), fmaxf(a[3], 0.0f));
        }
        u0 = make_uint4(hp0[0], hp1[0], hp0[1], hp1[1]);
        u1 = make_uint4(hp0[2], hp1[2], hp0[3], hp1[3]);
        bk0 = *(short8_t*)&u0;
        bk1 = *(short8_t*)&u1;

        f32x4 a3 = mfma16(w[12], bk0, zero);
        a3 = mfma16(w[13], bk1, a3);

        float v0 = wbv * a3[0], v1 = wbv * a3[1], v2 = wbv * a3[2], v3 = wbv * a3[3];
        #pragma unroll
        for (int s = 1; s < 8; s <<= 1) {
            v0 += __shfl_xor(v0, s);
            v1 += __shfl_xor(v1, s);
            v2 += __shfl_xor(v2, s);
            v3 += __shfl_xor(v3, s);
        }
        if (((lane & 7) == 0) && q < 2) {
            const int p = (blockIdx.x * BLOCK + ev) >> 3;
            *(float4*)(out + p * 8 + q * 4) = make_float4(v0, v1, v2, v3);
        }
    }
}

extern "C" void kernel_launch(void* const* d_in, const int* in_sizes, int n_in,
                              void* d_out, int out_size, void* d_ws, size_t ws_size,
                              hipStream_t stream) {
    const float*  xyz = (const float*)d_in[0];
    const float2* tbl = (const float2*)d_in[1];
    const float*  W0  = (const float*)d_in[2];
    const float*  W1  = (const float*)d_in[3];
    const float*  W2  = (const float*)d_in[4];
    const int*    bnd = (const int*)d_in[5];
    float* out = (float*)d_out;

    const int npts   = in_sizes[0] / 3;
    const int total  = npts * 8;
    const int ntiles = total / BLOCK;

    const bool big2 = (ws_size >= WS_NEED2);
    const int ncc  = big2 ? (1 << 19) / 256 : 0;                 // 2048
    const int ncA  = big2 ? (1 << 17) / 256 : 0;                 // 512
    const int ncB  = big2 ? (1 << 14) / 256 : 0;                 // 64
    const int ncC  = big2 ? (1 << 11) / 256 : 0;                 // 8
    const int ncD  = big2 ? 2 : 0;                               // 2 (2^9/256)
    const int nP01 = big2 ? (int)((N01 + 255u) / 256u) : 0;      // 141
    const int nP2  = big2 ? (int)((N2 + 255u) / 256u) : 0;       // 1073

    hipLaunchKernelGGL(prep_all,
                       dim3(ncc + ncA + ncB + ncC + ncD + nP01 + nP2 + 4),
                       dim3(256), 0, stream, W0, W1, W2, tbl, (unsigned*)d_ws,
                       ncc, ncA, ncB, ncC, ncD, nP01, nP2);

    if (big2) {
        hipLaunchKernelGGL(ngp_pa, dim3(total / 256), dim3(256), 0, stream,
                           xyz, bnd, (unsigned*)d_ws);
        hipLaunchKernelGGL(ngp_pb, dim3(ntiles), dim3(BLOCK), 0, stream,
                           xyz, bnd, (const unsigned*)d_ws, out);
    } else {
        hipLaunchKernelGGL(ngp_mfma, dim3(ntiles), dim3(BLOCK), 0, stream,
                           xyz, tbl, bnd, (const unsigned*)d_ws, out, ntiles);
    }
}